// Round 13
// baseline (775.348 us; speedup 1.0000x reference)
//
#include <hip/hip_runtime.h>
#include <hip/hip_bf16.h>
#include <math.h>

#define B_   2
#define S_   4096
#define D_   768
#define H_   12
#define DH_  64
#define BS_  16
#define NB_  256
#define FF_  3072
#define BT_  (B_ * S_)          // 8192 token rows
#define SCALE_F 0.125f          // 1/sqrt(64)

#define NSPLIT 32               // key-dimension splits for edge attention
#define TILES_PER_SPLIT (NB_ / NSPLIT)   // 8
#define NEDGE (B_ * H_ * 2)     // 48 edge (b,h,e) groups

#define DKS 8                   // disc pool k-splits
#define DKC (D_ / DKS)          // 96 rows per split

typedef _Float16 f16x8 __attribute__((ext_vector_type(8)));
typedef _Float16 f16x4 __attribute__((ext_vector_type(4)));
typedef _Float16 f16x2 __attribute__((ext_vector_type(2)));
typedef float    f32x4 __attribute__((ext_vector_type(4)));

#define SV2(v, k) __builtin_shufflevector(v, v, k, (k) + 1)

__device__ __forceinline__ float dot2acc(f16x2 a, f16x2 b, float c)
{
#if __has_builtin(__builtin_amdgcn_fdot2)
    return __builtin_amdgcn_fdot2(a, b, c, false);
#else
    return c + (float)a[0] * (float)b[0] + (float)a[1] * (float)b[1];
#endif
}

// async global->LDS, 16B per lane; LDS dest is wave-uniform base + lane*16
#define GLD16(gp, lp) __builtin_amdgcn_global_load_lds( \
    (const __attribute__((address_space(1))) void*)(gp), \
    (__attribute__((address_space(3))) void*)(lp), 16, 0, 0)

__device__ __forceinline__ float fast_tanh(float z)
{
    float az = fabsf(z);
    float t = __expf(-2.0f * az);
    float r = (1.0f - t) / (1.0f + t);
    return z < 0.f ? -r : r;
}

__device__ __forceinline__ float gelu_tanh(float v)
{
    float v3 = v * v * v;
    return 0.5f * v * (1.0f + fast_tanh(0.79788456080286535588f * (v + 0.044715f * v3)));
}

// ---------------------------------------------------------------------------
// Weight convert + transpose: W fp32 [K][N] -> Wt f16 [N][K]
// ---------------------------------------------------------------------------
__global__ __launch_bounds__(256) void wconvert_kernel(
    const float* __restrict__ W, _Float16* __restrict__ Wt, int K, int N)
{
    __shared__ float tile[32][33];
    int n0 = blockIdx.x * 32, k0 = blockIdx.y * 32;
    int t = threadIdx.x;
    int r = t >> 5, c = t & 31;
#pragma unroll
    for (int rr = 0; rr < 32; rr += 8)
        tile[r + rr][c] = W[(size_t)(k0 + r + rr) * N + n0 + c];
    __syncthreads();
#pragma unroll
    for (int rr = 0; rr < 32; rr += 8)
        Wt[(size_t)(n0 + r + rr) * K + k0 + c] = (_Float16)tile[c][r + rr];
}

// ---------------------------------------------------------------------------
// Embedding gather -> x fp32 and xb f16
// ---------------------------------------------------------------------------
__global__ __launch_bounds__(256) void embed_kernel(
    const int* __restrict__ ids, const float* __restrict__ emb,
    float* __restrict__ x, _Float16* __restrict__ xb)
{
    int row = blockIdx.x;
    int id = ids[row];
    const float* src = emb + (size_t)id * D_;
    float* dst = x + (size_t)row * D_;
    _Float16* dst16 = xb + (size_t)row * D_;
    for (int d = threadIdx.x; d < D_; d += 256) {
        float v = src[d];
        dst[d] = v;
        dst16[d] = (_Float16)v;
    }
}

// ---------------------------------------------------------------------------
// MFMA fp16 GEMM: C = A[M,K] @ Wt[N,K]^T + bias.  128x128 tile, BK=64,
// 4 waves, 4x4 frags/wave.  Swizzle: 16B-chunk ^= (row&7) involution.
// r12 change: OPERAND-SWAPPED mfma — acc = mfma(bf, af, acc).  By operand
// symmetry lane l then holds C[bm+i*16+(l&15)][bn+j*16+(l>>4)*4+r], i.e.
// 4 consecutive COLUMNS per acc quad -> one f16x4 (8B) store instead of
// 4 scalar stores (epilogue 64 -> 16 store insts; same 32B segments).
// ---------------------------------------------------------------------------
template<int ACT, int OUT16>
__global__ __launch_bounds__(256) void gemm_f16(
    const _Float16* __restrict__ A, const _Float16* __restrict__ Wt,
    const float* __restrict__ bias, void* __restrict__ Cp,
    int M, int N, int K)
{
    __shared__ __attribute__((aligned(16))) _Float16 As[128 * 64];
    __shared__ __attribute__((aligned(16))) _Float16 Bs[128 * 64];

    int t = threadIdx.x;
    int w = t >> 6, l = t & 63;
    int bm = blockIdx.y * 128, bn = blockIdx.x * 128;
    int wr = (w >> 1) * 64, wc = (w & 1) * 64;

    f32x4 acc[4][4];
#pragma unroll
    for (int i = 0; i < 4; ++i)
#pragma unroll
        for (int j = 0; j < 4; ++j) acc[i][j] = (f32x4){0.f, 0.f, 0.f, 0.f};

    // staging: wave w owns 1KB chunks {4w..4w+3} of each 16KB tile.
    const _Float16* gA[4];
    const _Float16* gB[4];
#pragma unroll
    for (int q = 0; q < 4; ++q) {
        int m = w * 4 + q;
        int row = m * 8 + (l >> 3);
        int sc = (l & 7) ^ (row & 7);
        gA[q] = A  + (size_t)(bm + row) * K + sc * 8;
        gB[q] = Wt + (size_t)(bn + row) * K + sc * 8;
    }

    // fragment LDS offsets (ar&7 == l&7 since wr,i*16 are multiples of 8)
    int aoff[2][4], boff[2][4];
#pragma unroll
    for (int kk = 0; kk < 2; ++kk)
#pragma unroll
        for (int i = 0; i < 4; ++i) {
            int ar = wr + i * 16 + (l & 15);
            int ch = (kk * 4 + (l >> 4)) ^ (l & 7);
            aoff[kk][i] = ar * 64 + ch * 8;
            int br = wc + i * 16 + (l & 15);
            boff[kk][i] = br * 64 + ch * 8;
        }

    for (int k0 = 0; k0 < K; k0 += 64) {
#pragma unroll
        for (int q = 0; q < 4; ++q) {
            int m = w * 4 + q;
            GLD16(gA[q] + k0, As + m * 512);
            GLD16(gB[q] + k0, Bs + m * 512);
        }
        __syncthreads();   // drains vmcnt (LDS writes) + lgkm

        f16x8 af[2][4], bf[2][4];
#pragma unroll
        for (int kk = 0; kk < 2; ++kk)
#pragma unroll
            for (int i = 0; i < 4; ++i) {
                af[kk][i] = *(const f16x8*)(As + aoff[kk][i]);
                bf[kk][i] = *(const f16x8*)(Bs + boff[kk][i]);
            }
#pragma unroll
        for (int kk = 0; kk < 2; ++kk)
#pragma unroll
            for (int i = 0; i < 4; ++i)
#pragma unroll
                for (int j = 0; j < 4; ++j)
                    acc[i][j] = __builtin_amdgcn_mfma_f32_16x16x32_f16(
                        bf[kk][j], af[kk][i], acc[i][j], 0, 0, 0);   // swapped
        __syncthreads();   // protect LDS before next stage
    }

    // epilogue (swapped layout): row = bm+wr+i*16+(l&15),
    // cols = bn+wc+j*16+(l>>4)*4 + r  -> f16x4 store per (i,j)
#pragma unroll
    for (int i = 0; i < 4; ++i) {
        int row = bm + wr + i * 16 + (l & 15);
#pragma unroll
        for (int j = 0; j < 4; ++j) {
            int col0 = bn + wc + j * 16 + ((l >> 4) << 2);
            f32x4 bv = *(const f32x4*)&bias[col0];
            if (OUT16) {
                f16x4 o;
#pragma unroll
                for (int r = 0; r < 4; ++r) {
                    float v = acc[i][j][r] + bv[r];
                    if (ACT) v = gelu_tanh(v);
                    o[r] = (_Float16)v;
                }
                *(f16x4*)&((_Float16*)Cp)[(size_t)row * N + col0] = o;
            } else {
                f32x4 o;
#pragma unroll
                for (int r = 0; r < 4; ++r) {
                    float v = acc[i][j][r] + bv[r];
                    if (ACT) v = gelu_tanh(v);
                    o[r] = v;
                }
                *(f32x4*)&((float*)Cp)[(size_t)row * N + col0] = o;
            }
        }
    }
}

// ---------------------------------------------------------------------------
// Attention core: double-buffered K/V LDS (1 barrier/tile), 2-deep register
// prefetch, unroll-1 (r7 lesson), PV p-broadcast via LDS (r11/r12 win).
// ---------------------------------------------------------------------------
template<int NT, bool EDGE>
__device__ __forceinline__ void attn_block(
    const _Float16* __restrict__ qkv, const int* __restrict__ key_idx,
    _Float16* __restrict__ outp, float* __restrict__ pm,
    float* __restrict__ pl, float* __restrict__ pacc,
    int b, int h, int n, int split, int be,
    _Float16 (*qs)[72], _Float16 (*ks)[16][72], float (*vs)[16][68],
    float (*ps)[20])
{
    int t = threadIdx.x;
    int i = t >> 4;        // query row / staging row
    int c = t & 15;
    int c4 = c * 4;

    // stage Q tile; load tile 0 into registers
    *(f16x4*)&qs[i][c4] =
        *(const f16x4*)&qkv[((size_t)(b * S_ + n * BS_ + i)) * (3 * D_) + h * DH_ + c4];
    int kb0 = EDGE ? split * NT : key_idx[n * 7];
    const _Float16* kp0 = qkv + ((size_t)(b * S_ + kb0 * BS_ + i)) * (3 * D_) + D_ + h * DH_;
    f16x4 kr = *(const f16x4*)(kp0 + c4);
    f16x4 vr = *(const f16x4*)(kp0 + D_ + c4);
    __syncthreads();   // qs visible

    // Q row into registers (broadcast reads across lanes sharing i)
    f16x8 qv[8];
#pragma unroll
    for (int d0 = 0; d0 < 8; ++d0) qv[d0] = *(const f16x8*)&qs[i][d0 * 8];

    // write tile 0 into buffer 0; prefetch tile 1
    *(f16x4*)&ks[0][i][c4] = kr;
    {
        f32x4 vf = {(float)vr[0], (float)vr[1], (float)vr[2], (float)vr[3]};
        *(f32x4*)&vs[0][i][c4] = vf;
    }
    if (NT > 1) {
        int kb1 = EDGE ? (split * NT + 1) : key_idx[n * 7 + 1];
        const _Float16* kp1 = qkv + ((size_t)(b * S_ + kb1 * BS_ + i)) * (3 * D_) + D_ + h * DH_;
        kr = *(const f16x4*)(kp1 + c4);
        vr = *(const f16x4*)(kp1 + D_ + c4);
    }
    __syncthreads();   // buffer 0 staged

    float m_old = -1e30f, lsum = 0.f;
    float acc0 = 0.f, acc1 = 0.f, acc2 = 0.f, acc3 = 0.f;

#pragma unroll 1
    for (int jj = 0; jj < NT; ++jj) {
        int cur = jj & 1;
        if (jj + 1 < NT) {
            *(f16x4*)&ks[cur ^ 1][i][c4] = kr;
            f32x4 vf = {(float)vr[0], (float)vr[1], (float)vr[2], (float)vr[3]};
            *(f32x4*)&vs[cur ^ 1][i][c4] = vf;
        }
        if (jj + 2 < NT) {
            int kb2 = EDGE ? (split * NT + jj + 2) : key_idx[n * 7 + jj + 2];
            const _Float16* kp2 = qkv + ((size_t)(b * S_ + kb2 * BS_ + i)) * (3 * D_) + D_ + h * DH_;
            kr = *(const f16x4*)(kp2 + c4);
            vr = *(const f16x4*)(kp2 + D_ + c4);
        }

        // score: <q_i, k_c> via fdot2 over b128 LDS reads
        float s0 = 0.f, s1 = 0.f;
#pragma unroll
        for (int d0 = 0; d0 < 8; ++d0) {
            f16x8 kv = *(const f16x8*)&ks[cur][c][d0 * 8];
            s0 = dot2acc(SV2(qv[d0], 0), SV2(kv, 0), s0);
            s1 = dot2acc(SV2(qv[d0], 2), SV2(kv, 2), s1);
            s0 = dot2acc(SV2(qv[d0], 4), SV2(kv, 4), s0);
            s1 = dot2acc(SV2(qv[d0], 6), SV2(kv, 6), s1);
        }
        float s = (s0 + s1) * SCALE_F;

        // online softmax within each 16-lane row group
        float rm = s;
#pragma unroll
        for (int off = 8; off; off >>= 1) rm = fmaxf(rm, __shfl_xor(rm, off, 64));
        float m_new = fmaxf(m_old, rm);
        float p = __expf(s - m_new);
        float rs = p;
#pragma unroll
        for (int off = 8; off; off >>= 1) rs += __shfl_xor(rs, off, 64);
        float corr = __expf(m_old - m_new);
        lsum = lsum * corr + rs;
        acc0 *= corr; acc1 *= corr; acc2 *= corr; acc3 *= corr;

        // PV: p shared via LDS within the row group (intra-wave, no barrier)
        ps[i][c] = p;
        float parr[16];
        *(f32x4*)&parr[0]  = *(const f32x4*)&ps[i][0];
        *(f32x4*)&parr[4]  = *(const f32x4*)&ps[i][4];
        *(f32x4*)&parr[8]  = *(const f32x4*)&ps[i][8];
        *(f32x4*)&parr[12] = *(const f32x4*)&ps[i][12];
#pragma unroll
        for (int j = 0; j < 16; ++j) {
            f32x4 vv = *(const f32x4*)&vs[cur][j][c4];
            acc0 += parr[j] * vv[0];
            acc1 += parr[j] * vv[1];
            acc2 += parr[j] * vv[2];
            acc3 += parr[j] * vv[3];
        }
        m_old = m_new;
        __syncthreads();   // all reads of cur done; writes to cur^1 visible
    }

    if (EDGE) {
        int psx = (be * NSPLIT + split) * 16 + i;
        if (c == 0) { pm[psx] = m_old; pl[psx] = lsum; }
        float* pd = pacc + (size_t)psx * 64 + c4;
        pd[0] = acc0; pd[1] = acc1; pd[2] = acc2; pd[3] = acc3;
    } else {
        float inv = 1.f / lsum;
        _Float16* dst = outp + ((size_t)(b * S_ + n * BS_ + i)) * D_ + h * DH_ + c4;
        dst[0] = (_Float16)(acc0 * inv);
        dst[1] = (_Float16)(acc1 * inv);
        dst[2] = (_Float16)(acc2 * inv);
        dst[3] = (_Float16)(acc3 * inv);
    }
}

// Sparse (non-edge) attention
__global__ __launch_bounds__(256) void attn_sparse(
    const _Float16* __restrict__ qkv, const int* __restrict__ key_idx,
    _Float16* __restrict__ outp)
{
    __shared__ __attribute__((aligned(16))) _Float16 qs[16][72];
    __shared__ __attribute__((aligned(16))) _Float16 ks[2][16][72];
    __shared__ __attribute__((aligned(16))) float    vs[2][16][68];
    __shared__ __attribute__((aligned(16))) float    ps[16][20];

    int bi = blockIdx.x;
    int n = bi % NB_;
    if (n == 0 || n == NB_ - 1) return;
    int h = (bi / NB_) % H_;
    int b = bi / (NB_ * H_);

    attn_block<7, false>(qkv, key_idx, outp, nullptr, nullptr, nullptr,
                         b, h, n, 0, 0, qs, ks, vs, ps);
}

// Edge attention split-K partials
__global__ __launch_bounds__(256) void attn_edge(
    const _Float16* __restrict__ qkv, float* __restrict__ pm,
    float* __restrict__ pl, float* __restrict__ pacc)
{
    __shared__ __attribute__((aligned(16))) _Float16 qs[16][72];
    __shared__ __attribute__((aligned(16))) _Float16 ks[2][16][72];
    __shared__ __attribute__((aligned(16))) float    vs[2][16][68];
    __shared__ __attribute__((aligned(16))) float    ps[16][20];

    int bi = blockIdx.x;
    int split = bi % NSPLIT;
    int be = bi / NSPLIT;
    int e = be & 1;
    int h = (be >> 1) % H_;
    int b = be / (2 * H_);
    int n = e ? (NB_ - 1) : 0;

    attn_block<TILES_PER_SPLIT, true>(qkv, nullptr, nullptr, pm, pl, pacc,
                                      b, h, n, split, be, qs, ks, vs, ps);
}

// ---------------------------------------------------------------------------
// Edge attention combine: one block per be group; merge NSPLIT partials.
// ---------------------------------------------------------------------------
__global__ __launch_bounds__(256) void attn_edge_combine(
    const float* __restrict__ pm, const float* __restrict__ pl,
    const float* __restrict__ pacc, _Float16* __restrict__ outp)
{
    int be = blockIdx.x;
    int e = be & 1;
    int h = (be >> 1) % H_;
    int b = be / (2 * H_);
    int n = e ? (NB_ - 1) : 0;

    int t = threadIdx.x;
    int i = t >> 4;
    int c = t & 15;

    float M = -1e30f;
#pragma unroll 4
    for (int s = 0; s < NSPLIT; ++s)
        M = fmaxf(M, pm[(be * NSPLIT + s) * 16 + i]);

    float L = 0.f;
    float acc[4] = {0.f, 0.f, 0.f, 0.f};
    for (int s = 0; s < NSPLIT; ++s) {
        int ps = (be * NSPLIT + s) * 16 + i;
        float wgt = __expf(pm[ps] - M);
        L += pl[ps] * wgt;
#pragma unroll
        for (int u = 0; u < 4; ++u) acc[u] += pacc[(size_t)ps * 64 + c * 4 + u] * wgt;
    }

    float inv = 1.f / L;
    _Float16* dst = outp + ((size_t)(b * S_ + n * BS_ + i)) * D_ + h * DH_ + c * 4;
#pragma unroll
    for (int u = 0; u < 4; ++u) dst[u] = (_Float16)(acc[u] * inv);
}

// ---------------------------------------------------------------------------
// x = LayerNorm(x + g); g is f16; writes fp32 x and f16 xb
// ---------------------------------------------------------------------------
__global__ __launch_bounds__(256) void add_ln_kernel(
    float* __restrict__ x, const _Float16* __restrict__ g,
    const float* __restrict__ gamma, const float* __restrict__ beta,
    _Float16* __restrict__ xb)
{
    int row = blockIdx.x;
    int t = threadIdx.x;
    float* xr = x + (size_t)row * D_;
    const _Float16* gr = g + (size_t)row * D_;
    _Float16* br = xb + (size_t)row * D_;

    float v[3];
    float s = 0.f, s2 = 0.f;
#pragma unroll
    for (int r = 0; r < 3; ++r) {
        int d = t + 256 * r;
        v[r] = xr[d] + (float)gr[d];
        s += v[r];
        s2 += v[r] * v[r];
    }
#pragma unroll
    for (int off = 32; off; off >>= 1) {
        s  += __shfl_xor(s, off, 64);
        s2 += __shfl_xor(s2, off, 64);
    }
    __shared__ float sA[4], sB[4];
    int wave = t >> 6, lane = t & 63;
    if (lane == 0) { sA[wave] = s; sB[wave] = s2; }
    __syncthreads();
    s  = sA[0] + sA[1] + sA[2] + sA[3];
    s2 = sB[0] + sB[1] + sB[2] + sB[3];
    float mean = s * (1.0f / D_);
    float var = s2 * (1.0f / D_) - mean * mean;
    float rstd = rsqrtf(var + 1e-12f);
#pragma unroll
    for (int r = 0; r < 3; ++r) {
        int d = t + 256 * r;
        float o = (v[r] - mean) * rstd * gamma[d] + beta[d];
        xr[d] = o;
        br[d] = (_Float16)o;
    }
}

// ---------------------------------------------------------------------------
__global__ __launch_bounds__(64) void head_logits(
    const float* __restrict__ x, const float* __restrict__ sw,
    const float* __restrict__ ew, float* __restrict__ sl, float* __restrict__ el)
{
    int row = blockIdx.x;
    int lane = threadIdx.x;
    const float* xr = x + (size_t)row * D_;
    float a = 0.f, e = 0.f;
    for (int d = lane; d < D_; d += 64) {
        float xv = xr[d];
        a += xv * sw[d];
        e += xv * ew[d];
    }
#pragma unroll
    for (int off = 32; off; off >>= 1) {
        a += __shfl_xor(a, off, 64);
        e += __shfl_xor(e, off, 64);
    }
    if (lane == 0) { sl[row] = a; el[row] = e; }
}

__global__ __launch_bounds__(256) void softmax_rows(
    const float* __restrict__ sl, const float* __restrict__ el,
    float* __restrict__ outp)
{
    int r = blockIdx.x;
    const float* src = (r < 2 ? sl : el) + (size_t)(r & 1) * S_;
    float* dst = outp + (r < 2 ? 0 : BT_) + (size_t)(r & 1) * S_;
    int t = threadIdx.x;
    int wave = t >> 6, lane = t & 63;
    __shared__ float sm[4], ss[4];

    float m = -1e30f;
    for (int k = t; k < S_; k += 256) m = fmaxf(m, src[k]);
#pragma unroll
    for (int off = 32; off; off >>= 1) m = fmaxf(m, __shfl_xor(m, off, 64));
    if (lane == 0) sm[wave] = m;
    __syncthreads();
    m = fmaxf(fmaxf(sm[0], sm[1]), fmaxf(sm[2], sm[3]));

    float s = 0.f;
    for (int k = t; k < S_; k += 256) s += __expf(src[k] - m);
#pragma unroll
    for (int off = 32; off; off >>= 1) s += __shfl_xor(s, off, 64);
    if (lane == 0) ss[wave] = s;
    __syncthreads();
    s = ss[0] + ss[1] + ss[2] + ss[3];

    float inv = 1.f / s;
    for (int k = t; k < S_; k += 256) dst[k] = __expf(src[k] - m) * inv;
}

// ---------------------------------------------------------------------------
// disc pool GEMV, split across grid; then tiny finish kernel
// ---------------------------------------------------------------------------
__global__ __launch_bounds__(256) void disc_pool_partial(
    const float* __restrict__ x, const float* __restrict__ Wp,
    float* __restrict__ partial)
{
    int jb = blockIdx.x;      // 0..2
    int ks = blockIdx.y;      // 0..DKS-1
    int t = threadIdx.x;
    int j = jb * 256 + t;
    int k0 = ks * DKC;

    __shared__ float xs[DKC];
    if (t < DKC) xs[t] = x[k0 + t];   // x0 = x row 0
    __syncthreads();

    float s = 0.f;
#pragma unroll 8
    for (int kk = 0; kk < DKC; ++kk)
        s += xs[kk] * Wp[(size_t)(k0 + kk) * D_ + j];
    partial[ks * D_ + j] = s;
}

__global__ __launch_bounds__(256) void disc_finish(
    const float* __restrict__ partial, const float* __restrict__ bp,
    const float* __restrict__ d1W, const float* __restrict__ d1b,
    const float* __restrict__ d2W, const float* __restrict__ d2b,
    float* __restrict__ out2)
{
    __shared__ float pool[D_];
    __shared__ float h1[20];
    int t = threadIdx.x;
    for (int j = t; j < D_; j += 256) {
        float s = bp[j];
#pragma unroll
        for (int ks = 0; ks < DKS; ++ks) s += partial[ks * D_ + j];
        pool[j] = tanhf(s);
    }
    __syncthreads();
    if (t < 20) {
        float s = d1b[t];
        for (int k = 0; k < D_; ++k) s += pool[k] * d1W[k * 20 + t];
        h1[t] = s;
    }
    __syncthreads();
    if (t == 0) {
        float d0 = d2b[0], d1v = d2b[1];
#pragma unroll
        for (int u = 0; u < 20; ++u) {
            d0  += h1[u] * d2W[u * 2 + 0];
            d1v += h1[u] * d2W[u * 2 + 1];
        }
        float m = fmaxf(d0, d1v);
        float e0 = __expf(d0 - m), e1 = __expf(d1v - m);
        float inv = 1.f / (e0 + e1);
        out2[0] = e0 * inv;
        out2[1] = e1 * inv;
    }
}

// ---------------------------------------------------------------------------
extern "C" void kernel_launch(void* const* d_in, const int* in_sizes, int n_in,
                              void* d_out, int out_size, void* d_ws, size_t ws_size,
                              hipStream_t stream)
{
    const int*   ids   = (const int*)d_in[0];
    const int*   kbi   = (const int*)d_in[1];
    const float* emb   = (const float*)d_in[2];
    const float* Wqkv  = (const float*)d_in[3];
    const float* bqkv  = (const float*)d_in[4];
    const float* Wo    = (const float*)d_in[5];
    const float* bo    = (const float*)d_in[6];
    const float* ln1g  = (const float*)d_in[7];
    const float* ln1b  = (const float*)d_in[8];
    const float* Wff1  = (const float*)d_in[9];
    const float* bff1  = (const float*)d_in[10];
    const float* Wff2  = (const float*)d_in[11];
    const float* bff2  = (const float*)d_in[12];
    const float* ln2g  = (const float*)d_in[13];
    const float* ln2b  = (const float*)d_in[14];
    const float* Wp    = (const float*)d_in[15];
    const float* bp    = (const float*)d_in[16];
    const float* sw    = (const float*)d_in[17];
    const float* ew    = (const float*)d_in[18];
    const float* d1W   = (const float*)d_in[19];
    const float* d1b   = (const float*)d_in[20];
    const float* d2W   = (const float*)d_in[21];
    const float* d2b   = (const float*)d_in[22];
    float* outp = (float*)d_out;

    // workspace carve (float units)
    float* ws   = (float*)d_ws;
    float* x    = ws;                          // BT_*D_ f32
    float* xbf  = x   + (size_t)BT_ * D_;      // f16 xb
    float* r1f  = xbf + (size_t)BT_ * D_ / 2;  // f16 qkv / f16 h
    float* abf  = r1f + (size_t)BT_ * FF_ / 2; // f16 attn out
    float* r2   = abf + (size_t)BT_ * D_ / 2;  // partials (early) / f16 g (late)
    float* wtf  = r2  + (size_t)BT_ * D_;      // f16 weights
    float* sl   = wtf + 7077888;
    float* el   = sl  + BT_;
    float* dpar = el  + BT_;                   // DKS * D_ disc partials

    _Float16* xb    = (_Float16*)xbf;
    _Float16* qkv16 = (_Float16*)r1f;
    _Float16* h16   = (_Float16*)r1f;
    _Float16* ab    = (_Float16*)abf;
    float* pm   = r2;
    float* pl   = r2 + NEDGE * NSPLIT * 16;
    float* pacc = pl + NEDGE * NSPLIT * 16;
    _Float16* g16 = (_Float16*)r2;   // aliased; partials dead once proj runs

    _Float16* Wt    = (_Float16*)wtf;
    _Float16* WqkvT = Wt;
    _Float16* WoT   = WqkvT + (size_t)2 * 2304 * 768;
    _Float16* Wff1T = WoT   + (size_t)2 * 768 * 768;
    _Float16* Wff2T = Wff1T + (size_t)2 * 3072 * 768;

    for (int l = 0; l < 2; ++l) {
        wconvert_kernel<<<dim3(2304/32, 768/32), 256, 0, stream>>>(
            Wqkv + (size_t)l * 768 * 2304, WqkvT + (size_t)l * 2304 * 768, 768, 2304);
        wconvert_kernel<<<dim3(768/32, 768/32), 256, 0, stream>>>(
            Wo + (size_t)l * 768 * 768, WoT + (size_t)l * 768 * 768, 768, 768);
        wconvert_kernel<<<dim3(3072/32, 768/32), 256, 0, stream>>>(
            Wff1 + (size_t)l * 768 * 3072, Wff1T + (size_t)l * 3072 * 768, 768, 3072);
        wconvert_kernel<<<dim3(768/32, 3072/32), 256, 0, stream>>>(
            Wff2 + (size_t)l * 3072 * 768, Wff2T + (size_t)l * 768 * 3072, 3072, 768);
    }

    embed_kernel<<<BT_, 256, 0, stream>>>(ids, emb, x, xb);

    for (int l = 0; l < 2; ++l) {
        gemm_f16<0,1><<<dim3(2304/128, BT_/128), 256, 0, stream>>>(
            xb, WqkvT + (size_t)l * 2304 * 768, bqkv + (size_t)l * 3 * D_,
            qkv16, BT_, 3 * D_, D_);
        attn_sparse<<<B_ * H_ * NB_, 256, 0, stream>>>(qkv16, kbi, ab);
        attn_edge<<<NEDGE * NSPLIT, 256, 0, stream>>>(qkv16, pm, pl, pacc);
        attn_edge_combine<<<NEDGE, 256, 0, stream>>>(pm, pl, pacc, ab);
        gemm_f16<0,1><<<dim3(768/128, BT_/128), 256, 0, stream>>>(
            ab, WoT + (size_t)l * 768 * 768, bo + (size_t)l * D_,
            g16, BT_, D_, D_);
        add_ln_kernel<<<BT_, 256, 0, stream>>>(x, g16, ln1g + (size_t)l * D_, ln1b + (size_t)l * D_, xb);
        gemm_f16<1,1><<<dim3(3072/128, BT_/128), 256, 0, stream>>>(
            xb, Wff1T + (size_t)l * 3072 * 768, bff1 + (size_t)l * FF_,
            h16, BT_, FF_, D_);
        gemm_f16<0,1><<<dim3(768/128, BT_/128), 256, 0, stream>>>(
            h16, Wff2T + (size_t)l * 768 * 3072, bff2 + (size_t)l * D_,
            g16, BT_, D_, FF_);
        add_ln_kernel<<<BT_, 256, 0, stream>>>(x, g16, ln2g + (size_t)l * D_, ln2b + (size_t)l * D_, xb);
    }

    head_logits<<<BT_, 64, 0, stream>>>(x, sw, ew, sl, el);
    softmax_rows<<<4, 256, 0, stream>>>(sl, el, outp);
    disc_pool_partial<<<dim3(3, DKS), 256, 0, stream>>>(x, Wp, dpar);
    disc_finish<<<1, 256, 0, stream>>>(dpar, bp, d1W, d1b, d2W, d2b, outp + 2 * BT_);
}

// Round 14
// 747.410 us; speedup vs baseline: 1.0374x; 1.0374x over previous
//
#include <hip/hip_runtime.h>
#include <hip/hip_bf16.h>
#include <math.h>

#define B_   2
#define S_   4096
#define D_   768
#define H_   12
#define DH_  64
#define BS_  16
#define NB_  256
#define FF_  3072
#define BT_  (B_ * S_)          // 8192 token rows
#define SCALE_F 0.125f          // 1/sqrt(64)

#define NSPLIT 32               // key-dimension splits for edge attention
#define TILES_PER_SPLIT (NB_ / NSPLIT)   // 8
#define NEDGE (B_ * H_ * 2)     // 48 edge (b,h,e) groups
#define NSPARSE (B_ * H_ * NB_) // 6144 sparse blocks

#define DKS 8                   // disc pool k-splits
#define DKC (D_ / DKS)          // 96 rows per split

typedef _Float16 f16x8 __attribute__((ext_vector_type(8)));
typedef _Float16 f16x4 __attribute__((ext_vector_type(4)));
typedef _Float16 f16x2 __attribute__((ext_vector_type(2)));
typedef float    f32x4 __attribute__((ext_vector_type(4)));

#define SV2(v, k) __builtin_shufflevector(v, v, k, (k) + 1)

__device__ __forceinline__ float dot2acc(f16x2 a, f16x2 b, float c)
{
#if __has_builtin(__builtin_amdgcn_fdot2)
    return __builtin_amdgcn_fdot2(a, b, c, false);
#else
    return c + (float)a[0] * (float)b[0] + (float)a[1] * (float)b[1];
#endif
}

// async global->LDS, 16B per lane; LDS dest is wave-uniform base + lane*16
#define GLD16(gp, lp) __builtin_amdgcn_global_load_lds( \
    (const __attribute__((address_space(1))) void*)(gp), \
    (__attribute__((address_space(3))) void*)(lp), 16, 0, 0)

__device__ __forceinline__ float fast_tanh(float z)
{
    float az = fabsf(z);
    float t = __expf(-2.0f * az);
    float r = (1.0f - t) / (1.0f + t);
    return z < 0.f ? -r : r;
}

__device__ __forceinline__ float gelu_tanh(float v)
{
    float v3 = v * v * v;
    return 0.5f * v * (1.0f + fast_tanh(0.79788456080286535588f * (v + 0.044715f * v3)));
}

// ---------------------------------------------------------------------------
// Weight convert + transpose: W fp32 [K][N] -> Wt f16 [N][K]
// ---------------------------------------------------------------------------
__global__ __launch_bounds__(256) void wconvert_kernel(
    const float* __restrict__ W, _Float16* __restrict__ Wt, int K, int N)
{
    __shared__ float tile[32][33];
    int n0 = blockIdx.x * 32, k0 = blockIdx.y * 32;
    int t = threadIdx.x;
    int r = t >> 5, c = t & 31;
#pragma unroll
    for (int rr = 0; rr < 32; rr += 8)
        tile[r + rr][c] = W[(size_t)(k0 + r + rr) * N + n0 + c];
    __syncthreads();
#pragma unroll
    for (int rr = 0; rr < 32; rr += 8)
        Wt[(size_t)(n0 + r + rr) * K + k0 + c] = (_Float16)tile[c][r + rr];
}

// ---------------------------------------------------------------------------
// Embedding gather -> x fp32 and xb f16
// ---------------------------------------------------------------------------
__global__ __launch_bounds__(256) void embed_kernel(
    const int* __restrict__ ids, const float* __restrict__ emb,
    float* __restrict__ x, _Float16* __restrict__ xb)
{
    int row = blockIdx.x;
    int id = ids[row];
    const float* src = emb + (size_t)id * D_;
    float* dst = x + (size_t)row * D_;
    _Float16* dst16 = xb + (size_t)row * D_;
    for (int d = threadIdx.x; d < D_; d += 256) {
        float v = src[d];
        dst[d] = v;
        dst16[d] = (_Float16)v;
    }
}

// ---------------------------------------------------------------------------
// MFMA fp16 GEMM (round-8/12 verified kernel, swap reverted — r13):
// C = A[M,K] @ Wt[N,K]^T + bias. 128x128 tile, BK=64, 4 waves, 4x4 frags.
// Swizzle: 16B-chunk ^= (row&7) involution on stage-source and read.
// ---------------------------------------------------------------------------
template<int ACT, int OUT16>
__global__ __launch_bounds__(256) void gemm_f16(
    const _Float16* __restrict__ A, const _Float16* __restrict__ Wt,
    const float* __restrict__ bias, void* __restrict__ Cp,
    int M, int N, int K)
{
    __shared__ __attribute__((aligned(16))) _Float16 As[128 * 64];
    __shared__ __attribute__((aligned(16))) _Float16 Bs[128 * 64];

    int t = threadIdx.x;
    int w = t >> 6, l = t & 63;
    int bm = blockIdx.y * 128, bn = blockIdx.x * 128;
    int wr = (w >> 1) * 64, wc = (w & 1) * 64;

    f32x4 acc[4][4];
#pragma unroll
    for (int i = 0; i < 4; ++i)
#pragma unroll
        for (int j = 0; j < 4; ++j) acc[i][j] = (f32x4){0.f, 0.f, 0.f, 0.f};

    const _Float16* gA[4];
    const _Float16* gB[4];
#pragma unroll
    for (int q = 0; q < 4; ++q) {
        int m = w * 4 + q;
        int row = m * 8 + (l >> 3);
        int sc = (l & 7) ^ (row & 7);
        gA[q] = A  + (size_t)(bm + row) * K + sc * 8;
        gB[q] = Wt + (size_t)(bn + row) * K + sc * 8;
    }

    int aoff[2][4], boff[2][4];
#pragma unroll
    for (int kk = 0; kk < 2; ++kk)
#pragma unroll
        for (int i = 0; i < 4; ++i) {
            int ar = wr + i * 16 + (l & 15);
            int ch = (kk * 4 + (l >> 4)) ^ (l & 7);
            aoff[kk][i] = ar * 64 + ch * 8;
            int br = wc + i * 16 + (l & 15);
            boff[kk][i] = br * 64 + ch * 8;
        }

    for (int k0 = 0; k0 < K; k0 += 64) {
#pragma unroll
        for (int q = 0; q < 4; ++q) {
            int m = w * 4 + q;
            GLD16(gA[q] + k0, As + m * 512);
            GLD16(gB[q] + k0, Bs + m * 512);
        }
        __syncthreads();

        f16x8 af[2][4], bf[2][4];
#pragma unroll
        for (int kk = 0; kk < 2; ++kk)
#pragma unroll
            for (int i = 0; i < 4; ++i) {
                af[kk][i] = *(const f16x8*)(As + aoff[kk][i]);
                bf[kk][i] = *(const f16x8*)(Bs + boff[kk][i]);
            }
#pragma unroll
        for (int kk = 0; kk < 2; ++kk)
#pragma unroll
            for (int i = 0; i < 4; ++i)
#pragma unroll
                for (int j = 0; j < 4; ++j)
                    acc[i][j] = __builtin_amdgcn_mfma_f32_16x16x32_f16(
                        af[kk][i], bf[kk][j], acc[i][j], 0, 0, 0);
        __syncthreads();
    }

    // epilogue: C/D layout col = lane&15, row = (lane>>4)*4 + reg
#pragma unroll
    for (int i = 0; i < 4; ++i) {
        int rowb = bm + wr + i * 16 + ((l >> 4) << 2);
#pragma unroll
        for (int j = 0; j < 4; ++j) {
            int col = bn + wc + j * 16 + (l & 15);
            float bv = bias[col];
#pragma unroll
            for (int r = 0; r < 4; ++r) {
                float v = acc[i][j][r] + bv;
                if (ACT) v = gelu_tanh(v);
                if (OUT16)
                    ((_Float16*)Cp)[(size_t)(rowb + r) * N + col] = (_Float16)v;
                else
                    ((float*)Cp)[(size_t)(rowb + r) * N + col] = v;
            }
        }
    }
}

// ---------------------------------------------------------------------------
// Attention core: double-buffered K/V LDS (1 barrier/tile), 2-deep register
// prefetch, unroll-1 (r7 lesson), PV p-broadcast via LDS (r12 win).
// ---------------------------------------------------------------------------
template<int NT, bool EDGE>
__device__ __forceinline__ void attn_block(
    const _Float16* __restrict__ qkv, const int* __restrict__ key_idx,
    _Float16* __restrict__ outp, float* __restrict__ pm,
    float* __restrict__ pl, float* __restrict__ pacc,
    int b, int h, int n, int split, int be,
    _Float16 (*qs)[72], _Float16 (*ks)[16][72], float (*vs)[16][68],
    float (*ps)[20])
{
    int t = threadIdx.x;
    int i = t >> 4;        // query row / staging row
    int c = t & 15;
    int c4 = c * 4;

    // stage Q tile; load tile 0 into registers
    *(f16x4*)&qs[i][c4] =
        *(const f16x4*)&qkv[((size_t)(b * S_ + n * BS_ + i)) * (3 * D_) + h * DH_ + c4];
    int kb0 = EDGE ? split * NT : key_idx[n * 7];
    const _Float16* kp0 = qkv + ((size_t)(b * S_ + kb0 * BS_ + i)) * (3 * D_) + D_ + h * DH_;
    f16x4 kr = *(const f16x4*)(kp0 + c4);
    f16x4 vr = *(const f16x4*)(kp0 + D_ + c4);
    __syncthreads();   // qs visible

    f16x8 qv[8];
#pragma unroll
    for (int d0 = 0; d0 < 8; ++d0) qv[d0] = *(const f16x8*)&qs[i][d0 * 8];

    *(f16x4*)&ks[0][i][c4] = kr;
    {
        f32x4 vf = {(float)vr[0], (float)vr[1], (float)vr[2], (float)vr[3]};
        *(f32x4*)&vs[0][i][c4] = vf;
    }
    if (NT > 1) {
        int kb1 = EDGE ? (split * NT + 1) : key_idx[n * 7 + 1];
        const _Float16* kp1 = qkv + ((size_t)(b * S_ + kb1 * BS_ + i)) * (3 * D_) + D_ + h * DH_;
        kr = *(const f16x4*)(kp1 + c4);
        vr = *(const f16x4*)(kp1 + D_ + c4);
    }
    __syncthreads();   // buffer 0 staged

    float m_old = -1e30f, lsum = 0.f;
    float acc0 = 0.f, acc1 = 0.f, acc2 = 0.f, acc3 = 0.f;

#pragma unroll 1
    for (int jj = 0; jj < NT; ++jj) {
        int cur = jj & 1;
        if (jj + 1 < NT) {
            *(f16x4*)&ks[cur ^ 1][i][c4] = kr;
            f32x4 vf = {(float)vr[0], (float)vr[1], (float)vr[2], (float)vr[3]};
            *(f32x4*)&vs[cur ^ 1][i][c4] = vf;
        }
        if (jj + 2 < NT) {
            int kb2 = EDGE ? (split * NT + jj + 2) : key_idx[n * 7 + jj + 2];
            const _Float16* kp2 = qkv + ((size_t)(b * S_ + kb2 * BS_ + i)) * (3 * D_) + D_ + h * DH_;
            kr = *(const f16x4*)(kp2 + c4);
            vr = *(const f16x4*)(kp2 + D_ + c4);
        }

        // score: <q_i, k_c> via fdot2 over b128 LDS reads
        float s0 = 0.f, s1 = 0.f;
#pragma unroll
        for (int d0 = 0; d0 < 8; ++d0) {
            f16x8 kv = *(const f16x8*)&ks[cur][c][d0 * 8];
            s0 = dot2acc(SV2(qv[d0], 0), SV2(kv, 0), s0);
            s1 = dot2acc(SV2(qv[d0], 2), SV2(kv, 2), s1);
            s0 = dot2acc(SV2(qv[d0], 4), SV2(kv, 4), s0);
            s1 = dot2acc(SV2(qv[d0], 6), SV2(kv, 6), s1);
        }
        float s = (s0 + s1) * SCALE_F;

        // online softmax within each 16-lane row group
        float rm = s;
#pragma unroll
        for (int off = 8; off; off >>= 1) rm = fmaxf(rm, __shfl_xor(rm, off, 64));
        float m_new = fmaxf(m_old, rm);
        float p = __expf(s - m_new);
        float rs = p;
#pragma unroll
        for (int off = 8; off; off >>= 1) rs += __shfl_xor(rs, off, 64);
        float corr = __expf(m_old - m_new);
        lsum = lsum * corr + rs;
        acc0 *= corr; acc1 *= corr; acc2 *= corr; acc3 *= corr;

        // PV: p shared via LDS within the row group (intra-wave, no barrier)
        ps[i][c] = p;
        float parr[16];
        *(f32x4*)&parr[0]  = *(const f32x4*)&ps[i][0];
        *(f32x4*)&parr[4]  = *(const f32x4*)&ps[i][4];
        *(f32x4*)&parr[8]  = *(const f32x4*)&ps[i][8];
        *(f32x4*)&parr[12] = *(const f32x4*)&ps[i][12];
#pragma unroll
        for (int j = 0; j < 16; ++j) {
            f32x4 vv = *(const f32x4*)&vs[cur][j][c4];
            acc0 += parr[j] * vv[0];
            acc1 += parr[j] * vv[1];
            acc2 += parr[j] * vv[2];
            acc3 += parr[j] * vv[3];
        }
        m_old = m_new;
        __syncthreads();   // all reads of cur done; writes to cur^1 visible
    }

    if (EDGE) {
        int psx = (be * NSPLIT + split) * 16 + i;
        if (c == 0) { pm[psx] = m_old; pl[psx] = lsum; }
        float* pd = pacc + (size_t)psx * 64 + c4;
        pd[0] = acc0; pd[1] = acc1; pd[2] = acc2; pd[3] = acc3;
    } else {
        float inv = 1.f / lsum;
        _Float16* dst = outp + ((size_t)(b * S_ + n * BS_ + i)) * D_ + h * DH_ + c4;
        dst[0] = (_Float16)(acc0 * inv);
        dst[1] = (_Float16)(acc1 * inv);
        dst[2] = (_Float16)(acc2 * inv);
        dst[3] = (_Float16)(acc3 * inv);
    }
}

// ---------------------------------------------------------------------------
// Fused attention dispatch (r13): grid = NSPARSE + NEDGE*NSPLIT blocks.
// bi < NSPARSE -> sparse path (edges skip); else -> edge split-K partials.
// Edge blocks fill the sparse dispatch's straggler tail (saves one serial
// dispatch boundary per layer). Outputs are disjoint (ab vs pm/pl/pacc).
// ---------------------------------------------------------------------------
__global__ __launch_bounds__(256) void attn_fused(
    const _Float16* __restrict__ qkv, const int* __restrict__ key_idx,
    _Float16* __restrict__ outp, float* __restrict__ pm,
    float* __restrict__ pl, float* __restrict__ pacc)
{
    __shared__ __attribute__((aligned(16))) _Float16 qs[16][72];
    __shared__ __attribute__((aligned(16))) _Float16 ks[2][16][72];
    __shared__ __attribute__((aligned(16))) float    vs[2][16][68];
    __shared__ __attribute__((aligned(16))) float    ps[16][20];

    int bi = blockIdx.x;
    if (bi < NSPARSE) {
        int n = bi % NB_;
        if (n == 0 || n == NB_ - 1) return;   // uniform per-block
        int h = (bi / NB_) % H_;
        int b = bi / (NB_ * H_);
        attn_block<7, false>(qkv, key_idx, outp, nullptr, nullptr, nullptr,
                             b, h, n, 0, 0, qs, ks, vs, ps);
    } else {
        int ei = bi - NSPARSE;
        int split = ei % NSPLIT;
        int be = ei / NSPLIT;
        int e = be & 1;
        int h = (be >> 1) % H_;
        int b = be / (2 * H_);
        int n = e ? (NB_ - 1) : 0;
        attn_block<TILES_PER_SPLIT, true>(qkv, nullptr, nullptr, pm, pl, pacc,
                                          b, h, n, split, be, qs, ks, vs, ps);
    }
}

// ---------------------------------------------------------------------------
// Edge attention combine: one block per be group; merge NSPLIT partials.
// ---------------------------------------------------------------------------
__global__ __launch_bounds__(256) void attn_edge_combine(
    const float* __restrict__ pm, const float* __restrict__ pl,
    const float* __restrict__ pacc, _Float16* __restrict__ outp)
{
    int be = blockIdx.x;
    int e = be & 1;
    int h = (be >> 1) % H_;
    int b = be / (2 * H_);
    int n = e ? (NB_ - 1) : 0;

    int t = threadIdx.x;
    int i = t >> 4;
    int c = t & 15;

    float M = -1e30f;
#pragma unroll 4
    for (int s = 0; s < NSPLIT; ++s)
        M = fmaxf(M, pm[(be * NSPLIT + s) * 16 + i]);

    float L = 0.f;
    float acc[4] = {0.f, 0.f, 0.f, 0.f};
    for (int s = 0; s < NSPLIT; ++s) {
        int ps = (be * NSPLIT + s) * 16 + i;
        float wgt = __expf(pm[ps] - M);
        L += pl[ps] * wgt;
#pragma unroll
        for (int u = 0; u < 4; ++u) acc[u] += pacc[(size_t)ps * 64 + c * 4 + u] * wgt;
    }

    float inv = 1.f / L;
    _Float16* dst = outp + ((size_t)(b * S_ + n * BS_ + i)) * D_ + h * DH_ + c * 4;
#pragma unroll
    for (int u = 0; u < 4; ++u) dst[u] = (_Float16)(acc[u] * inv);
}

// ---------------------------------------------------------------------------
// x = LayerNorm(x + g); g is f16; writes fp32 x and f16 xb
// ---------------------------------------------------------------------------
__global__ __launch_bounds__(256) void add_ln_kernel(
    float* __restrict__ x, const _Float16* __restrict__ g,
    const float* __restrict__ gamma, const float* __restrict__ beta,
    _Float16* __restrict__ xb)
{
    int row = blockIdx.x;
    int t = threadIdx.x;
    float* xr = x + (size_t)row * D_;
    const _Float16* gr = g + (size_t)row * D_;
    _Float16* br = xb + (size_t)row * D_;

    float v[3];
    float s = 0.f, s2 = 0.f;
#pragma unroll
    for (int r = 0; r < 3; ++r) {
        int d = t + 256 * r;
        v[r] = xr[d] + (float)gr[d];
        s += v[r];
        s2 += v[r] * v[r];
    }
#pragma unroll
    for (int off = 32; off; off >>= 1) {
        s  += __shfl_xor(s, off, 64);
        s2 += __shfl_xor(s2, off, 64);
    }
    __shared__ float sA[4], sB[4];
    int wave = t >> 6, lane = t & 63;
    if (lane == 0) { sA[wave] = s; sB[wave] = s2; }
    __syncthreads();
    s  = sA[0] + sA[1] + sA[2] + sA[3];
    s2 = sB[0] + sB[1] + sB[2] + sB[3];
    float mean = s * (1.0f / D_);
    float var = s2 * (1.0f / D_) - mean * mean;
    float rstd = rsqrtf(var + 1e-12f);
#pragma unroll
    for (int r = 0; r < 3; ++r) {
        int d = t + 256 * r;
        float o = (v[r] - mean) * rstd * gamma[d] + beta[d];
        xr[d] = o;
        br[d] = (_Float16)o;
    }
}

// ---------------------------------------------------------------------------
__global__ __launch_bounds__(64) void head_logits(
    const float* __restrict__ x, const float* __restrict__ sw,
    const float* __restrict__ ew, float* __restrict__ sl, float* __restrict__ el)
{
    int row = blockIdx.x;
    int lane = threadIdx.x;
    const float* xr = x + (size_t)row * D_;
    float a = 0.f, e = 0.f;
    for (int d = lane; d < D_; d += 64) {
        float xv = xr[d];
        a += xv * sw[d];
        e += xv * ew[d];
    }
#pragma unroll
    for (int off = 32; off; off >>= 1) {
        a += __shfl_xor(a, off, 64);
        e += __shfl_xor(e, off, 64);
    }
    if (lane == 0) { sl[row] = a; el[row] = e; }
}

__global__ __launch_bounds__(256) void softmax_rows(
    const float* __restrict__ sl, const float* __restrict__ el,
    float* __restrict__ outp)
{
    int r = blockIdx.x;
    const float* src = (r < 2 ? sl : el) + (size_t)(r & 1) * S_;
    float* dst = outp + (r < 2 ? 0 : BT_) + (size_t)(r & 1) * S_;
    int t = threadIdx.x;
    int wave = t >> 6, lane = t & 63;
    __shared__ float sm[4], ss[4];

    float m = -1e30f;
    for (int k = t; k < S_; k += 256) m = fmaxf(m, src[k]);
#pragma unroll
    for (int off = 32; off; off >>= 1) m = fmaxf(m, __shfl_xor(m, off, 64));
    if (lane == 0) sm[wave] = m;
    __syncthreads();
    m = fmaxf(fmaxf(sm[0], sm[1]), fmaxf(sm[2], sm[3]));

    float s = 0.f;
    for (int k = t; k < S_; k += 256) s += __expf(src[k] - m);
#pragma unroll
    for (int off = 32; off; off >>= 1) s += __shfl_xor(s, off, 64);
    if (lane == 0) ss[wave] = s;
    __syncthreads();
    s = ss[0] + ss[1] + ss[2] + ss[3];

    float inv = 1.f / s;
    for (int k = t; k < S_; k += 256) dst[k] = __expf(src[k] - m) * inv;
}

// ---------------------------------------------------------------------------
// disc pool GEMV, split across grid; then tiny finish kernel
// ---------------------------------------------------------------------------
__global__ __launch_bounds__(256) void disc_pool_partial(
    const float* __restrict__ x, const float* __restrict__ Wp,
    float* __restrict__ partial)
{
    int jb = blockIdx.x;      // 0..2
    int ks = blockIdx.y;      // 0..DKS-1
    int t = threadIdx.x;
    int j = jb * 256 + t;
    int k0 = ks * DKC;

    __shared__ float xs[DKC];
    if (t < DKC) xs[t] = x[k0 + t];   // x0 = x row 0
    __syncthreads();

    float s = 0.f;
#pragma unroll 8
    for (int kk = 0; kk < DKC; ++kk)
        s += xs[kk] * Wp[(size_t)(k0 + kk) * D_ + j];
    partial[ks * D_ + j] = s;
}

__global__ __launch_bounds__(256) void disc_finish(
    const float* __restrict__ partial, const float* __restrict__ bp,
    const float* __restrict__ d1W, const float* __restrict__ d1b,
    const float* __restrict__ d2W, const float* __restrict__ d2b,
    float* __restrict__ out2)
{
    __shared__ float pool[D_];
    __shared__ float h1[20];
    int t = threadIdx.x;
    for (int j = t; j < D_; j += 256) {
        float s = bp[j];
#pragma unroll
        for (int ks = 0; ks < DKS; ++ks) s += partial[ks * D_ + j];
        pool[j] = tanhf(s);
    }
    __syncthreads();
    if (t < 20) {
        float s = d1b[t];
        for (int k = 0; k < D_; ++k) s += pool[k] * d1W[k * 20 + t];
        h1[t] = s;
    }
    __syncthreads();
    if (t == 0) {
        float d0 = d2b[0], d1v = d2b[1];
#pragma unroll
        for (int u = 0; u < 20; ++u) {
            d0  += h1[u] * d2W[u * 2 + 0];
            d1v += h1[u] * d2W[u * 2 + 1];
        }
        float m = fmaxf(d0, d1v);
        float e0 = __expf(d0 - m), e1 = __expf(d1v - m);
        float inv = 1.f / (e0 + e1);
        out2[0] = e0 * inv;
        out2[1] = e1 * inv;
    }
}

// ---------------------------------------------------------------------------
extern "C" void kernel_launch(void* const* d_in, const int* in_sizes, int n_in,
                              void* d_out, int out_size, void* d_ws, size_t ws_size,
                              hipStream_t stream)
{
    const int*   ids   = (const int*)d_in[0];
    const int*   kbi   = (const int*)d_in[1];
    const float* emb   = (const float*)d_in[2];
    const float* Wqkv  = (const float*)d_in[3];
    const float* bqkv  = (const float*)d_in[4];
    const float* Wo    = (const float*)d_in[5];
    const float* bo    = (const float*)d_in[6];
    const float* ln1g  = (const float*)d_in[7];
    const float* ln1b  = (const float*)d_in[8];
    const float* Wff1  = (const float*)d_in[9];
    const float* bff1  = (const float*)d_in[10];
    const float* Wff2  = (const float*)d_in[11];
    const float* bff2  = (const float*)d_in[12];
    const float* ln2g  = (const float*)d_in[13];
    const float* ln2b  = (const float*)d_in[14];
    const float* Wp    = (const float*)d_in[15];
    const float* bp    = (const float*)d_in[16];
    const float* sw    = (const float*)d_in[17];
    const float* ew    = (const float*)d_in[18];
    const float* d1W   = (const float*)d_in[19];
    const float* d1b   = (const float*)d_in[20];
    const float* d2W   = (const float*)d_in[21];
    const float* d2b   = (const float*)d_in[22];
    float* outp = (float*)d_out;

    // workspace carve (float units)
    float* ws   = (float*)d_ws;
    float* x    = ws;                          // BT_*D_ f32
    float* xbf  = x   + (size_t)BT_ * D_;      // f16 xb
    float* r1f  = xbf + (size_t)BT_ * D_ / 2;  // f16 qkv / f16 h
    float* abf  = r1f + (size_t)BT_ * FF_ / 2; // f16 attn out
    float* r2   = abf + (size_t)BT_ * D_ / 2;  // partials (early) / f16 g (late)
    float* wtf  = r2  + (size_t)BT_ * D_;      // f16 weights
    float* sl   = wtf + 7077888;
    float* el   = sl  + BT_;
    float* dpar = el  + BT_;                   // DKS * D_ disc partials

    _Float16* xb    = (_Float16*)xbf;
    _Float16* qkv16 = (_Float16*)r1f;
    _Float16* h16   = (_Float16*)r1f;
    _Float16* ab    = (_Float16*)abf;
    float* pm   = r2;
    float* pl   = r2 + NEDGE * NSPLIT * 16;
    float* pacc = pl + NEDGE * NSPLIT * 16;
    _Float16* g16 = (_Float16*)r2;   // aliased; partials dead once proj runs

    _Float16* Wt    = (_Float16*)wtf;
    _Float16* WqkvT = Wt;
    _Float16* WoT   = WqkvT + (size_t)2 * 2304 * 768;
    _Float16* Wff1T = WoT   + (size_t)2 * 768 * 768;
    _Float16* Wff2T = Wff1T + (size_t)2 * 3072 * 768;

    for (int l = 0; l < 2; ++l) {
        wconvert_kernel<<<dim3(2304/32, 768/32), 256, 0, stream>>>(
            Wqkv + (size_t)l * 768 * 2304, WqkvT + (size_t)l * 2304 * 768, 768, 2304);
        wconvert_kernel<<<dim3(768/32, 768/32), 256, 0, stream>>>(
            Wo + (size_t)l * 768 * 768, WoT + (size_t)l * 768 * 768, 768, 768);
        wconvert_kernel<<<dim3(3072/32, 768/32), 256, 0, stream>>>(
            Wff1 + (size_t)l * 768 * 3072, Wff1T + (size_t)l * 3072 * 768, 768, 3072);
        wconvert_kernel<<<dim3(768/32, 3072/32), 256, 0, stream>>>(
            Wff2 + (size_t)l * 3072 * 768, Wff2T + (size_t)l * 768 * 3072, 3072, 768);
    }

    embed_kernel<<<BT_, 256, 0, stream>>>(ids, emb, x, xb);

    for (int l = 0; l < 2; ++l) {
        gemm_f16<0,1><<<dim3(2304/128, BT_/128), 256, 0, stream>>>(
            xb, WqkvT + (size_t)l * 2304 * 768, bqkv + (size_t)l * 3 * D_,
            qkv16, BT_, 3 * D_, D_);
        attn_fused<<<NSPARSE + NEDGE * NSPLIT, 256, 0, stream>>>(
            qkv16, kbi, ab, pm, pl, pacc);
        attn_edge_combine<<<NEDGE, 256, 0, stream>>>(pm, pl, pacc, ab);
        gemm_f16<0,1><<<dim3(768/128, BT_/128), 256, 0, stream>>>(
            ab, WoT + (size_t)l * 768 * 768, bo + (size_t)l * D_,
            g16, BT_, D_, D_);
        add_ln_kernel<<<BT_, 256, 0, stream>>>(x, g16, ln1g + (size_t)l * D_, ln1b + (size_t)l * D_, xb);
        gemm_f16<1,1><<<dim3(3072/128, BT_/128), 256, 0, stream>>>(
            xb, Wff1T + (size_t)l * 3072 * 768, bff1 + (size_t)l * FF_,
            h16, BT_, FF_, D_);
        gemm_f16<0,1><<<dim3(768/128, BT_/128), 256, 0, stream>>>(
            h16, Wff2T + (size_t)l * 768 * 3072, bff2 + (size_t)l * D_,
            g16, BT_, D_, FF_);
        add_ln_kernel<<<BT_, 256, 0, stream>>>(x, g16, ln2g + (size_t)l * D_, ln2b + (size_t)l * D_, xb);
    }

    head_logits<<<BT_, 64, 0, stream>>>(x, sw, ew, sl, el);
    softmax_rows<<<4, 256, 0, stream>>>(sl, el, outp);
    disc_pool_partial<<<dim3(3, DKS), 256, 0, stream>>>(x, Wp, dpar);
    disc_finish<<<1, 256, 0, stream>>>(dpar, bp, d1W, d1b, d2W, d2b, outp + 2 * BT_);
}

// Round 15
// 727.652 us; speedup vs baseline: 1.0655x; 1.0272x over previous
//
#include <hip/hip_runtime.h>
#include <hip/hip_bf16.h>
#include <math.h>

#define B_   2
#define S_   4096
#define D_   768
#define H_   12
#define DH_  64
#define BS_  16
#define NB_  256
#define FF_  3072
#define BT_  (B_ * S_)          // 8192 token rows
#define SCALE_F 0.125f          // 1/sqrt(64)

#define NSPLIT 32               // key-dimension splits for edge attention
#define TILES_PER_SPLIT (NB_ / NSPLIT)   // 8
#define NEDGE (B_ * H_ * 2)     // 48 edge (b,h,e) groups
#define NSPARSE (B_ * H_ * NB_) // 6144 sparse blocks

#define DKS 8                   // disc pool k-splits
#define DKC (D_ / DKS)          // 96 rows per split

typedef _Float16 f16x8 __attribute__((ext_vector_type(8)));
typedef _Float16 f16x4 __attribute__((ext_vector_type(4)));
typedef _Float16 f16x2 __attribute__((ext_vector_type(2)));
typedef float    f32x4 __attribute__((ext_vector_type(4)));

#define SV2(v, k) __builtin_shufflevector(v, v, k, (k) + 1)

__device__ __forceinline__ float dot2acc(f16x2 a, f16x2 b, float c)
{
#if __has_builtin(__builtin_amdgcn_fdot2)
    return __builtin_amdgcn_fdot2(a, b, c, false);
#else
    return c + (float)a[0] * (float)b[0] + (float)a[1] * (float)b[1];
#endif
}

// async global->LDS, 16B per lane; LDS dest is wave-uniform base + lane*16
#define GLD16(gp, lp) __builtin_amdgcn_global_load_lds( \
    (const __attribute__((address_space(1))) void*)(gp), \
    (__attribute__((address_space(3))) void*)(lp), 16, 0, 0)

__device__ __forceinline__ float fast_tanh(float z)
{
    float az = fabsf(z);
    float t = __expf(-2.0f * az);
    float r = (1.0f - t) / (1.0f + t);
    return z < 0.f ? -r : r;
}

__device__ __forceinline__ float gelu_tanh(float v)
{
    float v3 = v * v * v;
    return 0.5f * v * (1.0f + fast_tanh(0.79788456080286535588f * (v + 0.044715f * v3)));
}

// ---------------------------------------------------------------------------
// Fused weight convert (r14): all 8 W fp32 [K][N] -> Wt f16 [N][K] in one
// dispatch. 32x32 tiles; 8-entry segment table passed by value.
// ---------------------------------------------------------------------------
struct WSeg { const float* src; _Float16* dst; int K; int N; int start; };
struct WSegs { WSeg s[8]; int total; };

__global__ __launch_bounds__(256) void wconvert_all(WSegs segs)
{
    __shared__ float tile[32][33];
    int bt = blockIdx.x;
    int si = 0;
#pragma unroll
    for (int u = 1; u < 8; ++u)
        if (bt >= segs.s[u].start) si = u;
    const WSeg& sg = segs.s[si];
    int tid = bt - sg.start;
    int tn = sg.N >> 5;
    int n0 = (tid % tn) * 32;
    int k0 = (tid / tn) * 32;

    int t = threadIdx.x;
    int r = t >> 5, c = t & 31;
#pragma unroll
    for (int rr = 0; rr < 32; rr += 8)
        tile[r + rr][c] = sg.src[(size_t)(k0 + r + rr) * sg.N + n0 + c];
    __syncthreads();
#pragma unroll
    for (int rr = 0; rr < 32; rr += 8)
        sg.dst[(size_t)(n0 + r + rr) * sg.K + k0 + c] = (_Float16)tile[c][r + rr];
}

// ---------------------------------------------------------------------------
// Embedding gather -> x fp32 and xb f16
// ---------------------------------------------------------------------------
__global__ __launch_bounds__(256) void embed_kernel(
    const int* __restrict__ ids, const float* __restrict__ emb,
    float* __restrict__ x, _Float16* __restrict__ xb)
{
    int row = blockIdx.x;
    int id = ids[row];
    const float* src = emb + (size_t)id * D_;
    float* dst = x + (size_t)row * D_;
    _Float16* dst16 = xb + (size_t)row * D_;
    for (int d = threadIdx.x; d < D_; d += 256) {
        float v = src[d];
        dst[d] = v;
        dst16[d] = (_Float16)v;
    }
}

// ---------------------------------------------------------------------------
// MFMA fp16 GEMM (r8-verified): C = A[M,K] @ Wt[N,K]^T + bias.
// 128x128 tile, BK=64, 4 waves, 4x4 frags. Chunk-XOR swizzle involution.
// ---------------------------------------------------------------------------
template<int ACT, int OUT16>
__global__ __launch_bounds__(256) void gemm_f16(
    const _Float16* __restrict__ A, const _Float16* __restrict__ Wt,
    const float* __restrict__ bias, void* __restrict__ Cp,
    int M, int N, int K)
{
    __shared__ __attribute__((aligned(16))) _Float16 As[128 * 64];
    __shared__ __attribute__((aligned(16))) _Float16 Bs[128 * 64];

    int t = threadIdx.x;
    int w = t >> 6, l = t & 63;
    int bm = blockIdx.y * 128, bn = blockIdx.x * 128;
    int wr = (w >> 1) * 64, wc = (w & 1) * 64;

    f32x4 acc[4][4];
#pragma unroll
    for (int i = 0; i < 4; ++i)
#pragma unroll
        for (int j = 0; j < 4; ++j) acc[i][j] = (f32x4){0.f, 0.f, 0.f, 0.f};

    const _Float16* gA[4];
    const _Float16* gB[4];
#pragma unroll
    for (int q = 0; q < 4; ++q) {
        int m = w * 4 + q;
        int row = m * 8 + (l >> 3);
        int sc = (l & 7) ^ (row & 7);
        gA[q] = A  + (size_t)(bm + row) * K + sc * 8;
        gB[q] = Wt + (size_t)(bn + row) * K + sc * 8;
    }

    int aoff[2][4], boff[2][4];
#pragma unroll
    for (int kk = 0; kk < 2; ++kk)
#pragma unroll
        for (int i = 0; i < 4; ++i) {
            int ar = wr + i * 16 + (l & 15);
            int ch = (kk * 4 + (l >> 4)) ^ (l & 7);
            aoff[kk][i] = ar * 64 + ch * 8;
            int br = wc + i * 16 + (l & 15);
            boff[kk][i] = br * 64 + ch * 8;
        }

    for (int k0 = 0; k0 < K; k0 += 64) {
#pragma unroll
        for (int q = 0; q < 4; ++q) {
            int m = w * 4 + q;
            GLD16(gA[q] + k0, As + m * 512);
            GLD16(gB[q] + k0, Bs + m * 512);
        }
        __syncthreads();

        f16x8 af[2][4], bf[2][4];
#pragma unroll
        for (int kk = 0; kk < 2; ++kk)
#pragma unroll
            for (int i = 0; i < 4; ++i) {
                af[kk][i] = *(const f16x8*)(As + aoff[kk][i]);
                bf[kk][i] = *(const f16x8*)(Bs + boff[kk][i]);
            }
#pragma unroll
        for (int kk = 0; kk < 2; ++kk)
#pragma unroll
            for (int i = 0; i < 4; ++i)
#pragma unroll
                for (int j = 0; j < 4; ++j)
                    acc[i][j] = __builtin_amdgcn_mfma_f32_16x16x32_f16(
                        af[kk][i], bf[kk][j], acc[i][j], 0, 0, 0);
        __syncthreads();
    }

#pragma unroll
    for (int i = 0; i < 4; ++i) {
        int rowb = bm + wr + i * 16 + ((l >> 4) << 2);
#pragma unroll
        for (int j = 0; j < 4; ++j) {
            int col = bn + wc + j * 16 + (l & 15);
            float bv = bias[col];
#pragma unroll
            for (int r = 0; r < 4; ++r) {
                float v = acc[i][j][r] + bv;
                if (ACT) v = gelu_tanh(v);
                if (OUT16)
                    ((_Float16*)Cp)[(size_t)(rowb + r) * N + col] = (_Float16)v;
                else
                    ((float*)Cp)[(size_t)(rowb + r) * N + col] = v;
            }
        }
    }
}

// ---------------------------------------------------------------------------
// Attention core: double-buffered K/V LDS (1 barrier/tile), 2-deep register
// prefetch, unroll-1 (r7 lesson), PV p-broadcast via LDS (r12 win).
// ---------------------------------------------------------------------------
template<int NT, bool EDGE>
__device__ __forceinline__ void attn_block(
    const _Float16* __restrict__ qkv, const int* __restrict__ key_idx,
    _Float16* __restrict__ outp, float* __restrict__ pm,
    float* __restrict__ pl, float* __restrict__ pacc,
    int b, int h, int n, int split, int be,
    _Float16 (*qs)[72], _Float16 (*ks)[16][72], float (*vs)[16][68],
    float (*ps)[20])
{
    int t = threadIdx.x;
    int i = t >> 4;        // query row / staging row
    int c = t & 15;
    int c4 = c * 4;

    *(f16x4*)&qs[i][c4] =
        *(const f16x4*)&qkv[((size_t)(b * S_ + n * BS_ + i)) * (3 * D_) + h * DH_ + c4];
    int kb0 = EDGE ? split * NT : key_idx[n * 7];
    const _Float16* kp0 = qkv + ((size_t)(b * S_ + kb0 * BS_ + i)) * (3 * D_) + D_ + h * DH_;
    f16x4 kr = *(const f16x4*)(kp0 + c4);
    f16x4 vr = *(const f16x4*)(kp0 + D_ + c4);
    __syncthreads();   // qs visible

    f16x8 qv[8];
#pragma unroll
    for (int d0 = 0; d0 < 8; ++d0) qv[d0] = *(const f16x8*)&qs[i][d0 * 8];

    *(f16x4*)&ks[0][i][c4] = kr;
    {
        f32x4 vf = {(float)vr[0], (float)vr[1], (float)vr[2], (float)vr[3]};
        *(f32x4*)&vs[0][i][c4] = vf;
    }
    if (NT > 1) {
        int kb1 = EDGE ? (split * NT + 1) : key_idx[n * 7 + 1];
        const _Float16* kp1 = qkv + ((size_t)(b * S_ + kb1 * BS_ + i)) * (3 * D_) + D_ + h * DH_;
        kr = *(const f16x4*)(kp1 + c4);
        vr = *(const f16x4*)(kp1 + D_ + c4);
    }
    __syncthreads();   // buffer 0 staged

    float m_old = -1e30f, lsum = 0.f;
    float acc0 = 0.f, acc1 = 0.f, acc2 = 0.f, acc3 = 0.f;

#pragma unroll 1
    for (int jj = 0; jj < NT; ++jj) {
        int cur = jj & 1;
        if (jj + 1 < NT) {
            *(f16x4*)&ks[cur ^ 1][i][c4] = kr;
            f32x4 vf = {(float)vr[0], (float)vr[1], (float)vr[2], (float)vr[3]};
            *(f32x4*)&vs[cur ^ 1][i][c4] = vf;
        }
        if (jj + 2 < NT) {
            int kb2 = EDGE ? (split * NT + jj + 2) : key_idx[n * 7 + jj + 2];
            const _Float16* kp2 = qkv + ((size_t)(b * S_ + kb2 * BS_ + i)) * (3 * D_) + D_ + h * DH_;
            kr = *(const f16x4*)(kp2 + c4);
            vr = *(const f16x4*)(kp2 + D_ + c4);
        }

        float s0 = 0.f, s1 = 0.f;
#pragma unroll
        for (int d0 = 0; d0 < 8; ++d0) {
            f16x8 kv = *(const f16x8*)&ks[cur][c][d0 * 8];
            s0 = dot2acc(SV2(qv[d0], 0), SV2(kv, 0), s0);
            s1 = dot2acc(SV2(qv[d0], 2), SV2(kv, 2), s1);
            s0 = dot2acc(SV2(qv[d0], 4), SV2(kv, 4), s0);
            s1 = dot2acc(SV2(qv[d0], 6), SV2(kv, 6), s1);
        }
        float s = (s0 + s1) * SCALE_F;

        float rm = s;
#pragma unroll
        for (int off = 8; off; off >>= 1) rm = fmaxf(rm, __shfl_xor(rm, off, 64));
        float m_new = fmaxf(m_old, rm);
        float p = __expf(s - m_new);
        float rs = p;
#pragma unroll
        for (int off = 8; off; off >>= 1) rs += __shfl_xor(rs, off, 64);
        float corr = __expf(m_old - m_new);
        lsum = lsum * corr + rs;
        acc0 *= corr; acc1 *= corr; acc2 *= corr; acc3 *= corr;

        ps[i][c] = p;
        float parr[16];
        *(f32x4*)&parr[0]  = *(const f32x4*)&ps[i][0];
        *(f32x4*)&parr[4]  = *(const f32x4*)&ps[i][4];
        *(f32x4*)&parr[8]  = *(const f32x4*)&ps[i][8];
        *(f32x4*)&parr[12] = *(const f32x4*)&ps[i][12];
#pragma unroll
        for (int j = 0; j < 16; ++j) {
            f32x4 vv = *(const f32x4*)&vs[cur][j][c4];
            acc0 += parr[j] * vv[0];
            acc1 += parr[j] * vv[1];
            acc2 += parr[j] * vv[2];
            acc3 += parr[j] * vv[3];
        }
        m_old = m_new;
        __syncthreads();
    }

    if (EDGE) {
        int psx = (be * NSPLIT + split) * 16 + i;
        if (c == 0) { pm[psx] = m_old; pl[psx] = lsum; }
        float* pd = pacc + (size_t)psx * 64 + c4;
        pd[0] = acc0; pd[1] = acc1; pd[2] = acc2; pd[3] = acc3;
    } else {
        float inv = 1.f / lsum;
        _Float16* dst = outp + ((size_t)(b * S_ + n * BS_ + i)) * D_ + h * DH_ + c4;
        dst[0] = (_Float16)(acc0 * inv);
        dst[1] = (_Float16)(acc1 * inv);
        dst[2] = (_Float16)(acc2 * inv);
        dst[3] = (_Float16)(acc3 * inv);
    }
}

// ---------------------------------------------------------------------------
// Fused attention dispatch (r13): sparse + edge split-K in one grid.
// ---------------------------------------------------------------------------
__global__ __launch_bounds__(256) void attn_fused(
    const _Float16* __restrict__ qkv, const int* __restrict__ key_idx,
    _Float16* __restrict__ outp, float* __restrict__ pm,
    float* __restrict__ pl, float* __restrict__ pacc)
{
    __shared__ __attribute__((aligned(16))) _Float16 qs[16][72];
    __shared__ __attribute__((aligned(16))) _Float16 ks[2][16][72];
    __shared__ __attribute__((aligned(16))) float    vs[2][16][68];
    __shared__ __attribute__((aligned(16))) float    ps[16][20];

    int bi = blockIdx.x;
    if (bi < NSPARSE) {
        int n = bi % NB_;
        if (n == 0 || n == NB_ - 1) return;
        int h = (bi / NB_) % H_;
        int b = bi / (NB_ * H_);
        attn_block<7, false>(qkv, key_idx, outp, nullptr, nullptr, nullptr,
                             b, h, n, 0, 0, qs, ks, vs, ps);
    } else {
        int ei = bi - NSPARSE;
        int split = ei % NSPLIT;
        int be = ei / NSPLIT;
        int e = be & 1;
        int h = (be >> 1) % H_;
        int b = be / (2 * H_);
        int n = e ? (NB_ - 1) : 0;
        attn_block<TILES_PER_SPLIT, true>(qkv, nullptr, nullptr, pm, pl, pacc,
                                          b, h, n, split, be, qs, ks, vs, ps);
    }
}

// ---------------------------------------------------------------------------
// Edge attention combine
// ---------------------------------------------------------------------------
__global__ __launch_bounds__(256) void attn_edge_combine(
    const float* __restrict__ pm, const float* __restrict__ pl,
    const float* __restrict__ pacc, _Float16* __restrict__ outp)
{
    int be = blockIdx.x;
    int e = be & 1;
    int h = (be >> 1) % H_;
    int b = be / (2 * H_);
    int n = e ? (NB_ - 1) : 0;

    int t = threadIdx.x;
    int i = t >> 4;
    int c = t & 15;

    float M = -1e30f;
#pragma unroll 4
    for (int s = 0; s < NSPLIT; ++s)
        M = fmaxf(M, pm[(be * NSPLIT + s) * 16 + i]);

    float L = 0.f;
    float acc[4] = {0.f, 0.f, 0.f, 0.f};
    for (int s = 0; s < NSPLIT; ++s) {
        int ps = (be * NSPLIT + s) * 16 + i;
        float wgt = __expf(pm[ps] - M);
        L += pl[ps] * wgt;
#pragma unroll
        for (int u = 0; u < 4; ++u) acc[u] += pacc[(size_t)ps * 64 + c * 4 + u] * wgt;
    }

    float inv = 1.f / L;
    _Float16* dst = outp + ((size_t)(b * S_ + n * BS_ + i)) * D_ + h * DH_ + c * 4;
#pragma unroll
    for (int u = 0; u < 4; ++u) dst[u] = (_Float16)(acc[u] * inv);
}

// ---------------------------------------------------------------------------
// x = LayerNorm(x + g); g is f16; writes fp32 x and f16 xb
// ---------------------------------------------------------------------------
__global__ __launch_bounds__(256) void add_ln_kernel(
    float* __restrict__ x, const _Float16* __restrict__ g,
    const float* __restrict__ gamma, const float* __restrict__ beta,
    _Float16* __restrict__ xb)
{
    int row = blockIdx.x;
    int t = threadIdx.x;
    float* xr = x + (size_t)row * D_;
    const _Float16* gr = g + (size_t)row * D_;
    _Float16* br = xb + (size_t)row * D_;

    float v[3];
    float s = 0.f, s2 = 0.f;
#pragma unroll
    for (int r = 0; r < 3; ++r) {
        int d = t + 256 * r;
        v[r] = xr[d] + (float)gr[d];
        s += v[r];
        s2 += v[r] * v[r];
    }
#pragma unroll
    for (int off = 32; off; off >>= 1) {
        s  += __shfl_xor(s, off, 64);
        s2 += __shfl_xor(s2, off, 64);
    }
    __shared__ float sA[4], sB[4];
    int wave = t >> 6, lane = t & 63;
    if (lane == 0) { sA[wave] = s; sB[wave] = s2; }
    __syncthreads();
    s  = sA[0] + sA[1] + sA[2] + sA[3];
    s2 = sB[0] + sB[1] + sB[2] + sB[3];
    float mean = s * (1.0f / D_);
    float var = s2 * (1.0f / D_) - mean * mean;
    float rstd = rsqrtf(var + 1e-12f);
#pragma unroll
    for (int r = 0; r < 3; ++r) {
        int d = t + 256 * r;
        float o = (v[r] - mean) * rstd * gamma[d] + beta[d];
        xr[d] = o;
        br[d] = (_Float16)o;
    }
}

// ---------------------------------------------------------------------------
// Fused heads (r14): blockIdx < 2048 -> start/end logits (4 rows per block,
// one 64-lane wave each); else -> disc pool partial (24 blocks).
// ---------------------------------------------------------------------------
__global__ __launch_bounds__(256) void heads_fused(
    const float* __restrict__ x, const float* __restrict__ sw,
    const float* __restrict__ ew, const float* __restrict__ Wp,
    float* __restrict__ sl, float* __restrict__ el,
    float* __restrict__ partial)
{
    int bi = blockIdx.x;
    int t = threadIdx.x;
    if (bi < 2048) {
        int wave = t >> 6, lane = t & 63;
        int row = bi * 4 + wave;
        const float* xr = x + (size_t)row * D_;
        float a = 0.f, e = 0.f;
        for (int d = lane; d < D_; d += 64) {
            float xv = xr[d];
            a += xv * sw[d];
            e += xv * ew[d];
        }
#pragma unroll
        for (int off = 32; off; off >>= 1) {
            a += __shfl_xor(a, off, 64);
            e += __shfl_xor(e, off, 64);
        }
        if (lane == 0) { sl[row] = a; el[row] = e; }
    } else {
        int ei = bi - 2048;       // 0..23
        int jb = ei % 3;          // 0..2
        int ks = ei / 3;          // 0..7
        int j = jb * 256 + t;
        int k0 = ks * DKC;

        __shared__ float xs[DKC];
        if (t < DKC) xs[t] = x[k0 + t];   // x0 = x row 0
        __syncthreads();

        float s = 0.f;
#pragma unroll 8
        for (int kk = 0; kk < DKC; ++kk)
            s += xs[kk] * Wp[(size_t)(k0 + kk) * D_ + j];
        partial[ks * D_ + j] = s;
    }
}

// ---------------------------------------------------------------------------
// Fused final (r14): r<4 -> softmax over S; r==4 -> disc finish.
// ---------------------------------------------------------------------------
__global__ __launch_bounds__(256) void final_fused(
    const float* __restrict__ sl, const float* __restrict__ el,
    const float* __restrict__ partial, const float* __restrict__ bp,
    const float* __restrict__ d1W, const float* __restrict__ d1b,
    const float* __restrict__ d2W, const float* __restrict__ d2b,
    float* __restrict__ outp)
{
    int r = blockIdx.x;
    int t = threadIdx.x;
    if (r < 4) {
        const float* src = (r < 2 ? sl : el) + (size_t)(r & 1) * S_;
        float* dst = outp + (r < 2 ? 0 : BT_) + (size_t)(r & 1) * S_;
        int wave = t >> 6, lane = t & 63;
        __shared__ float sm[4], ss[4];

        float m = -1e30f;
        for (int k = t; k < S_; k += 256) m = fmaxf(m, src[k]);
#pragma unroll
        for (int off = 32; off; off >>= 1) m = fmaxf(m, __shfl_xor(m, off, 64));
        if (lane == 0) sm[wave] = m;
        __syncthreads();
        m = fmaxf(fmaxf(sm[0], sm[1]), fmaxf(sm[2], sm[3]));

        float s = 0.f;
        for (int k = t; k < S_; k += 256) s += __expf(src[k] - m);
#pragma unroll
        for (int off = 32; off; off >>= 1) s += __shfl_xor(s, off, 64);
        if (lane == 0) ss[wave] = s;
        __syncthreads();
        s = ss[0] + ss[1] + ss[2] + ss[3];

        float inv = 1.f / s;
        for (int k = t; k < S_; k += 256) dst[k] = __expf(src[k] - m) * inv;
    } else {
        __shared__ float pool[D_];
        __shared__ float h1[20];
        float* out2 = outp + 2 * BT_;
        for (int j = t; j < D_; j += 256) {
            float s = bp[j];
#pragma unroll
            for (int ks = 0; ks < DKS; ++ks) s += partial[ks * D_ + j];
            pool[j] = tanhf(s);
        }
        __syncthreads();
        if (t < 20) {
            float s = d1b[t];
            for (int k = 0; k < D_; ++k) s += pool[k] * d1W[k * 20 + t];
            h1[t] = s;
        }
        __syncthreads();
        if (t == 0) {
            float d0 = d2b[0], d1v = d2b[1];
#pragma unroll
            for (int u = 0; u < 20; ++u) {
                d0  += h1[u] * d2W[u * 2 + 0];
                d1v += h1[u] * d2W[u * 2 + 1];
            }
            float m = fmaxf(d0, d1v);
            float e0 = __expf(d0 - m), e1 = __expf(d1v - m);
            float inv = 1.f / (e0 + e1);
            out2[0] = e0 * inv;
            out2[1] = e1 * inv;
        }
    }
}

// ---------------------------------------------------------------------------
extern "C" void kernel_launch(void* const* d_in, const int* in_sizes, int n_in,
                              void* d_out, int out_size, void* d_ws, size_t ws_size,
                              hipStream_t stream)
{
    const int*   ids   = (const int*)d_in[0];
    const int*   kbi   = (const int*)d_in[1];
    const float* emb   = (const float*)d_in[2];
    const float* Wqkv  = (const float*)d_in[3];
    const float* bqkv  = (const float*)d_in[4];
    const float* Wo    = (const float*)d_in[5];
    const float* bo    = (const float*)d_in[6];
    const float* ln1g  = (const float*)d_in[7];
    const float* ln1b  = (const float*)d_in[8];
    const float* Wff1  = (const float*)d_in[9];
    const float* bff1  = (const float*)d_in[10];
    const float* Wff2  = (const float*)d_in[11];
    const float* bff2  = (const float*)d_in[12];
    const float* ln2g  = (const float*)d_in[13];
    const float* ln2b  = (const float*)d_in[14];
    const float* Wp    = (const float*)d_in[15];
    const float* bp    = (const float*)d_in[16];
    const float* sw    = (const float*)d_in[17];
    const float* ew    = (const float*)d_in[18];
    const float* d1W   = (const float*)d_in[19];
    const float* d1b   = (const float*)d_in[20];
    const float* d2W   = (const float*)d_in[21];
    const float* d2b   = (const float*)d_in[22];
    float* outp = (float*)d_out;

    // workspace carve (float units)
    float* ws   = (float*)d_ws;
    float* x    = ws;                          // BT_*D_ f32
    float* xbf  = x   + (size_t)BT_ * D_;      // f16 xb
    float* r1f  = xbf + (size_t)BT_ * D_ / 2;  // f16 qkv / f16 h
    float* abf  = r1f + (size_t)BT_ * FF_ / 2; // f16 attn out
    float* r2   = abf + (size_t)BT_ * D_ / 2;  // partials (early) / f16 g (late)
    float* wtf  = r2  + (size_t)BT_ * D_;      // f16 weights
    float* sl   = wtf + 7077888;
    float* el   = sl  + BT_;
    float* dpar = el  + BT_;                   // DKS * D_ disc partials

    _Float16* xb    = (_Float16*)xbf;
    _Float16* qkv16 = (_Float16*)r1f;
    _Float16* h16   = (_Float16*)r1f;
    _Float16* ab    = (_Float16*)abf;
    float* pm   = r2;
    float* pl   = r2 + NEDGE * NSPLIT * 16;
    float* pacc = pl + NEDGE * NSPLIT * 16;
    _Float16* g16 = (_Float16*)r2;   // aliased; partials dead once proj runs

    _Float16* Wt    = (_Float16*)wtf;
    _Float16* WqkvT = Wt;
    _Float16* WoT   = WqkvT + (size_t)2 * 2304 * 768;
    _Float16* Wff1T = WoT   + (size_t)2 * 768 * 768;
    _Float16* Wff2T = Wff1T + (size_t)2 * 3072 * 768;

    // fused weight convert: 8 segments, one dispatch
    WSegs segs;
    int start = 0;
    for (int l = 0; l < 2; ++l) {
        int base = l * 4;
        segs.s[base + 0] = { Wqkv + (size_t)l * 768 * 2304,
                             WqkvT + (size_t)l * 2304 * 768, 768, 2304, start };
        start += (2304 / 32) * (768 / 32);
        segs.s[base + 1] = { Wo + (size_t)l * 768 * 768,
                             WoT + (size_t)l * 768 * 768, 768, 768, start };
        start += (768 / 32) * (768 / 32);
        segs.s[base + 2] = { Wff1 + (size_t)l * 768 * 3072,
                             Wff1T + (size_t)l * 3072 * 768, 768, 3072, start };
        start += (3072 / 32) * (768 / 32);
        segs.s[base + 3] = { Wff2 + (size_t)l * 3072 * 768,
                             Wff2T + (size_t)l * 768 * 3072, 3072, 768, start };
        start += (768 / 32) * (3072 / 32);
    }
    segs.total = start;   // 13824

    wconvert_all<<<segs.total, 256, 0, stream>>>(segs);
    embed_kernel<<<BT_, 256, 0, stream>>>(ids, emb, x, xb);

    for (int l = 0; l < 2; ++l) {
        gemm_f16<0,1><<<dim3(2304/128, BT_/128), 256, 0, stream>>>(
            xb, WqkvT + (size_t)l * 2304 * 768, bqkv + (size_t)l * 3 * D_,
            qkv16, BT_, 3 * D_, D_);
        attn_fused<<<NSPARSE + NEDGE * NSPLIT, 256, 0, stream>>>(
            qkv16, kbi, ab, pm, pl, pacc);
        attn_edge_combine<<<NEDGE, 256, 0, stream>>>(pm, pl, pacc, ab);
        gemm_f16<0,1><<<dim3(768/128, BT_/128), 256, 0, stream>>>(
            ab, WoT + (size_t)l * 768 * 768, bo + (size_t)l * D_,
            g16, BT_, D_, D_);
        add_ln_kernel<<<BT_, 256, 0, stream>>>(x, g16, ln1g + (size_t)l * D_, ln1b + (size_t)l * D_, xb);
        gemm_f16<1,1><<<dim3(3072/128, BT_/128), 256, 0, stream>>>(
            xb, Wff1T + (size_t)l * 3072 * 768, bff1 + (size_t)l * FF_,
            h16, BT_, FF_, D_);
        gemm_f16<0,1><<<dim3(768/128, BT_/128), 256, 0, stream>>>(
            h16, Wff2T + (size_t)l * 768 * 3072, bff2 + (size_t)l * D_,
            g16, BT_, D_, FF_);
        add_ln_kernel<<<BT_, 256, 0, stream>>>(x, g16, ln2g + (size_t)l * D_, ln2b + (size_t)l * D_, xb);
    }

    heads_fused<<<2048 + 3 * DKS, 256, 0, stream>>>(x, sw, ew, Wp, sl, el, dpar);
    final_fused<<<5, 256, 0, stream>>>(sl, el, dpar, bp, d1W, d1b, d2W, d2b, outp);
}

// Round 17
// 700.031 us; speedup vs baseline: 1.1076x; 1.0395x over previous
//
#include <hip/hip_runtime.h>
#include <hip/hip_bf16.h>
#include <math.h>

#define B_   2
#define S_   4096
#define D_   768
#define H_   12
#define DH_  64
#define BS_  16
#define NB_  256
#define FF_  3072
#define BT_  (B_ * S_)          // 8192 token rows
#define SCALE_F 0.125f          // 1/sqrt(64)

#define NSPLIT 32               // key-dimension splits for edge attention
#define TILES_PER_SPLIT (NB_ / NSPLIT)   // 8
#define NEDGE (B_ * H_ * 2)     // 48 edge (b,h,e) groups
#define NSPARSE (B_ * H_ * NB_) // 6144 sparse blocks

#define DKS 8                   // disc pool k-splits
#define DKC (D_ / DKS)          // 96 rows per split

typedef _Float16 f16x8 __attribute__((ext_vector_type(8)));
typedef _Float16 f16x4 __attribute__((ext_vector_type(4)));
typedef _Float16 f16x2 __attribute__((ext_vector_type(2)));
typedef float    f32x4 __attribute__((ext_vector_type(4)));

#define SV2(v, k) __builtin_shufflevector(v, v, k, (k) + 1)

__device__ __forceinline__ float dot2acc(f16x2 a, f16x2 b, float c)
{
#if __has_builtin(__builtin_amdgcn_fdot2)
    return __builtin_amdgcn_fdot2(a, b, c, false);
#else
    return c + (float)a[0] * (float)b[0] + (float)a[1] * (float)b[1];
#endif
}

// async global->LDS, 16B per lane; LDS dest is wave-uniform base + lane*16
#define GLD16(gp, lp) __builtin_amdgcn_global_load_lds( \
    (const __attribute__((address_space(1))) void*)(gp), \
    (__attribute__((address_space(3))) void*)(lp), 16, 0, 0)

__device__ __forceinline__ float fast_tanh(float z)
{
    float az = fabsf(z);
    float t = __expf(-2.0f * az);
    float r = (1.0f - t) / (1.0f + t);
    return z < 0.f ? -r : r;
}

__device__ __forceinline__ float gelu_tanh(float v)
{
    float v3 = v * v * v;
    return 0.5f * v * (1.0f + fast_tanh(0.79788456080286535588f * (v + 0.044715f * v3)));
}

// ---------------------------------------------------------------------------
// Fused weight convert: all 8 W fp32 [K][N] -> Wt f16 [N][K] in one dispatch.
// ---------------------------------------------------------------------------
struct WSeg { const float* src; _Float16* dst; int K; int N; int start; };
struct WSegs { WSeg s[8]; int total; };

__global__ __launch_bounds__(256) void wconvert_all(WSegs segs)
{
    __shared__ float tile[32][33];
    int bt = blockIdx.x;
    int si = 0;
#pragma unroll
    for (int u = 1; u < 8; ++u)
        if (bt >= segs.s[u].start) si = u;
    const WSeg& sg = segs.s[si];
    int tid = bt - sg.start;
    int tn = sg.N >> 5;
    int n0 = (tid % tn) * 32;
    int k0 = (tid / tn) * 32;

    int t = threadIdx.x;
    int r = t >> 5, c = t & 31;
#pragma unroll
    for (int rr = 0; rr < 32; rr += 8)
        tile[r + rr][c] = sg.src[(size_t)(k0 + r + rr) * sg.N + n0 + c];
    __syncthreads();
#pragma unroll
    for (int rr = 0; rr < 32; rr += 8)
        sg.dst[(size_t)(n0 + r + rr) * sg.K + k0 + c] = (_Float16)tile[c][r + rr];
}

// ---------------------------------------------------------------------------
// Embedding gather -> x fp32 and xb f16
// ---------------------------------------------------------------------------
__global__ __launch_bounds__(256) void embed_kernel(
    const int* __restrict__ ids, const float* __restrict__ emb,
    float* __restrict__ x, _Float16* __restrict__ xb)
{
    int row = blockIdx.x;
    int id = ids[row];
    const float* src = emb + (size_t)id * D_;
    float* dst = x + (size_t)row * D_;
    _Float16* dst16 = xb + (size_t)row * D_;
    for (int d = threadIdx.x; d < D_; d += 256) {
        float v = src[d];
        dst[d] = v;
        dst16[d] = (_Float16)v;
    }
}

// ---------------------------------------------------------------------------
// MFMA fp16 GEMM (r8-verified): C = A[M,K] @ Wt[N,K]^T + bias.
// 128x128 tile, BK=64, 4 waves, 4x4 frags. Chunk-XOR swizzle involution.
// ---------------------------------------------------------------------------
template<int ACT, int OUT16>
__global__ __launch_bounds__(256) void gemm_f16(
    const _Float16* __restrict__ A, const _Float16* __restrict__ Wt,
    const float* __restrict__ bias, void* __restrict__ Cp,
    int M, int N, int K)
{
    __shared__ __attribute__((aligned(16))) _Float16 As[128 * 64];
    __shared__ __attribute__((aligned(16))) _Float16 Bs[128 * 64];

    int t = threadIdx.x;
    int w = t >> 6, l = t & 63;
    int bm = blockIdx.y * 128, bn = blockIdx.x * 128;
    int wr = (w >> 1) * 64, wc = (w & 1) * 64;

    f32x4 acc[4][4];
#pragma unroll
    for (int i = 0; i < 4; ++i)
#pragma unroll
        for (int j = 0; j < 4; ++j) acc[i][j] = (f32x4){0.f, 0.f, 0.f, 0.f};

    const _Float16* gA[4];
    const _Float16* gB[4];
#pragma unroll
    for (int q = 0; q < 4; ++q) {
        int m = w * 4 + q;
        int row = m * 8 + (l >> 3);
        int sc = (l & 7) ^ (row & 7);
        gA[q] = A  + (size_t)(bm + row) * K + sc * 8;
        gB[q] = Wt + (size_t)(bn + row) * K + sc * 8;
    }

    int aoff[2][4], boff[2][4];
#pragma unroll
    for (int kk = 0; kk < 2; ++kk)
#pragma unroll
        for (int i = 0; i < 4; ++i) {
            int ar = wr + i * 16 + (l & 15);
            int ch = (kk * 4 + (l >> 4)) ^ (l & 7);
            aoff[kk][i] = ar * 64 + ch * 8;
            int br = wc + i * 16 + (l & 15);
            boff[kk][i] = br * 64 + ch * 8;
        }

    for (int k0 = 0; k0 < K; k0 += 64) {
#pragma unroll
        for (int q = 0; q < 4; ++q) {
            int m = w * 4 + q;
            GLD16(gA[q] + k0, As + m * 512);
            GLD16(gB[q] + k0, Bs + m * 512);
        }
        __syncthreads();

        f16x8 af[2][4], bf[2][4];
#pragma unroll
        for (int kk = 0; kk < 2; ++kk)
#pragma unroll
            for (int i = 0; i < 4; ++i) {
                af[kk][i] = *(const f16x8*)(As + aoff[kk][i]);
                bf[kk][i] = *(const f16x8*)(Bs + boff[kk][i]);
            }
#pragma unroll
        for (int kk = 0; kk < 2; ++kk)
#pragma unroll
            for (int i = 0; i < 4; ++i)
#pragma unroll
                for (int j = 0; j < 4; ++j)
                    acc[i][j] = __builtin_amdgcn_mfma_f32_16x16x32_f16(
                        af[kk][i], bf[kk][j], acc[i][j], 0, 0, 0);
        __syncthreads();
    }

#pragma unroll
    for (int i = 0; i < 4; ++i) {
        int rowb = bm + wr + i * 16 + ((l >> 4) << 2);
#pragma unroll
        for (int j = 0; j < 4; ++j) {
            int col = bn + wc + j * 16 + (l & 15);
            float bv = bias[col];
#pragma unroll
            for (int r = 0; r < 4; ++r) {
                float v = acc[i][j][r] + bv;
                if (ACT) v = gelu_tanh(v);
                if (OUT16)
                    ((_Float16*)Cp)[(size_t)(rowb + r) * N + col] = (_Float16)v;
                else
                    ((float*)Cp)[(size_t)(rowb + r) * N + col] = v;
            }
        }
    }
}

// ---------------------------------------------------------------------------
// Attention core (r15/r16): K double-buffered f16 LDS; V staged j-PAIRED f16
// (vpl[buf][jp][d][2]) so PV runs on fdot2 (32 ops vs 64 FMA) with 8 aligned
// b128 reads; p broadcast via f16 LDS. Softmax statistics stay fp32.
// r16 fix: PV steps expanded via macro with LITERAL shuffle indices
// (__builtin_shufflevector requires compile-time constants).
// ---------------------------------------------------------------------------
template<int NT, bool EDGE>
__device__ __forceinline__ void attn_block(
    const _Float16* __restrict__ qkv, const int* __restrict__ key_idx,
    _Float16* __restrict__ outp, float* __restrict__ pm,
    float* __restrict__ pl, float* __restrict__ pacc,
    int b, int h, int n, int split, int be,
    _Float16 (*qs)[72], _Float16 (*ks)[16][72],
    _Float16 (*vpl)[8][64][2], _Float16 (*ps16)[24])
{
    int t = threadIdx.x;
    int i = t >> 4;        // query row / staging row
    int c = t & 15;
    int c4 = c * 4;

    // stage Q tile; load tile 0 into registers
    *(f16x4*)&qs[i][c4] =
        *(const f16x4*)&qkv[((size_t)(b * S_ + n * BS_ + i)) * (3 * D_) + h * DH_ + c4];
    int kb0 = EDGE ? split * NT : key_idx[n * 7];
    const _Float16* kp0 = qkv + ((size_t)(b * S_ + kb0 * BS_ + i)) * (3 * D_) + D_ + h * DH_;
    f16x4 kr = *(const f16x4*)(kp0 + c4);
    f16x4 vr = *(const f16x4*)(kp0 + D_ + c4);
    __syncthreads();   // qs visible

    f16x8 qv[8];
#pragma unroll
    for (int d0 = 0; d0 < 8; ++d0) qv[d0] = *(const f16x8*)&qs[i][d0 * 8];

    // write tile 0 into buffer 0; prefetch tile 1
    *(f16x4*)&ks[0][i][c4] = kr;
#pragma unroll
    for (int u = 0; u < 4; ++u) vpl[0][i >> 1][c4 + u][i & 1] = vr[u];
    if (NT > 1) {
        int kb1 = EDGE ? (split * NT + 1) : key_idx[n * 7 + 1];
        const _Float16* kp1 = qkv + ((size_t)(b * S_ + kb1 * BS_ + i)) * (3 * D_) + D_ + h * DH_;
        kr = *(const f16x4*)(kp1 + c4);
        vr = *(const f16x4*)(kp1 + D_ + c4);
    }
    __syncthreads();   // buffer 0 staged

    float m_old = -1e30f, lsum = 0.f;
    float acc0 = 0.f, acc1 = 0.f, acc2 = 0.f, acc3 = 0.f;

#pragma unroll 1
    for (int jj = 0; jj < NT; ++jj) {
        int cur = jj & 1;
        if (jj + 1 < NT) {
            *(f16x4*)&ks[cur ^ 1][i][c4] = kr;
#pragma unroll
            for (int u = 0; u < 4; ++u) vpl[cur ^ 1][i >> 1][c4 + u][i & 1] = vr[u];
        }
        if (jj + 2 < NT) {
            int kb2 = EDGE ? (split * NT + jj + 2) : key_idx[n * 7 + jj + 2];
            const _Float16* kp2 = qkv + ((size_t)(b * S_ + kb2 * BS_ + i)) * (3 * D_) + D_ + h * DH_;
            kr = *(const f16x4*)(kp2 + c4);
            vr = *(const f16x4*)(kp2 + D_ + c4);
        }

        // score: <q_i, k_c> via fdot2 over b128 LDS reads
        float s0 = 0.f, s1 = 0.f;
#pragma unroll
        for (int d0 = 0; d0 < 8; ++d0) {
            f16x8 kv = *(const f16x8*)&ks[cur][c][d0 * 8];
            s0 = dot2acc(SV2(qv[d0], 0), SV2(kv, 0), s0);
            s1 = dot2acc(SV2(qv[d0], 2), SV2(kv, 2), s1);
            s0 = dot2acc(SV2(qv[d0], 4), SV2(kv, 4), s0);
            s1 = dot2acc(SV2(qv[d0], 6), SV2(kv, 6), s1);
        }
        float s = (s0 + s1) * SCALE_F;

        // online softmax within each 16-lane row group (fp32 statistics)
        float rm = s;
#pragma unroll
        for (int off = 8; off; off >>= 1) rm = fmaxf(rm, __shfl_xor(rm, off, 64));
        float m_new = fmaxf(m_old, rm);
        float p = __expf(s - m_new);
        float rs = p;
#pragma unroll
        for (int off = 8; off; off >>= 1) rs += __shfl_xor(rs, off, 64);
        float corr = __expf(m_old - m_new);
        lsum = lsum * corr + rs;
        acc0 *= corr; acc1 *= corr; acc2 *= corr; acc3 *= corr;

        // PV: p as f16 via LDS (intra-wave); V j-paired; fdot2 accumulation
        ps16[i][c] = (_Float16)p;
        f16x8 plo = *(const f16x8*)&ps16[i][0];   // p0..p7  (jp 0..3)
        f16x8 phi = *(const f16x8*)&ps16[i][8];   // p8..p15 (jp 4..7)
#define PVJ(JP, PSRC, OFF)                                            \
        {                                                             \
            f16x8 vv = *(const f16x8*)&vpl[cur][JP][c4][0];           \
            f16x2 pp = SV2(PSRC, OFF);                                \
            acc0 = dot2acc(pp, SV2(vv, 0), acc0);                     \
            acc1 = dot2acc(pp, SV2(vv, 2), acc1);                     \
            acc2 = dot2acc(pp, SV2(vv, 4), acc2);                     \
            acc3 = dot2acc(pp, SV2(vv, 6), acc3);                     \
        }
        PVJ(0, plo, 0) PVJ(1, plo, 2) PVJ(2, plo, 4) PVJ(3, plo, 6)
        PVJ(4, phi, 0) PVJ(5, phi, 2) PVJ(6, phi, 4) PVJ(7, phi, 6)
#undef PVJ
        m_old = m_new;
        __syncthreads();   // all reads of cur done; writes to cur^1 visible
    }

    if (EDGE) {
        int psx = (be * NSPLIT + split) * 16 + i;
        if (c == 0) { pm[psx] = m_old; pl[psx] = lsum; }
        float* pd = pacc + (size_t)psx * 64 + c4;
        pd[0] = acc0; pd[1] = acc1; pd[2] = acc2; pd[3] = acc3;
    } else {
        float inv = 1.f / lsum;
        _Float16* dst = outp + ((size_t)(b * S_ + n * BS_ + i)) * D_ + h * DH_ + c4;
        dst[0] = (_Float16)(acc0 * inv);
        dst[1] = (_Float16)(acc1 * inv);
        dst[2] = (_Float16)(acc2 * inv);
        dst[3] = (_Float16)(acc3 * inv);
    }
}

// ---------------------------------------------------------------------------
// Fused attention dispatch: sparse + edge split-K in one grid.
// ---------------------------------------------------------------------------
__global__ __launch_bounds__(256) void attn_fused(
    const _Float16* __restrict__ qkv, const int* __restrict__ key_idx,
    _Float16* __restrict__ outp, float* __restrict__ pm,
    float* __restrict__ pl, float* __restrict__ pacc)
{
    __shared__ __attribute__((aligned(16))) _Float16 qs[16][72];
    __shared__ __attribute__((aligned(16))) _Float16 ks[2][16][72];
    __shared__ __attribute__((aligned(16))) _Float16 vpl[2][8][64][2];
    __shared__ __attribute__((aligned(16))) _Float16 ps16[16][24];

    int bi = blockIdx.x;
    if (bi < NSPARSE) {
        int n = bi % NB_;
        if (n == 0 || n == NB_ - 1) return;
        int h = (bi / NB_) % H_;
        int b = bi / (NB_ * H_);
        attn_block<7, false>(qkv, key_idx, outp, nullptr, nullptr, nullptr,
                             b, h, n, 0, 0, qs, ks, vpl, ps16);
    } else {
        int ei = bi - NSPARSE;
        int split = ei % NSPLIT;
        int be = ei / NSPLIT;
        int e = be & 1;
        int h = (be >> 1) % H_;
        int b = be / (2 * H_);
        int n = e ? (NB_ - 1) : 0;
        attn_block<TILES_PER_SPLIT, true>(qkv, nullptr, nullptr, pm, pl, pacc,
                                          b, h, n, split, be, qs, ks, vpl, ps16);
    }
}

// ---------------------------------------------------------------------------
// Edge attention combine
// ---------------------------------------------------------------------------
__global__ __launch_bounds__(256) void attn_edge_combine(
    const float* __restrict__ pm, const float* __restrict__ pl,
    const float* __restrict__ pacc, _Float16* __restrict__ outp)
{
    int be = blockIdx.x;
    int e = be & 1;
    int h = (be >> 1) % H_;
    int b = be / (2 * H_);
    int n = e ? (NB_ - 1) : 0;

    int t = threadIdx.x;
    int i = t >> 4;
    int c = t & 15;

    float M = -1e30f;
#pragma unroll 4
    for (int s = 0; s < NSPLIT; ++s)
        M = fmaxf(M, pm[(be * NSPLIT + s) * 16 + i]);

    float L = 0.f;
    float acc[4] = {0.f, 0.f, 0.f, 0.f};
    for (int s = 0; s < NSPLIT; ++s) {
        int ps = (be * NSPLIT + s) * 16 + i;
        float wgt = __expf(pm[ps] - M);
        L += pl[ps] * wgt;
#pragma unroll
        for (int u = 0; u < 4; ++u) acc[u] += pacc[(size_t)ps * 64 + c * 4 + u] * wgt;
    }

    float inv = 1.f / L;
    _Float16* dst = outp + ((size_t)(b * S_ + n * BS_ + i)) * D_ + h * DH_ + c * 4;
#pragma unroll
    for (int u = 0; u < 4; ++u) dst[u] = (_Float16)(acc[u] * inv);
}

// ---------------------------------------------------------------------------
// x = LayerNorm(x + g); g is f16; writes fp32 x and f16 xb
// ---------------------------------------------------------------------------
__global__ __launch_bounds__(256) void add_ln_kernel(
    float* __restrict__ x, const _Float16* __restrict__ g,
    const float* __restrict__ gamma, const float* __restrict__ beta,
    _Float16* __restrict__ xb)
{
    int row = blockIdx.x;
    int t = threadIdx.x;
    float* xr = x + (size_t)row * D_;
    const _Float16* gr = g + (size_t)row * D_;
    _Float16* br = xb + (size_t)row * D_;

    float v[3];
    float s = 0.f, s2 = 0.f;
#pragma unroll
    for (int r = 0; r < 3; ++r) {
        int d = t + 256 * r;
        v[r] = xr[d] + (float)gr[d];
        s += v[r];
        s2 += v[r] * v[r];
    }
#pragma unroll
    for (int off = 32; off; off >>= 1) {
        s  += __shfl_xor(s, off, 64);
        s2 += __shfl_xor(s2, off, 64);
    }
    __shared__ float sA[4], sB[4];
    int wave = t >> 6, lane = t & 63;
    if (lane == 0) { sA[wave] = s; sB[wave] = s2; }
    __syncthreads();
    s  = sA[0] + sA[1] + sA[2] + sA[3];
    s2 = sB[0] + sB[1] + sB[2] + sB[3];
    float mean = s * (1.0f / D_);
    float var = s2 * (1.0f / D_) - mean * mean;
    float rstd = rsqrtf(var + 1e-12f);
#pragma unroll
    for (int r = 0; r < 3; ++r) {
        int d = t + 256 * r;
        float o = (v[r] - mean) * rstd * gamma[d] + beta[d];
        xr[d] = o;
        br[d] = (_Float16)o;
    }
}

// ---------------------------------------------------------------------------
// Fused heads: blockIdx < 2048 -> start/end logits; else disc pool partial.
// ---------------------------------------------------------------------------
__global__ __launch_bounds__(256) void heads_fused(
    const float* __restrict__ x, const float* __restrict__ sw,
    const float* __restrict__ ew, const float* __restrict__ Wp,
    float* __restrict__ sl, float* __restrict__ el,
    float* __restrict__ partial)
{
    int bi = blockIdx.x;
    int t = threadIdx.x;
    if (bi < 2048) {
        int wave = t >> 6, lane = t & 63;
        int row = bi * 4 + wave;
        const float* xr = x + (size_t)row * D_;
        float a = 0.f, e = 0.f;
        for (int d = lane; d < D_; d += 64) {
            float xv = xr[d];
            a += xv * sw[d];
            e += xv * ew[d];
        }
#pragma unroll
        for (int off = 32; off; off >>= 1) {
            a += __shfl_xor(a, off, 64);
            e += __shfl_xor(e, off, 64);
        }
        if (lane == 0) { sl[row] = a; el[row] = e; }
    } else {
        int ei = bi - 2048;       // 0..23
        int jb = ei % 3;          // 0..2
        int ks = ei / 3;          // 0..7
        int j = jb * 256 + t;
        int k0 = ks * DKC;

        __shared__ float xs[DKC];
        if (t < DKC) xs[t] = x[k0 + t];   // x0 = x row 0
        __syncthreads();

        float s = 0.f;
#pragma unroll 8
        for (int kk = 0; kk < DKC; ++kk)
            s += xs[kk] * Wp[(size_t)(k0 + kk) * D_ + j];
        partial[ks * D_ + j] = s;
    }
}

// ---------------------------------------------------------------------------
// Fused final: r<4 -> softmax over S; r==4 -> disc finish.
// ---------------------------------------------------------------------------
__global__ __launch_bounds__(256) void final_fused(
    const float* __restrict__ sl, const float* __restrict__ el,
    const float* __restrict__ partial, const float* __restrict__ bp,
    const float* __restrict__ d1W, const float* __restrict__ d1b,
    const float* __restrict__ d2W, const float* __restrict__ d2b,
    float* __restrict__ outp)
{
    int r = blockIdx.x;
    int t = threadIdx.x;
    if (r < 4) {
        const float* src = (r < 2 ? sl : el) + (size_t)(r & 1) * S_;
        float* dst = outp + (r < 2 ? 0 : BT_) + (size_t)(r & 1) * S_;
        int wave = t >> 6, lane = t & 63;
        __shared__ float sm[4], ss[4];

        float m = -1e30f;
        for (int k = t; k < S_; k += 256) m = fmaxf(m, src[k]);
#pragma unroll
        for (int off = 32; off; off >>= 1) m = fmaxf(m, __shfl_xor(m, off, 64));
        if (lane == 0) sm[wave] = m;
        __syncthreads();
        m = fmaxf(fmaxf(sm[0], sm[1]), fmaxf(sm[2], sm[3]));

        float s = 0.f;
        for (int k = t; k < S_; k += 256) s += __expf(src[k] - m);
#pragma unroll
        for (int off = 32; off; off >>= 1) s += __shfl_xor(s, off, 64);
        if (lane == 0) ss[wave] = s;
        __syncthreads();
        s = ss[0] + ss[1] + ss[2] + ss[3];

        float inv = 1.f / s;
        for (int k = t; k < S_; k += 256) dst[k] = __expf(src[k] - m) * inv;
    } else {
        __shared__ float pool[D_];
        __shared__ float h1[20];
        float* out2 = outp + 2 * BT_;
        for (int j = t; j < D_; j += 256) {
            float s = bp[j];
#pragma unroll
            for (int ks = 0; ks < DKS; ++ks) s += partial[ks * D_ + j];
            pool[j] = tanhf(s);
        }
        __syncthreads();
        if (t < 20) {
            float s = d1b[t];
            for (int k = 0; k < D_; ++k) s += pool[k] * d1W[k * 20 + t];
            h1[t] = s;
        }
        __syncthreads();
        if (t == 0) {
            float d0 = d2b[0], d1v = d2b[1];
#pragma unroll
            for (int u = 0; u < 20; ++u) {
                d0  += h1[u] * d2W[u * 2 + 0];
                d1v += h1[u] * d2W[u * 2 + 1];
            }
            float m = fmaxf(d0, d1v);
            float e0 = __expf(d0 - m), e1 = __expf(d1v - m);
            float inv = 1.f / (e0 + e1);
            out2[0] = e0 * inv;
            out2[1] = e1 * inv;
        }
    }
}

// ---------------------------------------------------------------------------
extern "C" void kernel_launch(void* const* d_in, const int* in_sizes, int n_in,
                              void* d_out, int out_size, void* d_ws, size_t ws_size,
                              hipStream_t stream)
{
    const int*   ids   = (const int*)d_in[0];
    const int*   kbi   = (const int*)d_in[1];
    const float* emb   = (const float*)d_in[2];
    const float* Wqkv  = (const float*)d_in[3];
    const float* bqkv  = (const float*)d_in[4];
    const float* Wo    = (const float*)d_in[5];
    const float* bo    = (const float*)d_in[6];
    const float* ln1g  = (const float*)d_in[7];
    const float* ln1b  = (const float*)d_in[8];
    const float* Wff1  = (const float*)d_in[9];
    const float* bff1  = (const float*)d_in[10];
    const float* Wff2  = (const float*)d_in[11];
    const float* bff2  = (const float*)d_in[12];
    const float* ln2g  = (const float*)d_in[13];
    const float* ln2b  = (const float*)d_in[14];
    const float* Wp    = (const float*)d_in[15];
    const float* bp    = (const float*)d_in[16];
    const float* sw    = (const float*)d_in[17];
    const float* ew    = (const float*)d_in[18];
    const float* d1W   = (const float*)d_in[19];
    const float* d1b   = (const float*)d_in[20];
    const float* d2W   = (const float*)d_in[21];
    const float* d2b   = (const float*)d_in[22];
    float* outp = (float*)d_out;

    // workspace carve (float units)
    float* ws   = (float*)d_ws;
    float* x    = ws;                          // BT_*D_ f32
    float* xbf  = x   + (size_t)BT_ * D_;      // f16 xb
    float* r1f  = xbf + (size_t)BT_ * D_ / 2;  // f16 qkv / f16 h
    float* abf  = r1f + (size_t)BT_ * FF_ / 2; // f16 attn out
    float* r2   = abf + (size_t)BT_ * D_ / 2;  // partials (early) / f16 g (late)
    float* wtf  = r2  + (size_t)BT_ * D_;      // f16 weights
    float* sl   = wtf + 7077888;
    float* el   = sl  + BT_;
    float* dpar = el  + BT_;                   // DKS * D_ disc partials

    _Float16* xb    = (_Float16*)xbf;
    _Float16* qkv16 = (_Float16*)r1f;
    _Float16* h16   = (_Float16*)r1f;
    _Float16* ab    = (_Float16*)abf;
    float* pm   = r2;
    float* pl   = r2 + NEDGE * NSPLIT * 16;
    float* pacc = pl + NEDGE * NSPLIT * 16;
    _Float16* g16 = (_Float16*)r2;   // aliased; partials dead once proj runs

    _Float16* Wt    = (_Float16*)wtf;
    _Float16* WqkvT = Wt;
    _Float16* WoT   = WqkvT + (size_t)2 * 2304 * 768;
    _Float16* Wff1T = WoT   + (size_t)2 * 768 * 768;
    _Float16* Wff2T = Wff1T + (size_t)2 * 3072 * 768;

    // fused weight convert: 8 segments, one dispatch
    WSegs segs;
    int start = 0;
    for (int l = 0; l < 2; ++l) {
        int base = l * 4;
        segs.s[base + 0] = { Wqkv + (size_t)l * 768 * 2304,
                             WqkvT + (size_t)l * 2304 * 768, 768, 2304, start };
        start += (2304 / 32) * (768 / 32);
        segs.s[base + 1] = { Wo + (size_t)l * 768 * 768,
                             WoT + (size_t)l * 768 * 768, 768, 768, start };
        start += (768 / 32) * (768 / 32);
        segs.s[base + 2] = { Wff1 + (size_t)l * 768 * 3072,
                             Wff1T + (size_t)l * 3072 * 768, 768, 3072, start };
        start += (3072 / 32) * (768 / 32);
        segs.s[base + 3] = { Wff2 + (size_t)l * 3072 * 768,
                             Wff2T + (size_t)l * 768 * 3072, 3072, 768, start };
        start += (768 / 32) * (3072 / 32);
    }
    segs.total = start;   // 13824

    wconvert_all<<<segs.total, 256, 0, stream>>>(segs);
    embed_kernel<<<BT_, 256, 0, stream>>>(ids, emb, x, xb);

    for (int l = 0; l < 2; ++l) {
        gemm_f16<0,1><<<dim3(2304/128, BT_/128), 256, 0, stream>>>(
            xb, WqkvT + (size_t)l * 2304 * 768, bqkv + (size_t)l * 3 * D_,
            qkv16, BT_, 3 * D_, D_);
        attn_fused<<<NSPARSE + NEDGE * NSPLIT, 256, 0, stream>>>(
            qkv16, kbi, ab, pm, pl, pacc);
        attn_edge_combine<<<NEDGE, 256, 0, stream>>>(pm, pl, pacc, ab);
        gemm_f16<0,1><<<dim3(768/128, BT_/128), 256, 0, stream>>>(
            ab, WoT + (size_t)l * 768 * 768, bo + (size_t)l * D_,
            g16, BT_, D_, D_);
        add_ln_kernel<<<BT_, 256, 0, stream>>>(x, g16, ln1g + (size_t)l * D_, ln1b + (size_t)l * D_, xb);
        gemm_f16<1,1><<<dim3(3072/128, BT_/128), 256, 0, stream>>>(
            xb, Wff1T + (size_t)l * 3072 * 768, bff1 + (size_t)l * FF_,
            h16, BT_, FF_, D_);
        gemm_f16<0,1><<<dim3(768/128, BT_/128), 256, 0, stream>>>(
            h16, Wff2T + (size_t)l * 768 * 3072, bff2 + (size_t)l * D_,
            g16, BT_, D_, FF_);
        add_ln_kernel<<<BT_, 256, 0, stream>>>(x, g16, ln2g + (size_t)l * D_, ln2b + (size_t)l * D_, xb);
    }

    heads_fused<<<2048 + 3 * DKS, 256, 0, stream>>>(x, sw, ew, Wp, sl, el, dpar);
    final_fused<<<5, 256, 0, stream>>>(sl, el, dpar, bp, d1W, d1b, d2W, d2b, outp);
}

// Round 18
// 685.411 us; speedup vs baseline: 1.1312x; 1.0213x over previous
//
#include <hip/hip_runtime.h>
#include <hip/hip_bf16.h>
#include <math.h>

#define B_   2
#define S_   4096
#define D_   768
#define H_   12
#define DH_  64
#define BS_  16
#define NB_  256
#define FF_  3072
#define BT_  (B_ * S_)          // 8192 token rows
#define SCALE_F 0.125f          // 1/sqrt(64)

#define NSPLIT 32               // key-dimension splits for edge attention
#define TILES_PER_SPLIT (NB_ / NSPLIT)   // 8
#define NEDGE (B_ * H_ * 2)     // 48 edge (b,h,e) groups
#define NSPARSE (B_ * H_ * NB_) // 6144 sparse blocks

#define DKS 8                   // disc pool k-splits
#define DKC (D_ / DKS)          // 96 rows per split

typedef _Float16 f16x8 __attribute__((ext_vector_type(8)));
typedef _Float16 f16x4 __attribute__((ext_vector_type(4)));
typedef _Float16 f16x2 __attribute__((ext_vector_type(2)));
typedef float    f32x4 __attribute__((ext_vector_type(4)));

#define SV2(v, k) __builtin_shufflevector(v, v, k, (k) + 1)

__device__ __forceinline__ float dot2acc(f16x2 a, f16x2 b, float c)
{
#if __has_builtin(__builtin_amdgcn_fdot2)
    return __builtin_amdgcn_fdot2(a, b, c, false);
#else
    return c + (float)a[0] * (float)b[0] + (float)a[1] * (float)b[1];
#endif
}

// async global->LDS, 16B per lane; LDS dest is wave-uniform base + lane*16
#define GLD16(gp, lp) __builtin_amdgcn_global_load_lds( \
    (const __attribute__((address_space(1))) void*)(gp), \
    (__attribute__((address_space(3))) void*)(lp), 16, 0, 0)

__device__ __forceinline__ float fast_tanh(float z)
{
    float az = fabsf(z);
    float t = __expf(-2.0f * az);
    float r = (1.0f - t) / (1.0f + t);
    return z < 0.f ? -r : r;
}

__device__ __forceinline__ float gelu_tanh(float v)
{
    float v3 = v * v * v;
    return 0.5f * v * (1.0f + fast_tanh(0.79788456080286535588f * (v + 0.044715f * v3)));
}

// ---------------------------------------------------------------------------
// Fused weight convert + embedding (r17): one dispatch.
// blockIdx < segs.total -> 32x32 W transpose tile; else -> embed row.
// ---------------------------------------------------------------------------
struct WSeg { const float* src; _Float16* dst; int K; int N; int start; };
struct WSegs { WSeg s[8]; int total; };

__global__ __launch_bounds__(256) void prep_all(
    WSegs segs, const int* __restrict__ ids, const float* __restrict__ emb,
    float* __restrict__ x, _Float16* __restrict__ xb)
{
    int bt = blockIdx.x;
    int t = threadIdx.x;
    if (bt < segs.total) {
        __shared__ float tile[32][33];
        int si = 0;
#pragma unroll
        for (int u = 1; u < 8; ++u)
            if (bt >= segs.s[u].start) si = u;
        const WSeg& sg = segs.s[si];
        int tid = bt - sg.start;
        int tn = sg.N >> 5;
        int n0 = (tid % tn) * 32;
        int k0 = (tid / tn) * 32;

        int r = t >> 5, c = t & 31;
#pragma unroll
        for (int rr = 0; rr < 32; rr += 8)
            tile[r + rr][c] = sg.src[(size_t)(k0 + r + rr) * sg.N + n0 + c];
        __syncthreads();
#pragma unroll
        for (int rr = 0; rr < 32; rr += 8)
            sg.dst[(size_t)(n0 + r + rr) * sg.K + k0 + c] = (_Float16)tile[c][r + rr];
    } else {
        int row = bt - segs.total;
        int id = ids[row];
        const float* src = emb + (size_t)id * D_;
        float* dst = x + (size_t)row * D_;
        _Float16* dst16 = xb + (size_t)row * D_;
        for (int d = t; d < D_; d += 256) {
            float v = src[d];
            dst[d] = v;
            dst16[d] = (_Float16)v;
        }
    }
}

// ---------------------------------------------------------------------------
// MFMA fp16 GEMM (r8-verified): C = A[M,K] @ Wt[N,K]^T + bias.
// 128x128 tile, BK=64, 4 waves, 4x4 frags. Chunk-XOR swizzle involution.
// ---------------------------------------------------------------------------
template<int ACT, int OUT16>
__global__ __launch_bounds__(256) void gemm_f16(
    const _Float16* __restrict__ A, const _Float16* __restrict__ Wt,
    const float* __restrict__ bias, void* __restrict__ Cp,
    int M, int N, int K)
{
    __shared__ __attribute__((aligned(16))) _Float16 As[128 * 64];
    __shared__ __attribute__((aligned(16))) _Float16 Bs[128 * 64];

    int t = threadIdx.x;
    int w = t >> 6, l = t & 63;
    int bm = blockIdx.y * 128, bn = blockIdx.x * 128;
    int wr = (w >> 1) * 64, wc = (w & 1) * 64;

    f32x4 acc[4][4];
#pragma unroll
    for (int i = 0; i < 4; ++i)
#pragma unroll
        for (int j = 0; j < 4; ++j) acc[i][j] = (f32x4){0.f, 0.f, 0.f, 0.f};

    const _Float16* gA[4];
    const _Float16* gB[4];
#pragma unroll
    for (int q = 0; q < 4; ++q) {
        int m = w * 4 + q;
        int row = m * 8 + (l >> 3);
        int sc = (l & 7) ^ (row & 7);
        gA[q] = A  + (size_t)(bm + row) * K + sc * 8;
        gB[q] = Wt + (size_t)(bn + row) * K + sc * 8;
    }

    int aoff[2][4], boff[2][4];
#pragma unroll
    for (int kk = 0; kk < 2; ++kk)
#pragma unroll
        for (int i = 0; i < 4; ++i) {
            int ar = wr + i * 16 + (l & 15);
            int ch = (kk * 4 + (l >> 4)) ^ (l & 7);
            aoff[kk][i] = ar * 64 + ch * 8;
            int br = wc + i * 16 + (l & 15);
            boff[kk][i] = br * 64 + ch * 8;
        }

    for (int k0 = 0; k0 < K; k0 += 64) {
#pragma unroll
        for (int q = 0; q < 4; ++q) {
            int m = w * 4 + q;
            GLD16(gA[q] + k0, As + m * 512);
            GLD16(gB[q] + k0, Bs + m * 512);
        }
        __syncthreads();

        f16x8 af[2][4], bf[2][4];
#pragma unroll
        for (int kk = 0; kk < 2; ++kk)
#pragma unroll
            for (int i = 0; i < 4; ++i) {
                af[kk][i] = *(const f16x8*)(As + aoff[kk][i]);
                bf[kk][i] = *(const f16x8*)(Bs + boff[kk][i]);
            }
#pragma unroll
        for (int kk = 0; kk < 2; ++kk)
#pragma unroll
            for (int i = 0; i < 4; ++i)
#pragma unroll
                for (int j = 0; j < 4; ++j)
                    acc[i][j] = __builtin_amdgcn_mfma_f32_16x16x32_f16(
                        af[kk][i], bf[kk][j], acc[i][j], 0, 0, 0);
        __syncthreads();
    }

#pragma unroll
    for (int i = 0; i < 4; ++i) {
        int rowb = bm + wr + i * 16 + ((l >> 4) << 2);
#pragma unroll
        for (int j = 0; j < 4; ++j) {
            int col = bn + wc + j * 16 + (l & 15);
            float bv = bias[col];
#pragma unroll
            for (int r = 0; r < 4; ++r) {
                float v = acc[i][j][r] + bv;
                if (ACT) v = gelu_tanh(v);
                if (OUT16)
                    ((_Float16*)Cp)[(size_t)(rowb + r) * N + col] = (_Float16)v;
                else
                    ((float*)Cp)[(size_t)(rowb + r) * N + col] = v;
            }
        }
    }
}

// ---------------------------------------------------------------------------
// Attention core (r17): K dbuf f16 LDS; V j-paired f16; PV on fdot2.
// r17: lsum computed from the f16 p values already loaded for PV (replaces
// the 4-step shuffle sum — moves work from the busy LDS pipe to VALU, and
// makes numerator/denominator use identical rounded p); s_setprio(1) around
// the compute region (T5; attn blocks are phase-staggered -> m191 regime).
// ---------------------------------------------------------------------------
template<int NT, bool EDGE>
__device__ __forceinline__ void attn_block(
    const _Float16* __restrict__ qkv, const int* __restrict__ key_idx,
    _Float16* __restrict__ outp, float* __restrict__ pm,
    float* __restrict__ pl, float* __restrict__ pacc,
    int b, int h, int n, int split, int be,
    _Float16 (*qs)[72], _Float16 (*ks)[16][72],
    _Float16 (*vpl)[8][64][2], _Float16 (*ps16)[24])
{
    int t = threadIdx.x;
    int i = t >> 4;        // query row / staging row
    int c = t & 15;
    int c4 = c * 4;

    // stage Q tile; load tile 0 into registers
    *(f16x4*)&qs[i][c4] =
        *(const f16x4*)&qkv[((size_t)(b * S_ + n * BS_ + i)) * (3 * D_) + h * DH_ + c4];
    int kb0 = EDGE ? split * NT : key_idx[n * 7];
    const _Float16* kp0 = qkv + ((size_t)(b * S_ + kb0 * BS_ + i)) * (3 * D_) + D_ + h * DH_;
    f16x4 kr = *(const f16x4*)(kp0 + c4);
    f16x4 vr = *(const f16x4*)(kp0 + D_ + c4);
    __syncthreads();   // qs visible

    f16x8 qv[8];
#pragma unroll
    for (int d0 = 0; d0 < 8; ++d0) qv[d0] = *(const f16x8*)&qs[i][d0 * 8];

    // write tile 0 into buffer 0; prefetch tile 1
    *(f16x4*)&ks[0][i][c4] = kr;
#pragma unroll
    for (int u = 0; u < 4; ++u) vpl[0][i >> 1][c4 + u][i & 1] = vr[u];
    if (NT > 1) {
        int kb1 = EDGE ? (split * NT + 1) : key_idx[n * 7 + 1];
        const _Float16* kp1 = qkv + ((size_t)(b * S_ + kb1 * BS_ + i)) * (3 * D_) + D_ + h * DH_;
        kr = *(const f16x4*)(kp1 + c4);
        vr = *(const f16x4*)(kp1 + D_ + c4);
    }
    __syncthreads();   // buffer 0 staged

    float m_old = -1e30f, lsum = 0.f;
    float acc0 = 0.f, acc1 = 0.f, acc2 = 0.f, acc3 = 0.f;
    const f16x2 one2 = {(_Float16)1.f, (_Float16)1.f};

#pragma unroll 1
    for (int jj = 0; jj < NT; ++jj) {
        int cur = jj & 1;
        if (jj + 1 < NT) {
            *(f16x4*)&ks[cur ^ 1][i][c4] = kr;
#pragma unroll
            for (int u = 0; u < 4; ++u) vpl[cur ^ 1][i >> 1][c4 + u][i & 1] = vr[u];
        }
        if (jj + 2 < NT) {
            int kb2 = EDGE ? (split * NT + jj + 2) : key_idx[n * 7 + jj + 2];
            const _Float16* kp2 = qkv + ((size_t)(b * S_ + kb2 * BS_ + i)) * (3 * D_) + D_ + h * DH_;
            kr = *(const f16x4*)(kp2 + c4);
            vr = *(const f16x4*)(kp2 + D_ + c4);
        }

        __builtin_amdgcn_s_setprio(1);
        // score: <q_i, k_c> via fdot2 over b128 LDS reads
        float s0 = 0.f, s1 = 0.f;
#pragma unroll
        for (int d0 = 0; d0 < 8; ++d0) {
            f16x8 kv = *(const f16x8*)&ks[cur][c][d0 * 8];
            s0 = dot2acc(SV2(qv[d0], 0), SV2(kv, 0), s0);
            s1 = dot2acc(SV2(qv[d0], 2), SV2(kv, 2), s1);
            s0 = dot2acc(SV2(qv[d0], 4), SV2(kv, 4), s0);
            s1 = dot2acc(SV2(qv[d0], 6), SV2(kv, 6), s1);
        }
        float s = (s0 + s1) * SCALE_F;

        // row max (fp32, 16-lane shuffle); p in f16 via LDS
        float rm = s;
#pragma unroll
        for (int off = 8; off; off >>= 1) rm = fmaxf(rm, __shfl_xor(rm, off, 64));
        float m_new = fmaxf(m_old, rm);
        float p = __expf(s - m_new);

        ps16[i][c] = (_Float16)p;
        f16x8 plo = *(const f16x8*)&ps16[i][0];   // p0..p7  (jp 0..3)
        f16x8 phi = *(const f16x8*)&ps16[i][8];   // p8..p15 (jp 4..7)

        // row sum from the same f16 p values (no shuffle reduce)
        float rs = 0.f;
        rs = dot2acc(SV2(plo, 0), one2, rs);
        rs = dot2acc(SV2(plo, 2), one2, rs);
        rs = dot2acc(SV2(plo, 4), one2, rs);
        rs = dot2acc(SV2(plo, 6), one2, rs);
        rs = dot2acc(SV2(phi, 0), one2, rs);
        rs = dot2acc(SV2(phi, 2), one2, rs);
        rs = dot2acc(SV2(phi, 4), one2, rs);
        rs = dot2acc(SV2(phi, 6), one2, rs);

        float corr = __expf(m_old - m_new);
        lsum = lsum * corr + rs;
        acc0 *= corr; acc1 *= corr; acc2 *= corr; acc3 *= corr;

        // PV: V j-paired; fdot2 accumulation (literal shuffle indices)
#define PVJ(JP, PSRC, OFF)                                            \
        {                                                             \
            f16x8 vv = *(const f16x8*)&vpl[cur][JP][c4][0];           \
            f16x2 pp = SV2(PSRC, OFF);                                \
            acc0 = dot2acc(pp, SV2(vv, 0), acc0);                     \
            acc1 = dot2acc(pp, SV2(vv, 2), acc1);                     \
            acc2 = dot2acc(pp, SV2(vv, 4), acc2);                     \
            acc3 = dot2acc(pp, SV2(vv, 6), acc3);                     \
        }
        PVJ(0, plo, 0) PVJ(1, plo, 2) PVJ(2, plo, 4) PVJ(3, plo, 6)
        PVJ(4, phi, 0) PVJ(5, phi, 2) PVJ(6, phi, 4) PVJ(7, phi, 6)
#undef PVJ
        __builtin_amdgcn_s_setprio(0);
        m_old = m_new;
        __syncthreads();   // all reads of cur done; writes to cur^1 visible
    }

    if (EDGE) {
        int psx = (be * NSPLIT + split) * 16 + i;
        if (c == 0) { pm[psx] = m_old; pl[psx] = lsum; }
        float* pd = pacc + (size_t)psx * 64 + c4;
        pd[0] = acc0; pd[1] = acc1; pd[2] = acc2; pd[3] = acc3;
    } else {
        float inv = 1.f / lsum;
        _Float16* dst = outp + ((size_t)(b * S_ + n * BS_ + i)) * D_ + h * DH_ + c4;
        dst[0] = (_Float16)(acc0 * inv);
        dst[1] = (_Float16)(acc1 * inv);
        dst[2] = (_Float16)(acc2 * inv);
        dst[3] = (_Float16)(acc3 * inv);
    }
}

// ---------------------------------------------------------------------------
// Fused attention dispatch: sparse + edge split-K in one grid.
// ---------------------------------------------------------------------------
__global__ __launch_bounds__(256) void attn_fused(
    const _Float16* __restrict__ qkv, const int* __restrict__ key_idx,
    _Float16* __restrict__ outp, float* __restrict__ pm,
    float* __restrict__ pl, float* __restrict__ pacc)
{
    __shared__ __attribute__((aligned(16))) _Float16 qs[16][72];
    __shared__ __attribute__((aligned(16))) _Float16 ks[2][16][72];
    __shared__ __attribute__((aligned(16))) _Float16 vpl[2][8][64][2];
    __shared__ __attribute__((aligned(16))) _Float16 ps16[16][24];

    int bi = blockIdx.x;
    if (bi < NSPARSE) {
        int n = bi % NB_;
        if (n == 0 || n == NB_ - 1) return;
        int h = (bi / NB_) % H_;
        int b = bi / (NB_ * H_);
        attn_block<7, false>(qkv, key_idx, outp, nullptr, nullptr, nullptr,
                             b, h, n, 0, 0, qs, ks, vpl, ps16);
    } else {
        int ei = bi - NSPARSE;
        int split = ei % NSPLIT;
        int be = ei / NSPLIT;
        int e = be & 1;
        int h = (be >> 1) % H_;
        int b = be / (2 * H_);
        int n = e ? (NB_ - 1) : 0;
        attn_block<TILES_PER_SPLIT, true>(qkv, nullptr, nullptr, pm, pl, pacc,
                                          b, h, n, split, be, qs, ks, vpl, ps16);
    }
}

// ---------------------------------------------------------------------------
// Edge attention combine
// ---------------------------------------------------------------------------
__global__ __launch_bounds__(256) void attn_edge_combine(
    const float* __restrict__ pm, const float* __restrict__ pl,
    const float* __restrict__ pacc, _Float16* __restrict__ outp)
{
    int be = blockIdx.x;
    int e = be & 1;
    int h = (be >> 1) % H_;
    int b = be / (2 * H_);
    int n = e ? (NB_ - 1) : 0;

    int t = threadIdx.x;
    int i = t >> 4;
    int c = t & 15;

    float M = -1e30f;
#pragma unroll 4
    for (int s = 0; s < NSPLIT; ++s)
        M = fmaxf(M, pm[(be * NSPLIT + s) * 16 + i]);

    float L = 0.f;
    float acc[4] = {0.f, 0.f, 0.f, 0.f};
    for (int s = 0; s < NSPLIT; ++s) {
        int ps = (be * NSPLIT + s) * 16 + i;
        float wgt = __expf(pm[ps] - M);
        L += pl[ps] * wgt;
#pragma unroll
        for (int u = 0; u < 4; ++u) acc[u] += pacc[(size_t)ps * 64 + c * 4 + u] * wgt;
    }

    float inv = 1.f / L;
    _Float16* dst = outp + ((size_t)(b * S_ + n * BS_ + i)) * D_ + h * DH_ + c * 4;
#pragma unroll
    for (int u = 0; u < 4; ++u) dst[u] = (_Float16)(acc[u] * inv);
}

// ---------------------------------------------------------------------------
// x = LayerNorm(x + g); g is f16; writes fp32 x and f16 xb
// ---------------------------------------------------------------------------
__global__ __launch_bounds__(256) void add_ln_kernel(
    float* __restrict__ x, const _Float16* __restrict__ g,
    const float* __restrict__ gamma, const float* __restrict__ beta,
    _Float16* __restrict__ xb)
{
    int row = blockIdx.x;
    int t = threadIdx.x;
    float* xr = x + (size_t)row * D_;
    const _Float16* gr = g + (size_t)row * D_;
    _Float16* br = xb + (size_t)row * D_;

    float v[3];
    float s = 0.f, s2 = 0.f;
#pragma unroll
    for (int r = 0; r < 3; ++r) {
        int d = t + 256 * r;
        v[r] = xr[d] + (float)gr[d];
        s += v[r];
        s2 += v[r] * v[r];
    }
#pragma unroll
    for (int off = 32; off; off >>= 1) {
        s  += __shfl_xor(s, off, 64);
        s2 += __shfl_xor(s2, off, 64);
    }
    __shared__ float sA[4], sB[4];
    int wave = t >> 6, lane = t & 63;
    if (lane == 0) { sA[wave] = s; sB[wave] = s2; }
    __syncthreads();
    s  = sA[0] + sA[1] + sA[2] + sA[3];
    s2 = sB[0] + sB[1] + sB[2] + sB[3];
    float mean = s * (1.0f / D_);
    float var = s2 * (1.0f / D_) - mean * mean;
    float rstd = rsqrtf(var + 1e-12f);
#pragma unroll
    for (int r = 0; r < 3; ++r) {
        int d = t + 256 * r;
        float o = (v[r] - mean) * rstd * gamma[d] + beta[d];
        xr[d] = o;
        br[d] = (_Float16)o;
    }
}

// ---------------------------------------------------------------------------
// Fused heads: blockIdx < 2048 -> start/end logits; else disc pool partial.
// ---------------------------------------------------------------------------
__global__ __launch_bounds__(256) void heads_fused(
    const float* __restrict__ x, const float* __restrict__ sw,
    const float* __restrict__ ew, const float* __restrict__ Wp,
    float* __restrict__ sl, float* __restrict__ el,
    float* __restrict__ partial)
{
    int bi = blockIdx.x;
    int t = threadIdx.x;
    if (bi < 2048) {
        int wave = t >> 6, lane = t & 63;
        int row = bi * 4 + wave;
        const float* xr = x + (size_t)row * D_;
        float a = 0.f, e = 0.f;
        for (int d = lane; d < D_; d += 64) {
            float xv = xr[d];
            a += xv * sw[d];
            e += xv * ew[d];
        }
#pragma unroll
        for (int off = 32; off; off >>= 1) {
            a += __shfl_xor(a, off, 64);
            e += __shfl_xor(e, off, 64);
        }
        if (lane == 0) { sl[row] = a; el[row] = e; }
    } else {
        int ei = bi - 2048;       // 0..23
        int jb = ei % 3;          // 0..2
        int ks = ei / 3;          // 0..7
        int j = jb * 256 + t;
        int k0 = ks * DKC;

        __shared__ float xs[DKC];
        if (t < DKC) xs[t] = x[k0 + t];   // x0 = x row 0
        __syncthreads();

        float s = 0.f;
#pragma unroll 8
        for (int kk = 0; kk < DKC; ++kk)
            s += xs[kk] * Wp[(size_t)(k0 + kk) * D_ + j];
        partial[ks * D_ + j] = s;
    }
}

// ---------------------------------------------------------------------------
// Fused final: r<4 -> softmax over S; r==4 -> disc finish.
// ---------------------------------------------------------------------------
__global__ __launch_bounds__(256) void final_fused(
    const float* __restrict__ sl, const float* __restrict__ el,
    const float* __restrict__ partial, const float* __restrict__ bp,
    const float* __restrict__ d1W, const float* __restrict__ d1b,
    const float* __restrict__ d2W, const float* __restrict__ d2b,
    float* __restrict__ outp)
{
    int r = blockIdx.x;
    int t = threadIdx.x;
    if (r < 4) {
        const float* src = (r < 2 ? sl : el) + (size_t)(r & 1) * S_;
        float* dst = outp + (r < 2 ? 0 : BT_) + (size_t)(r & 1) * S_;
        int wave = t >> 6, lane = t & 63;
        __shared__ float sm[4], ss[4];

        float m = -1e30f;
        for (int k = t; k < S_; k += 256) m = fmaxf(m, src[k]);
#pragma unroll
        for (int off = 32; off; off >>= 1) m = fmaxf(m, __shfl_xor(m, off, 64));
        if (lane == 0) sm[wave] = m;
        __syncthreads();
        m = fmaxf(fmaxf(sm[0], sm[1]), fmaxf(sm[2], sm[3]));

        float s = 0.f;
        for (int k = t; k < S_; k += 256) s += __expf(src[k] - m);
#pragma unroll
        for (int off = 32; off; off >>= 1) s += __shfl_xor(s, off, 64);
        if (lane == 0) ss[wave] = s;
        __syncthreads();
        s = ss[0] + ss[1] + ss[2] + ss[3];

        float inv = 1.f / s;
        for (int k = t; k < S_; k += 256) dst[k] = __expf(src[k] - m) * inv;
    } else {
        __shared__ float pool[D_];
        __shared__ float h1[20];
        float* out2 = outp + 2 * BT_;
        for (int j = t; j < D_; j += 256) {
            float s = bp[j];
#pragma unroll
            for (int ks = 0; ks < DKS; ++ks) s += partial[ks * D_ + j];
            pool[j] = tanhf(s);
        }
        __syncthreads();
        if (t < 20) {
            float s = d1b[t];
            for (int k = 0; k < D_; ++k) s += pool[k] * d1W[k * 20 + t];
            h1[t] = s;
        }
        __syncthreads();
        if (t == 0) {
            float d0 = d2b[0], d1v = d2b[1];
#pragma unroll
            for (int u = 0; u < 20; ++u) {
                d0  += h1[u] * d2W[u * 2 + 0];
                d1v += h1[u] * d2W[u * 2 + 1];
            }
            float m = fmaxf(d0, d1v);
            float e0 = __expf(d0 - m), e1 = __expf(d1v - m);
            float inv = 1.f / (e0 + e1);
            out2[0] = e0 * inv;
            out2[1] = e1 * inv;
        }
    }
}

// ---------------------------------------------------------------------------
extern "C" void kernel_launch(void* const* d_in, const int* in_sizes, int n_in,
                              void* d_out, int out_size, void* d_ws, size_t ws_size,
                              hipStream_t stream)
{
    const int*   ids   = (const int*)d_in[0];
    const int*   kbi   = (const int*)d_in[1];
    const float* emb   = (const float*)d_in[2];
    const float* Wqkv  = (const float*)d_in[3];
    const float* bqkv  = (const float*)d_in[4];
    const float* Wo    = (const float*)d_in[5];
    const float* bo    = (const float*)d_in[6];
    const float* ln1g  = (const float*)d_in[7];
    const float* ln1b  = (const float*)d_in[8];
    const float* Wff1  = (const float*)d_in[9];
    const float* bff1  = (const float*)d_in[10];
    const float* Wff2  = (const float*)d_in[11];
    const float* bff2  = (const float*)d_in[12];
    const float* ln2g  = (const float*)d_in[13];
    const float* ln2b  = (const float*)d_in[14];
    const float* Wp    = (const float*)d_in[15];
    const float* bp    = (const float*)d_in[16];
    const float* sw    = (const float*)d_in[17];
    const float* ew    = (const float*)d_in[18];
    const float* d1W   = (const float*)d_in[19];
    const float* d1b   = (const float*)d_in[20];
    const float* d2W   = (const float*)d_in[21];
    const float* d2b   = (const float*)d_in[22];
    float* outp = (float*)d_out;

    // workspace carve (float units)
    float* ws   = (float*)d_ws;
    float* x    = ws;                          // BT_*D_ f32
    float* xbf  = x   + (size_t)BT_ * D_;      // f16 xb
    float* r1f  = xbf + (size_t)BT_ * D_ / 2;  // f16 qkv / f16 h
    float* abf  = r1f + (size_t)BT_ * FF_ / 2; // f16 attn out
    float* r2   = abf + (size_t)BT_ * D_ / 2;  // partials (early) / f16 g (late)
    float* wtf  = r2  + (size_t)BT_ * D_;      // f16 weights
    float* sl   = wtf + 7077888;
    float* el   = sl  + BT_;
    float* dpar = el  + BT_;                   // DKS * D_ disc partials

    _Float16* xb    = (_Float16*)xbf;
    _Float16* qkv16 = (_Float16*)r1f;
    _Float16* h16   = (_Float16*)r1f;
    _Float16* ab    = (_Float16*)abf;
    float* pm   = r2;
    float* pl   = r2 + NEDGE * NSPLIT * 16;
    float* pacc = pl + NEDGE * NSPLIT * 16;
    _Float16* g16 = (_Float16*)r2;   // aliased; partials dead once proj runs

    _Float16* Wt    = (_Float16*)wtf;
    _Float16* WqkvT = Wt;
    _Float16* WoT   = WqkvT + (size_t)2 * 2304 * 768;
    _Float16* Wff1T = WoT   + (size_t)2 * 768 * 768;
    _Float16* Wff2T = Wff1T + (size_t)2 * 3072 * 768;

    // fused weight convert + embed: one dispatch
    WSegs segs;
    int start = 0;
    for (int l = 0; l < 2; ++l) {
        int base = l * 4;
        segs.s[base + 0] = { Wqkv + (size_t)l * 768 * 2304,
                             WqkvT + (size_t)l * 2304 * 768, 768, 2304, start };
        start += (2304 / 32) * (768 / 32);
        segs.s[base + 1] = { Wo + (size_t)l * 768 * 768,
                             WoT + (size_t)l * 768 * 768, 768, 768, start };
        start += (768 / 32) * (768 / 32);
        segs.s[base + 2] = { Wff1 + (size_t)l * 768 * 3072,
                             Wff1T + (size_t)l * 3072 * 768, 768, 3072, start };
        start += (3072 / 32) * (768 / 32);
        segs.s[base + 3] = { Wff2 + (size_t)l * 3072 * 768,
                             Wff2T + (size_t)l * 768 * 3072, 3072, 768, start };
        start += (768 / 32) * (3072 / 32);
    }
    segs.total = start;   // 13824

    prep_all<<<segs.total + BT_, 256, 0, stream>>>(segs, ids, emb, x, xb);

    for (int l = 0; l < 2; ++l) {
        gemm_f16<0,1><<<dim3(2304/128, BT_/128), 256, 0, stream>>>(
            xb, WqkvT + (size_t)l * 2304 * 768, bqkv + (size_t)l * 3 * D_,
            qkv16, BT_, 3 * D_, D_);
        attn_fused<<<NSPARSE + NEDGE * NSPLIT, 256, 0, stream>>>(
            qkv16, kbi, ab, pm, pl, pacc);
        attn_edge_combine<<<NEDGE, 256, 0, stream>>>(pm, pl, pacc, ab);
        gemm_f16<0,1><<<dim3(768/128, BT_/128), 256, 0, stream>>>(
            ab, WoT + (size_t)l * 768 * 768, bo + (size_t)l * D_,
            g16, BT_, D_, D_);
        add_ln_kernel<<<BT_, 256, 0, stream>>>(x, g16, ln1g + (size_t)l * D_, ln1b + (size_t)l * D_, xb);
        gemm_f16<1,1><<<dim3(3072/128, BT_/128), 256, 0, stream>>>(
            xb, Wff1T + (size_t)l * 3072 * 768, bff1 + (size_t)l * FF_,
            h16, BT_, FF_, D_);
        gemm_f16<0,1><<<dim3(768/128, BT_/128), 256, 0, stream>>>(
            h16, Wff2T + (size_t)l * 768 * 3072, bff2 + (size_t)l * D_,
            g16, BT_, D_, FF_);
        add_ln_kernel<<<BT_, 256, 0, stream>>>(x, g16, ln2g + (size_t)l * D_, ln2b + (size_t)l * D_, xb);
    }

    heads_fused<<<2048 + 3 * DKS, 256, 0, stream>>>(x, sw, ew, Wp, sl, el, dpar);
    final_fused<<<5, 256, 0, stream>>>(sl, el, dpar, bp, d1W, d1b, d2W, d2b, outp);
}

// Round 19
// 672.898 us; speedup vs baseline: 1.1523x; 1.0186x over previous
//
#include <hip/hip_runtime.h>
#include <hip/hip_bf16.h>
#include <math.h>

#define B_   2
#define S_   4096
#define D_   768
#define H_   12
#define DH_  64
#define BS_  16
#define NB_  256
#define FF_  3072
#define BT_  (B_ * S_)          // 8192 token rows
#define SCALE_F 0.125f          // 1/sqrt(64)

#define NSPLIT 32               // key-dimension splits for edge attention
#define TILES_PER_SPLIT (NB_ / NSPLIT)   // 8
#define NEDGE (B_ * H_ * 2)     // 48 edge (b,h,e) groups
#define NSPARSE (B_ * H_ * NB_) // 6144 sparse blocks

#define DKS 8                   // disc pool k-splits
#define DKC (D_ / DKS)          // 96 rows per split

typedef _Float16 f16x8 __attribute__((ext_vector_type(8)));
typedef _Float16 f16x4 __attribute__((ext_vector_type(4)));
typedef _Float16 f16x2 __attribute__((ext_vector_type(2)));
typedef float    f32x4 __attribute__((ext_vector_type(4)));

#define SV2(v, k) __builtin_shufflevector(v, v, k, (k) + 1)

__device__ __forceinline__ float dot2acc(f16x2 a, f16x2 b, float c)
{
#if __has_builtin(__builtin_amdgcn_fdot2)
    return __builtin_amdgcn_fdot2(a, b, c, false);
#else
    return c + (float)a[0] * (float)b[0] + (float)a[1] * (float)b[1];
#endif
}

// async global->LDS, 16B per lane; LDS dest is wave-uniform base + lane*16
#define GLD16(gp, lp) __builtin_amdgcn_global_load_lds( \
    (const __attribute__((address_space(1))) void*)(gp), \
    (__attribute__((address_space(3))) void*)(lp), 16, 0, 0)

__device__ __forceinline__ float fast_tanh(float z)
{
    float az = fabsf(z);
    float t = __expf(-2.0f * az);
    float r = (1.0f - t) / (1.0f + t);
    return z < 0.f ? -r : r;
}

__device__ __forceinline__ float gelu_tanh(float v)
{
    float v3 = v * v * v;
    return 0.5f * v * (1.0f + fast_tanh(0.79788456080286535588f * (v + 0.044715f * v3)));
}

// ---------------------------------------------------------------------------
// Fused weight convert + embedding: one dispatch.
// blockIdx < segs.total -> 32x32 W transpose tile; else -> embed row (f16).
// ---------------------------------------------------------------------------
struct WSeg { const float* src; _Float16* dst; int K; int N; int start; };
struct WSegs { WSeg s[8]; int total; };

__global__ __launch_bounds__(256) void prep_all(
    WSegs segs, const int* __restrict__ ids, const float* __restrict__ emb,
    _Float16* __restrict__ xh)
{
    int bt = blockIdx.x;
    int t = threadIdx.x;
    if (bt < segs.total) {
        __shared__ float tile[32][33];
        int si = 0;
#pragma unroll
        for (int u = 1; u < 8; ++u)
            if (bt >= segs.s[u].start) si = u;
        const WSeg& sg = segs.s[si];
        int tid = bt - sg.start;
        int tn = sg.N >> 5;
        int n0 = (tid % tn) * 32;
        int k0 = (tid / tn) * 32;

        int r = t >> 5, c = t & 31;
#pragma unroll
        for (int rr = 0; rr < 32; rr += 8)
            tile[r + rr][c] = sg.src[(size_t)(k0 + r + rr) * sg.N + n0 + c];
        __syncthreads();
#pragma unroll
        for (int rr = 0; rr < 32; rr += 8)
            sg.dst[(size_t)(n0 + r + rr) * sg.K + k0 + c] = (_Float16)tile[c][r + rr];
    } else {
        int row = bt - segs.total;
        int id = ids[row];
        const float* src = emb + (size_t)id * D_;
        _Float16* dst16 = xh + (size_t)row * D_;
        for (int d = t; d < D_; d += 256)
            dst16[d] = (_Float16)src[d];
    }
}

// ---------------------------------------------------------------------------
// MFMA fp16 GEMM (r8-verified): C = A[M,K] @ Wt[N,K]^T + bias.
// 128x128 tile, BK=64, 4 waves, 4x4 frags. Chunk-XOR swizzle involution.
// ---------------------------------------------------------------------------
template<int ACT, int OUT16>
__global__ __launch_bounds__(256) void gemm_f16(
    const _Float16* __restrict__ A, const _Float16* __restrict__ Wt,
    const float* __restrict__ bias, void* __restrict__ Cp,
    int M, int N, int K)
{
    __shared__ __attribute__((aligned(16))) _Float16 As[128 * 64];
    __shared__ __attribute__((aligned(16))) _Float16 Bs[128 * 64];

    int t = threadIdx.x;
    int w = t >> 6, l = t & 63;
    int bm = blockIdx.y * 128, bn = blockIdx.x * 128;
    int wr = (w >> 1) * 64, wc = (w & 1) * 64;

    f32x4 acc[4][4];
#pragma unroll
    for (int i = 0; i < 4; ++i)
#pragma unroll
        for (int j = 0; j < 4; ++j) acc[i][j] = (f32x4){0.f, 0.f, 0.f, 0.f};

    const _Float16* gA[4];
    const _Float16* gB[4];
#pragma unroll
    for (int q = 0; q < 4; ++q) {
        int m = w * 4 + q;
        int row = m * 8 + (l >> 3);
        int sc = (l & 7) ^ (row & 7);
        gA[q] = A  + (size_t)(bm + row) * K + sc * 8;
        gB[q] = Wt + (size_t)(bn + row) * K + sc * 8;
    }

    int aoff[2][4], boff[2][4];
#pragma unroll
    for (int kk = 0; kk < 2; ++kk)
#pragma unroll
        for (int i = 0; i < 4; ++i) {
            int ar = wr + i * 16 + (l & 15);
            int ch = (kk * 4 + (l >> 4)) ^ (l & 7);
            aoff[kk][i] = ar * 64 + ch * 8;
            int br = wc + i * 16 + (l & 15);
            boff[kk][i] = br * 64 + ch * 8;
        }

    for (int k0 = 0; k0 < K; k0 += 64) {
#pragma unroll
        for (int q = 0; q < 4; ++q) {
            int m = w * 4 + q;
            GLD16(gA[q] + k0, As + m * 512);
            GLD16(gB[q] + k0, Bs + m * 512);
        }
        __syncthreads();

        f16x8 af[2][4], bf[2][4];
#pragma unroll
        for (int kk = 0; kk < 2; ++kk)
#pragma unroll
            for (int i = 0; i < 4; ++i) {
                af[kk][i] = *(const f16x8*)(As + aoff[kk][i]);
                bf[kk][i] = *(const f16x8*)(Bs + boff[kk][i]);
            }
#pragma unroll
        for (int kk = 0; kk < 2; ++kk)
#pragma unroll
            for (int i = 0; i < 4; ++i)
#pragma unroll
                for (int j = 0; j < 4; ++j)
                    acc[i][j] = __builtin_amdgcn_mfma_f32_16x16x32_f16(
                        af[kk][i], bf[kk][j], acc[i][j], 0, 0, 0);
        __syncthreads();
    }

#pragma unroll
    for (int i = 0; i < 4; ++i) {
        int rowb = bm + wr + i * 16 + ((l >> 4) << 2);
#pragma unroll
        for (int j = 0; j < 4; ++j) {
            int col = bn + wc + j * 16 + (l & 15);
            float bv = bias[col];
#pragma unroll
            for (int r = 0; r < 4; ++r) {
                float v = acc[i][j][r] + bv;
                if (ACT) v = gelu_tanh(v);
                if (OUT16)
                    ((_Float16*)Cp)[(size_t)(rowb + r) * N + col] = (_Float16)v;
                else
                    ((float*)Cp)[(size_t)(rowb + r) * N + col] = v;
            }
        }
    }
}

// ---------------------------------------------------------------------------
// Attention core (r17): K dbuf f16 LDS; V j-paired f16; PV on fdot2; lsum
// from the f16 p values; setprio(1) around compute.
// ---------------------------------------------------------------------------
template<int NT, bool EDGE>
__device__ __forceinline__ void attn_block(
    const _Float16* __restrict__ qkv, const int* __restrict__ key_idx,
    _Float16* __restrict__ outp, float* __restrict__ pm,
    float* __restrict__ pl, float* __restrict__ pacc,
    int b, int h, int n, int split, int be,
    _Float16 (*qs)[72], _Float16 (*ks)[16][72],
    _Float16 (*vpl)[8][64][2], _Float16 (*ps16)[24])
{
    int t = threadIdx.x;
    int i = t >> 4;        // query row / staging row
    int c = t & 15;
    int c4 = c * 4;

    // stage Q tile; load tile 0 into registers
    *(f16x4*)&qs[i][c4] =
        *(const f16x4*)&qkv[((size_t)(b * S_ + n * BS_ + i)) * (3 * D_) + h * DH_ + c4];
    int kb0 = EDGE ? split * NT : key_idx[n * 7];
    const _Float16* kp0 = qkv + ((size_t)(b * S_ + kb0 * BS_ + i)) * (3 * D_) + D_ + h * DH_;
    f16x4 kr = *(const f16x4*)(kp0 + c4);
    f16x4 vr = *(const f16x4*)(kp0 + D_ + c4);
    __syncthreads();   // qs visible

    f16x8 qv[8];
#pragma unroll
    for (int d0 = 0; d0 < 8; ++d0) qv[d0] = *(const f16x8*)&qs[i][d0 * 8];

    // write tile 0 into buffer 0; prefetch tile 1
    *(f16x4*)&ks[0][i][c4] = kr;
#pragma unroll
    for (int u = 0; u < 4; ++u) vpl[0][i >> 1][c4 + u][i & 1] = vr[u];
    if (NT > 1) {
        int kb1 = EDGE ? (split * NT + 1) : key_idx[n * 7 + 1];
        const _Float16* kp1 = qkv + ((size_t)(b * S_ + kb1 * BS_ + i)) * (3 * D_) + D_ + h * DH_;
        kr = *(const f16x4*)(kp1 + c4);
        vr = *(const f16x4*)(kp1 + D_ + c4);
    }
    __syncthreads();   // buffer 0 staged

    float m_old = -1e30f, lsum = 0.f;
    float acc0 = 0.f, acc1 = 0.f, acc2 = 0.f, acc3 = 0.f;
    const f16x2 one2 = {(_Float16)1.f, (_Float16)1.f};

#pragma unroll 1
    for (int jj = 0; jj < NT; ++jj) {
        int cur = jj & 1;
        if (jj + 1 < NT) {
            *(f16x4*)&ks[cur ^ 1][i][c4] = kr;
#pragma unroll
            for (int u = 0; u < 4; ++u) vpl[cur ^ 1][i >> 1][c4 + u][i & 1] = vr[u];
        }
        if (jj + 2 < NT) {
            int kb2 = EDGE ? (split * NT + jj + 2) : key_idx[n * 7 + jj + 2];
            const _Float16* kp2 = qkv + ((size_t)(b * S_ + kb2 * BS_ + i)) * (3 * D_) + D_ + h * DH_;
            kr = *(const f16x4*)(kp2 + c4);
            vr = *(const f16x4*)(kp2 + D_ + c4);
        }

        __builtin_amdgcn_s_setprio(1);
        // score: <q_i, k_c> via fdot2 over b128 LDS reads
        float s0 = 0.f, s1 = 0.f;
#pragma unroll
        for (int d0 = 0; d0 < 8; ++d0) {
            f16x8 kv = *(const f16x8*)&ks[cur][c][d0 * 8];
            s0 = dot2acc(SV2(qv[d0], 0), SV2(kv, 0), s0);
            s1 = dot2acc(SV2(qv[d0], 2), SV2(kv, 2), s1);
            s0 = dot2acc(SV2(qv[d0], 4), SV2(kv, 4), s0);
            s1 = dot2acc(SV2(qv[d0], 6), SV2(kv, 6), s1);
        }
        float s = (s0 + s1) * SCALE_F;

        // row max (fp32, 16-lane shuffle); p in f16 via LDS
        float rm = s;
#pragma unroll
        for (int off = 8; off; off >>= 1) rm = fmaxf(rm, __shfl_xor(rm, off, 64));
        float m_new = fmaxf(m_old, rm);
        float p = __expf(s - m_new);

        ps16[i][c] = (_Float16)p;
        f16x8 plo = *(const f16x8*)&ps16[i][0];   // p0..p7  (jp 0..3)
        f16x8 phi = *(const f16x8*)&ps16[i][8];   // p8..p15 (jp 4..7)

        // row sum from the same f16 p values (no shuffle reduce)
        float rs = 0.f;
        rs = dot2acc(SV2(plo, 0), one2, rs);
        rs = dot2acc(SV2(plo, 2), one2, rs);
        rs = dot2acc(SV2(plo, 4), one2, rs);
        rs = dot2acc(SV2(plo, 6), one2, rs);
        rs = dot2acc(SV2(phi, 0), one2, rs);
        rs = dot2acc(SV2(phi, 2), one2, rs);
        rs = dot2acc(SV2(phi, 4), one2, rs);
        rs = dot2acc(SV2(phi, 6), one2, rs);

        float corr = __expf(m_old - m_new);
        lsum = lsum * corr + rs;
        acc0 *= corr; acc1 *= corr; acc2 *= corr; acc3 *= corr;

        // PV: V j-paired; fdot2 accumulation (literal shuffle indices)
#define PVJ(JP, PSRC, OFF)                                            \
        {                                                             \
            f16x8 vv = *(const f16x8*)&vpl[cur][JP][c4][0];           \
            f16x2 pp = SV2(PSRC, OFF);                                \
            acc0 = dot2acc(pp, SV2(vv, 0), acc0);                     \
            acc1 = dot2acc(pp, SV2(vv, 2), acc1);                     \
            acc2 = dot2acc(pp, SV2(vv, 4), acc2);                     \
            acc3 = dot2acc(pp, SV2(vv, 6), acc3);                     \
        }
        PVJ(0, plo, 0) PVJ(1, plo, 2) PVJ(2, plo, 4) PVJ(3, plo, 6)
        PVJ(4, phi, 0) PVJ(5, phi, 2) PVJ(6, phi, 4) PVJ(7, phi, 6)
#undef PVJ
        __builtin_amdgcn_s_setprio(0);
        m_old = m_new;
        __syncthreads();   // all reads of cur done; writes to cur^1 visible
    }

    if (EDGE) {
        int psx = (be * NSPLIT + split) * 16 + i;
        if (c == 0) { pm[psx] = m_old; pl[psx] = lsum; }
        float* pd = pacc + (size_t)psx * 64 + c4;
        pd[0] = acc0; pd[1] = acc1; pd[2] = acc2; pd[3] = acc3;
    } else {
        float inv = 1.f / lsum;
        _Float16* dst = outp + ((size_t)(b * S_ + n * BS_ + i)) * D_ + h * DH_ + c4;
        dst[0] = (_Float16)(acc0 * inv);
        dst[1] = (_Float16)(acc1 * inv);
        dst[2] = (_Float16)(acc2 * inv);
        dst[3] = (_Float16)(acc3 * inv);
    }
}

// ---------------------------------------------------------------------------
// Fused attention dispatch: sparse + edge split-K in one grid.
// ---------------------------------------------------------------------------
__global__ __launch_bounds__(256) void attn_fused(
    const _Float16* __restrict__ qkv, const int* __restrict__ key_idx,
    _Float16* __restrict__ outp, float* __restrict__ pm,
    float* __restrict__ pl, float* __restrict__ pacc)
{
    __shared__ __attribute__((aligned(16))) _Float16 qs[16][72];
    __shared__ __attribute__((aligned(16))) _Float16 ks[2][16][72];
    __shared__ __attribute__((aligned(16))) _Float16 vpl[2][8][64][2];
    __shared__ __attribute__((aligned(16))) _Float16 ps16[16][24];

    int bi = blockIdx.x;
    if (bi < NSPARSE) {
        int n = bi % NB_;
        if (n == 0 || n == NB_ - 1) return;
        int h = (bi / NB_) % H_;
        int b = bi / (NB_ * H_);
        attn_block<7, false>(qkv, key_idx, outp, nullptr, nullptr, nullptr,
                             b, h, n, 0, 0, qs, ks, vpl, ps16);
    } else {
        int ei = bi - NSPARSE;
        int split = ei % NSPLIT;
        int be = ei / NSPLIT;
        int e = be & 1;
        int h = (be >> 1) % H_;
        int b = be / (2 * H_);
        int n = e ? (NB_ - 1) : 0;
        attn_block<TILES_PER_SPLIT, true>(qkv, nullptr, nullptr, pm, pl, pacc,
                                          b, h, n, split, be, qs, ks, vpl, ps16);
    }
}

// ---------------------------------------------------------------------------
// Edge attention combine
// ---------------------------------------------------------------------------
__global__ __launch_bounds__(256) void attn_edge_combine(
    const float* __restrict__ pm, const float* __restrict__ pl,
    const float* __restrict__ pacc, _Float16* __restrict__ outp)
{
    int be = blockIdx.x;
    int e = be & 1;
    int h = (be >> 1) % H_;
    int b = be / (2 * H_);
    int n = e ? (NB_ - 1) : 0;

    int t = threadIdx.x;
    int i = t >> 4;
    int c = t & 15;

    float M = -1e30f;
#pragma unroll 4
    for (int s = 0; s < NSPLIT; ++s)
        M = fmaxf(M, pm[(be * NSPLIT + s) * 16 + i]);

    float L = 0.f;
    float acc[4] = {0.f, 0.f, 0.f, 0.f};
    for (int s = 0; s < NSPLIT; ++s) {
        int ps = (be * NSPLIT + s) * 16 + i;
        float wgt = __expf(pm[ps] - M);
        L += pl[ps] * wgt;
#pragma unroll
        for (int u = 0; u < 4; ++u) acc[u] += pacc[(size_t)ps * 64 + c * 4 + u] * wgt;
    }

    float inv = 1.f / L;
    _Float16* dst = outp + ((size_t)(b * S_ + n * BS_ + i)) * D_ + h * DH_ + c * 4;
#pragma unroll
    for (int u = 0; u < 4; ++u) dst[u] = (_Float16)(acc[u] * inv);
}

// ---------------------------------------------------------------------------
// LN (r18): residual stream in f16. xh = LN(xh + g) (stats in f32).
// WRITE32: additionally write the f32 row (only the FINAL LN, for heads).
// ---------------------------------------------------------------------------
template<int WRITE32>
__global__ __launch_bounds__(256) void add_ln_kernel(
    _Float16* __restrict__ xh, const _Float16* __restrict__ g,
    const float* __restrict__ gamma, const float* __restrict__ beta,
    float* __restrict__ x32)
{
    int row = blockIdx.x;
    int t = threadIdx.x;
    _Float16* xr = xh + (size_t)row * D_;
    const _Float16* gr = g + (size_t)row * D_;

    float v[3];
    float s = 0.f, s2 = 0.f;
#pragma unroll
    for (int r = 0; r < 3; ++r) {
        int d = t + 256 * r;
        v[r] = (float)xr[d] + (float)gr[d];
        s += v[r];
        s2 += v[r] * v[r];
    }
#pragma unroll
    for (int off = 32; off; off >>= 1) {
        s  += __shfl_xor(s, off, 64);
        s2 += __shfl_xor(s2, off, 64);
    }
    __shared__ float sA[4], sB[4];
    int wave = t >> 6, lane = t & 63;
    if (lane == 0) { sA[wave] = s; sB[wave] = s2; }
    __syncthreads();
    s  = sA[0] + sA[1] + sA[2] + sA[3];
    s2 = sB[0] + sB[1] + sB[2] + sB[3];
    float mean = s * (1.0f / D_);
    float var = s2 * (1.0f / D_) - mean * mean;
    float rstd = rsqrtf(var + 1e-12f);
#pragma unroll
    for (int r = 0; r < 3; ++r) {
        int d = t + 256 * r;
        float o = (v[r] - mean) * rstd * gamma[d] + beta[d];
        xr[d] = (_Float16)o;
        if (WRITE32) x32[(size_t)row * D_ + d] = o;
    }
}

// ---------------------------------------------------------------------------
// Fused heads: blockIdx < 2048 -> start/end logits; else disc pool partial.
// (reads the f32 x written by the final LN — head precision unchanged)
// ---------------------------------------------------------------------------
__global__ __launch_bounds__(256) void heads_fused(
    const float* __restrict__ x, const float* __restrict__ sw,
    const float* __restrict__ ew, const float* __restrict__ Wp,
    float* __restrict__ sl, float* __restrict__ el,
    float* __restrict__ partial)
{
    int bi = blockIdx.x;
    int t = threadIdx.x;
    if (bi < 2048) {
        int wave = t >> 6, lane = t & 63;
        int row = bi * 4 + wave;
        const float* xr = x + (size_t)row * D_;
        float a = 0.f, e = 0.f;
        for (int d = lane; d < D_; d += 64) {
            float xv = xr[d];
            a += xv * sw[d];
            e += xv * ew[d];
        }
#pragma unroll
        for (int off = 32; off; off >>= 1) {
            a += __shfl_xor(a, off, 64);
            e += __shfl_xor(e, off, 64);
        }
        if (lane == 0) { sl[row] = a; el[row] = e; }
    } else {
        int ei = bi - 2048;       // 0..23
        int jb = ei % 3;          // 0..2
        int ks = ei / 3;          // 0..7
        int j = jb * 256 + t;
        int k0 = ks * DKC;

        __shared__ float xs[DKC];
        if (t < DKC) xs[t] = x[k0 + t];   // x0 = x row 0
        __syncthreads();

        float s = 0.f;
#pragma unroll 8
        for (int kk = 0; kk < DKC; ++kk)
            s += xs[kk] * Wp[(size_t)(k0 + kk) * D_ + j];
        partial[ks * D_ + j] = s;
    }
}

// ---------------------------------------------------------------------------
// Fused final: r<4 -> softmax over S; r==4 -> disc finish.
// ---------------------------------------------------------------------------
__global__ __launch_bounds__(256) void final_fused(
    const float* __restrict__ sl, const float* __restrict__ el,
    const float* __restrict__ partial, const float* __restrict__ bp,
    const float* __restrict__ d1W, const float* __restrict__ d1b,
    const float* __restrict__ d2W, const float* __restrict__ d2b,
    float* __restrict__ outp)
{
    int r = blockIdx.x;
    int t = threadIdx.x;
    if (r < 4) {
        const float* src = (r < 2 ? sl : el) + (size_t)(r & 1) * S_;
        float* dst = outp + (r < 2 ? 0 : BT_) + (size_t)(r & 1) * S_;
        int wave = t >> 6, lane = t & 63;
        __shared__ float sm[4], ss[4];

        float m = -1e30f;
        for (int k = t; k < S_; k += 256) m = fmaxf(m, src[k]);
#pragma unroll
        for (int off = 32; off; off >>= 1) m = fmaxf(m, __shfl_xor(m, off, 64));
        if (lane == 0) sm[wave] = m;
        __syncthreads();
        m = fmaxf(fmaxf(sm[0], sm[1]), fmaxf(sm[2], sm[3]));

        float s = 0.f;
        for (int k = t; k < S_; k += 256) s += __expf(src[k] - m);
#pragma unroll
        for (int off = 32; off; off >>= 1) s += __shfl_xor(s, off, 64);
        if (lane == 0) ss[wave] = s;
        __syncthreads();
        s = ss[0] + ss[1] + ss[2] + ss[3];

        float inv = 1.f / s;
        for (int k = t; k < S_; k += 256) dst[k] = __expf(src[k] - m) * inv;
    } else {
        __shared__ float pool[D_];
        __shared__ float h1[20];
        float* out2 = outp + 2 * BT_;
        for (int j = t; j < D_; j += 256) {
            float s = bp[j];
#pragma unroll
            for (int ks = 0; ks < DKS; ++ks) s += partial[ks * D_ + j];
            pool[j] = tanhf(s);
        }
        __syncthreads();
        if (t < 20) {
            float s = d1b[t];
            for (int k = 0; k < D_; ++k) s += pool[k] * d1W[k * 20 + t];
            h1[t] = s;
        }
        __syncthreads();
        if (t == 0) {
            float d0 = d2b[0], d1v = d2b[1];
#pragma unroll
            for (int u = 0; u < 20; ++u) {
                d0  += h1[u] * d2W[u * 2 + 0];
                d1v += h1[u] * d2W[u * 2 + 1];
            }
            float m = fmaxf(d0, d1v);
            float e0 = __expf(d0 - m), e1 = __expf(d1v - m);
            float inv = 1.f / (e0 + e1);
            out2[0] = e0 * inv;
            out2[1] = e1 * inv;
        }
    }
}

// ---------------------------------------------------------------------------
extern "C" void kernel_launch(void* const* d_in, const int* in_sizes, int n_in,
                              void* d_out, int out_size, void* d_ws, size_t ws_size,
                              hipStream_t stream)
{
    const int*   ids   = (const int*)d_in[0];
    const int*   kbi   = (const int*)d_in[1];
    const float* emb   = (const float*)d_in[2];
    const float* Wqkv  = (const float*)d_in[3];
    const float* bqkv  = (const float*)d_in[4];
    const float* Wo    = (const float*)d_in[5];
    const float* bo    = (const float*)d_in[6];
    const float* ln1g  = (const float*)d_in[7];
    const float* ln1b  = (const float*)d_in[8];
    const float* Wff1  = (const float*)d_in[9];
    const float* bff1  = (const float*)d_in[10];
    const float* Wff2  = (const float*)d_in[11];
    const float* bff2  = (const float*)d_in[12];
    const float* ln2g  = (const float*)d_in[13];
    const float* ln2b  = (const float*)d_in[14];
    const float* Wp    = (const float*)d_in[15];
    const float* bp    = (const float*)d_in[16];
    const float* sw    = (const float*)d_in[17];
    const float* ew    = (const float*)d_in[18];
    const float* d1W   = (const float*)d_in[19];
    const float* d1b   = (const float*)d_in[20];
    const float* d2W   = (const float*)d_in[21];
    const float* d2b   = (const float*)d_in[22];
    float* outp = (float*)d_out;

    // workspace carve (float units)
    float* ws   = (float*)d_ws;
    float* x    = ws;                          // BT_*D_ f32 (final LN only)
    float* xbf  = x   + (size_t)BT_ * D_;      // f16 xh (residual stream)
    float* r1f  = xbf + (size_t)BT_ * D_ / 2;  // f16 qkv / f16 h
    float* abf  = r1f + (size_t)BT_ * FF_ / 2; // f16 attn out
    float* r2   = abf + (size_t)BT_ * D_ / 2;  // partials (early) / f16 g (late)
    float* wtf  = r2  + (size_t)BT_ * D_;      // f16 weights
    float* sl   = wtf + 7077888;
    float* el   = sl  + BT_;
    float* dpar = el  + BT_;                   // DKS * D_ disc partials

    _Float16* xh    = (_Float16*)xbf;
    _Float16* qkv16 = (_Float16*)r1f;
    _Float16* h16   = (_Float16*)r1f;
    _Float16* ab    = (_Float16*)abf;
    float* pm   = r2;
    float* pl   = r2 + NEDGE * NSPLIT * 16;
    float* pacc = pl + NEDGE * NSPLIT * 16;
    _Float16* g16 = (_Float16*)r2;   // aliased; partials dead once proj runs

    _Float16* Wt    = (_Float16*)wtf;
    _Float16* WqkvT = Wt;
    _Float16* WoT   = WqkvT + (size_t)2 * 2304 * 768;
    _Float16* Wff1T = WoT   + (size_t)2 * 768 * 768;
    _Float16* Wff2T = Wff1T + (size_t)2 * 3072 * 768;

    // fused weight convert + embed: one dispatch
    WSegs segs;
    int start = 0;
    for (int l = 0; l < 2; ++l) {
        int base = l * 4;
        segs.s[base + 0] = { Wqkv + (size_t)l * 768 * 2304,
                             WqkvT + (size_t)l * 2304 * 768, 768, 2304, start };
        start += (2304 / 32) * (768 / 32);
        segs.s[base + 1] = { Wo + (size_t)l * 768 * 768,
                             WoT + (size_t)l * 768 * 768, 768, 768, start };
        start += (768 / 32) * (768 / 32);
        segs.s[base + 2] = { Wff1 + (size_t)l * 768 * 3072,
                             Wff1T + (size_t)l * 3072 * 768, 768, 3072, start };
        start += (3072 / 32) * (768 / 32);
        segs.s[base + 3] = { Wff2 + (size_t)l * 3072 * 768,
                             Wff2T + (size_t)l * 768 * 3072, 3072, 768, start };
        start += (768 / 32) * (3072 / 32);
    }
    segs.total = start;   // 13824

    prep_all<<<segs.total + BT_, 256, 0, stream>>>(segs, ids, emb, xh);

    for (int l = 0; l < 2; ++l) {
        gemm_f16<0,1><<<dim3(2304/128, BT_/128), 256, 0, stream>>>(
            xh, WqkvT + (size_t)l * 2304 * 768, bqkv + (size_t)l * 3 * D_,
            qkv16, BT_, 3 * D_, D_);
        attn_fused<<<NSPARSE + NEDGE * NSPLIT, 256, 0, stream>>>(
            qkv16, kbi, ab, pm, pl, pacc);
        attn_edge_combine<<<NEDGE, 256, 0, stream>>>(pm, pl, pacc, ab);
        gemm_f16<0,1><<<dim3(768/128, BT_/128), 256, 0, stream>>>(
            ab, WoT + (size_t)l * 768 * 768, bo + (size_t)l * D_,
            g16, BT_, D_, D_);
        add_ln_kernel<0><<<BT_, 256, 0, stream>>>(
            xh, g16, ln1g + (size_t)l * D_, ln1b + (size_t)l * D_, nullptr);
        gemm_f16<1,1><<<dim3(3072/128, BT_/128), 256, 0, stream>>>(
            xh, Wff1T + (size_t)l * 3072 * 768, bff1 + (size_t)l * FF_,
            h16, BT_, FF_, D_);
        gemm_f16<0,1><<<dim3(768/128, BT_/128), 256, 0, stream>>>(
            h16, Wff2T + (size_t)l * 768 * 3072, bff2 + (size_t)l * D_,
            g16, BT_, D_, FF_);
        if (l == 1)
            add_ln_kernel<1><<<BT_, 256, 0, stream>>>(
                xh, g16, ln2g + (size_t)l * D_, ln2b + (size_t)l * D_, x);
        else
            add_ln_kernel<0><<<BT_, 256, 0, stream>>>(
                xh, g16, ln2g + (size_t)l * D_, ln2b + (size_t)l * D_, nullptr);
    }

    heads_fused<<<2048 + 3 * DKS, 256, 0, stream>>>(x, sw, ew, Wp, sl, el, dpar);
    final_fused<<<5, 256, 0, stream>>>(sl, el, dpar, bp, d1W, d1b, d2W, d2b, outp);
}

// Round 20
// 638.350 us; speedup vs baseline: 1.2146x; 1.0541x over previous
//
#include <hip/hip_runtime.h>
#include <hip/hip_bf16.h>
#include <math.h>

#define B_   2
#define S_   4096
#define D_   768
#define H_   12
#define DH_  64
#define BS_  16
#define NB_  256
#define FF_  3072
#define BT_  (B_ * S_)          // 8192 token rows
#define SCALE_F 0.125f          // 1/sqrt(64)

#define NSPLIT 32               // key-dimension splits for edge attention
#define TILES_PER_SPLIT (NB_ / NSPLIT)   // 8
#define NEDGE (B_ * H_ * 2)     // 48 edge (b,h,e) groups
#define NSPARSE (B_ * H_ * NB_) // 6144 sparse blocks

#define DKS 8                   // disc pool k-splits
#define DKC (D_ / DKS)          // 96 rows per split

typedef _Float16 f16x8 __attribute__((ext_vector_type(8)));
typedef _Float16 f16x4 __attribute__((ext_vector_type(4)));
typedef _Float16 f16x2 __attribute__((ext_vector_type(2)));
typedef float    f32x4 __attribute__((ext_vector_type(4)));
typedef float    f32x16 __attribute__((ext_vector_type(16)));

#define SV2(v, k) __builtin_shufflevector(v, v, k, (k) + 1)

__device__ __forceinline__ float dot2acc(f16x2 a, f16x2 b, float c)
{
#if __has_builtin(__builtin_amdgcn_fdot2)
    return __builtin_amdgcn_fdot2(a, b, c, false);
#else
    return c + (float)a[0] * (float)b[0] + (float)a[1] * (float)b[1];
#endif
}

// async global->LDS, 16B per lane; LDS dest is wave-uniform base + lane*16
#define GLD16(gp, lp) __builtin_amdgcn_global_load_lds( \
    (const __attribute__((address_space(1))) void*)(gp), \
    (__attribute__((address_space(3))) void*)(lp), 16, 0, 0)

__device__ __forceinline__ float fast_tanh(float z)
{
    float az = fabsf(z);
    float t = __expf(-2.0f * az);
    float r = (1.0f - t) / (1.0f + t);
    return z < 0.f ? -r : r;
}

__device__ __forceinline__ float gelu_tanh(float v)
{
    float v3 = v * v * v;
    return 0.5f * v * (1.0f + fast_tanh(0.79788456080286535588f * (v + 0.044715f * v3)));
}

// ---------------------------------------------------------------------------
// Fused weight convert + embedding (r19: vectorized transpose — f32x4 reads,
// single read pass + single write pass).
// ---------------------------------------------------------------------------
struct WSeg { const float* src; _Float16* dst; int K; int N; int start; };
struct WSegs { WSeg s[8]; int total; };

__global__ __launch_bounds__(256) void prep_all(
    WSegs segs, const int* __restrict__ ids, const float* __restrict__ emb,
    _Float16* __restrict__ xh)
{
    int bt = blockIdx.x;
    int t = threadIdx.x;
    if (bt < segs.total) {
        __shared__ float tile[32][33];
        int si = 0;
#pragma unroll
        for (int u = 1; u < 8; ++u)
            if (bt >= segs.s[u].start) si = u;
        const WSeg& sg = segs.s[si];
        int tid = bt - sg.start;
        int tn = sg.N >> 5;
        int n0 = (tid % tn) * 32;
        int k0 = (tid / tn) * 32;

        // read: row r = t>>3 (0..31), cols (t&7)*4 .. +3 (f32x4)
        {
            int r = t >> 3, c = (t & 7) * 4;
            f32x4 v = *(const f32x4*)&sg.src[(size_t)(k0 + r) * sg.N + n0 + c];
            tile[r][c + 0] = v[0];
            tile[r][c + 1] = v[1];
            tile[r][c + 2] = v[2];
            tile[r][c + 3] = v[3];
        }
        __syncthreads();
        // write: n-row = t>>3, k-cols (t&7)*4 .. +3 (f16x4 = 8B store)
        {
            int r = t >> 3, c = (t & 7) * 4;
            f16x4 o;
            o[0] = (_Float16)tile[c + 0][r];
            o[1] = (_Float16)tile[c + 1][r];
            o[2] = (_Float16)tile[c + 2][r];
            o[3] = (_Float16)tile[c + 3][r];
            *(f16x4*)&sg.dst[(size_t)(n0 + r) * sg.K + k0 + c] = o;
        }
    } else {
        int row = bt - segs.total;
        int id = ids[row];
        const float* src = emb + (size_t)id * D_;
        _Float16* dst16 = xh + (size_t)row * D_;
        for (int d = t; d < D_; d += 256)
            dst16[d] = (_Float16)src[d];
    }
}

// ---------------------------------------------------------------------------
// MFMA fp16 GEMM (r19): 32x32x16 MFMA. C = A[M,K] @ Wt[N,K]^T + bias.
// 128x128 block, BK=64, 4 waves (2x2), wave tile 64x64 = 2x2 frags of 32x32.
// Same staging + chunk-XOR swizzle as r8 (row&7 == l&7 since bases are
// multiples of 32). Per BK-tile: 16 b128 LDS reads (same as r8) but only
// 16 MFMA (vs 32) at the faster 32x32 rate (2382 vs 2075 TF ubench).
// A/B frag: row/col = l&31, k-group = l>>5, 8 f16 each.
// C/D (guide m74/m101): col = l&31, row = (r&3) + 8*(r>>2) + 4*(l>>5).
// ---------------------------------------------------------------------------
template<int ACT, int OUT16>
__global__ __launch_bounds__(256) void gemm_f16(
    const _Float16* __restrict__ A, const _Float16* __restrict__ Wt,
    const float* __restrict__ bias, void* __restrict__ Cp,
    int M, int N, int K)
{
    __shared__ __attribute__((aligned(16))) _Float16 As[128 * 64];
    __shared__ __attribute__((aligned(16))) _Float16 Bs[128 * 64];

    int t = threadIdx.x;
    int w = t >> 6, l = t & 63;
    int bm = blockIdx.y * 128, bn = blockIdx.x * 128;
    int wr = (w >> 1) * 64, wc = (w & 1) * 64;

    f32x16 acc[2][2];
#pragma unroll
    for (int i = 0; i < 2; ++i)
#pragma unroll
        for (int j = 0; j < 2; ++j)
#pragma unroll
            for (int r = 0; r < 16; ++r) acc[i][j][r] = 0.f;

    // staging: wave w owns 1KB chunks {4w..4w+3} of each 16KB tile.
    const _Float16* gA[4];
    const _Float16* gB[4];
#pragma unroll
    for (int q = 0; q < 4; ++q) {
        int m = w * 4 + q;
        int row = m * 8 + (l >> 3);
        int sc = (l & 7) ^ (row & 7);
        gA[q] = A  + (size_t)(bm + row) * K + sc * 8;
        gB[q] = Wt + (size_t)(bn + row) * K + sc * 8;
    }

    // fragment LDS offsets: 4 kk-steps of K=16.
    // row = base + (l&31) (base mult of 32 -> row&7 == l&7);
    // chunk = (kk*2 + (l>>5)) ^ (l&7)
    int aoff[4][2], boff[4][2];
#pragma unroll
    for (int kk = 0; kk < 4; ++kk) {
        int ch = (kk * 2 + (l >> 5)) ^ (l & 7);
#pragma unroll
        for (int f = 0; f < 2; ++f) {
            aoff[kk][f] = (wr + f * 32 + (l & 31)) * 64 + ch * 8;
            boff[kk][f] = (wc + f * 32 + (l & 31)) * 64 + ch * 8;
        }
    }

    for (int k0 = 0; k0 < K; k0 += 64) {
#pragma unroll
        for (int q = 0; q < 4; ++q) {
            int m = w * 4 + q;
            GLD16(gA[q] + k0, As + m * 512);
            GLD16(gB[q] + k0, Bs + m * 512);
        }
        __syncthreads();

#pragma unroll
        for (int kk = 0; kk < 4; ++kk) {
            f16x8 af[2], bf[2];
#pragma unroll
            for (int f = 0; f < 2; ++f) {
                af[f] = *(const f16x8*)(As + aoff[kk][f]);
                bf[f] = *(const f16x8*)(Bs + boff[kk][f]);
            }
#pragma unroll
            for (int i = 0; i < 2; ++i)
#pragma unroll
                for (int j = 0; j < 2; ++j)
                    acc[i][j] = __builtin_amdgcn_mfma_f32_32x32x16_f16(
                        af[i], bf[j], acc[i][j], 0, 0, 0);
        }
        __syncthreads();
    }

    // epilogue: col = bn+wc+fj*32+(l&31); rows = bm+wr+fi*32+8*rg+4*(l>>5)+0..3
#pragma unroll
    for (int i = 0; i < 2; ++i) {
#pragma unroll
        for (int j = 0; j < 2; ++j) {
            int col = bn + wc + j * 32 + (l & 31);
            float bv = bias[col];
#pragma unroll
            for (int rg = 0; rg < 4; ++rg) {
                int row0 = bm + wr + i * 32 + 8 * rg + 4 * (l >> 5);
#pragma unroll
                for (int r = 0; r < 4; ++r) {
                    float v = acc[i][j][rg * 4 + r] + bv;
                    if (ACT) v = gelu_tanh(v);
                    if (OUT16)
                        ((_Float16*)Cp)[(size_t)(row0 + r) * N + col] = (_Float16)v;
                    else
                        ((float*)Cp)[(size_t)(row0 + r) * N + col] = v;
                }
            }
        }
    }
}

// ---------------------------------------------------------------------------
// Attention core (r17): K dbuf f16 LDS; V j-paired f16; PV on fdot2; lsum
// from the f16 p values; setprio(1) around compute.
// ---------------------------------------------------------------------------
template<int NT, bool EDGE>
__device__ __forceinline__ void attn_block(
    const _Float16* __restrict__ qkv, const int* __restrict__ key_idx,
    _Float16* __restrict__ outp, float* __restrict__ pm,
    float* __restrict__ pl, float* __restrict__ pacc,
    int b, int h, int n, int split, int be,
    _Float16 (*qs)[72], _Float16 (*ks)[16][72],
    _Float16 (*vpl)[8][64][2], _Float16 (*ps16)[24])
{
    int t = threadIdx.x;
    int i = t >> 4;        // query row / staging row
    int c = t & 15;
    int c4 = c * 4;

    // stage Q tile; load tile 0 into registers
    *(f16x4*)&qs[i][c4] =
        *(const f16x4*)&qkv[((size_t)(b * S_ + n * BS_ + i)) * (3 * D_) + h * DH_ + c4];
    int kb0 = EDGE ? split * NT : key_idx[n * 7];
    const _Float16* kp0 = qkv + ((size_t)(b * S_ + kb0 * BS_ + i)) * (3 * D_) + D_ + h * DH_;
    f16x4 kr = *(const f16x4*)(kp0 + c4);
    f16x4 vr = *(const f16x4*)(kp0 + D_ + c4);
    __syncthreads();   // qs visible

    f16x8 qv[8];
#pragma unroll
    for (int d0 = 0; d0 < 8; ++d0) qv[d0] = *(const f16x8*)&qs[i][d0 * 8];

    // write tile 0 into buffer 0; prefetch tile 1
    *(f16x4*)&ks[0][i][c4] = kr;
#pragma unroll
    for (int u = 0; u < 4; ++u) vpl[0][i >> 1][c4 + u][i & 1] = vr[u];
    if (NT > 1) {
        int kb1 = EDGE ? (split * NT + 1) : key_idx[n * 7 + 1];
        const _Float16* kp1 = qkv + ((size_t)(b * S_ + kb1 * BS_ + i)) * (3 * D_) + D_ + h * DH_;
        kr = *(const f16x4*)(kp1 + c4);
        vr = *(const f16x4*)(kp1 + D_ + c4);
    }
    __syncthreads();   // buffer 0 staged

    float m_old = -1e30f, lsum = 0.f;
    float acc0 = 0.f, acc1 = 0.f, acc2 = 0.f, acc3 = 0.f;
    const f16x2 one2 = {(_Float16)1.f, (_Float16)1.f};

#pragma unroll 1
    for (int jj = 0; jj < NT; ++jj) {
        int cur = jj & 1;
        if (jj + 1 < NT) {
            *(f16x4*)&ks[cur ^ 1][i][c4] = kr;
#pragma unroll
            for (int u = 0; u < 4; ++u) vpl[cur ^ 1][i >> 1][c4 + u][i & 1] = vr[u];
        }
        if (jj + 2 < NT) {
            int kb2 = EDGE ? (split * NT + jj + 2) : key_idx[n * 7 + jj + 2];
            const _Float16* kp2 = qkv + ((size_t)(b * S_ + kb2 * BS_ + i)) * (3 * D_) + D_ + h * DH_;
            kr = *(const f16x4*)(kp2 + c4);
            vr = *(const f16x4*)(kp2 + D_ + c4);
        }

        __builtin_amdgcn_s_setprio(1);
        // score: <q_i, k_c> via fdot2 over b128 LDS reads
        float s0 = 0.f, s1 = 0.f;
#pragma unroll
        for (int d0 = 0; d0 < 8; ++d0) {
            f16x8 kv = *(const f16x8*)&ks[cur][c][d0 * 8];
            s0 = dot2acc(SV2(qv[d0], 0), SV2(kv, 0), s0);
            s1 = dot2acc(SV2(qv[d0], 2), SV2(kv, 2), s1);
            s0 = dot2acc(SV2(qv[d0], 4), SV2(kv, 4), s0);
            s1 = dot2acc(SV2(qv[d0], 6), SV2(kv, 6), s1);
        }
        float s = (s0 + s1) * SCALE_F;

        // row max (fp32, 16-lane shuffle); p in f16 via LDS
        float rm = s;
#pragma unroll
        for (int off = 8; off; off >>= 1) rm = fmaxf(rm, __shfl_xor(rm, off, 64));
        float m_new = fmaxf(m_old, rm);
        float p = __expf(s - m_new);

        ps16[i][c] = (_Float16)p;
        f16x8 plo = *(const f16x8*)&ps16[i][0];   // p0..p7  (jp 0..3)
        f16x8 phi = *(const f16x8*)&ps16[i][8];   // p8..p15 (jp 4..7)

        // row sum from the same f16 p values (no shuffle reduce)
        float rs = 0.f;
        rs = dot2acc(SV2(plo, 0), one2, rs);
        rs = dot2acc(SV2(plo, 2), one2, rs);
        rs = dot2acc(SV2(plo, 4), one2, rs);
        rs = dot2acc(SV2(plo, 6), one2, rs);
        rs = dot2acc(SV2(phi, 0), one2, rs);
        rs = dot2acc(SV2(phi, 2), one2, rs);
        rs = dot2acc(SV2(phi, 4), one2, rs);
        rs = dot2acc(SV2(phi, 6), one2, rs);

        float corr = __expf(m_old - m_new);
        lsum = lsum * corr + rs;
        acc0 *= corr; acc1 *= corr; acc2 *= corr; acc3 *= corr;

        // PV: V j-paired; fdot2 accumulation (literal shuffle indices)
#define PVJ(JP, PSRC, OFF)                                            \
        {                                                             \
            f16x8 vv = *(const f16x8*)&vpl[cur][JP][c4][0];           \
            f16x2 pp = SV2(PSRC, OFF);                                \
            acc0 = dot2acc(pp, SV2(vv, 0), acc0);                     \
            acc1 = dot2acc(pp, SV2(vv, 2), acc1);                     \
            acc2 = dot2acc(pp, SV2(vv, 4), acc2);                     \
            acc3 = dot2acc(pp, SV2(vv, 6), acc3);                     \
        }
        PVJ(0, plo, 0) PVJ(1, plo, 2) PVJ(2, plo, 4) PVJ(3, plo, 6)
        PVJ(4, phi, 0) PVJ(5, phi, 2) PVJ(6, phi, 4) PVJ(7, phi, 6)
#undef PVJ
        __builtin_amdgcn_s_setprio(0);
        m_old = m_new;
        __syncthreads();   // all reads of cur done; writes to cur^1 visible
    }

    if (EDGE) {
        int psx = (be * NSPLIT + split) * 16 + i;
        if (c == 0) { pm[psx] = m_old; pl[psx] = lsum; }
        float* pd = pacc + (size_t)psx * 64 + c4;
        pd[0] = acc0; pd[1] = acc1; pd[2] = acc2; pd[3] = acc3;
    } else {
        float inv = 1.f / lsum;
        _Float16* dst = outp + ((size_t)(b * S_ + n * BS_ + i)) * D_ + h * DH_ + c4;
        dst[0] = (_Float16)(acc0 * inv);
        dst[1] = (_Float16)(acc1 * inv);
        dst[2] = (_Float16)(acc2 * inv);
        dst[3] = (_Float16)(acc3 * inv);
    }
}

// ---------------------------------------------------------------------------
// Fused attention dispatch: sparse + edge split-K in one grid.
// ---------------------------------------------------------------------------
__global__ __launch_bounds__(256) void attn_fused(
    const _Float16* __restrict__ qkv, const int* __restrict__ key_idx,
    _Float16* __restrict__ outp, float* __restrict__ pm,
    float* __restrict__ pl, float* __restrict__ pacc)
{
    __shared__ __attribute__((aligned(16))) _Float16 qs[16][72];
    __shared__ __attribute__((aligned(16))) _Float16 ks[2][16][72];
    __shared__ __attribute__((aligned(16))) _Float16 vpl[2][8][64][2];
    __shared__ __attribute__((aligned(16))) _Float16 ps16[16][24];

    int bi = blockIdx.x;
    if (bi < NSPARSE) {
        int n = bi % NB_;
        if (n == 0 || n == NB_ - 1) return;
        int h = (bi / NB_) % H_;
        int b = bi / (NB_ * H_);
        attn_block<7, false>(qkv, key_idx, outp, nullptr, nullptr, nullptr,
                             b, h, n, 0, 0, qs, ks, vpl, ps16);
    } else {
        int ei = bi - NSPARSE;
        int split = ei % NSPLIT;
        int be = ei / NSPLIT;
        int e = be & 1;
        int h = (be >> 1) % H_;
        int b = be / (2 * H_);
        int n = e ? (NB_ - 1) : 0;
        attn_block<TILES_PER_SPLIT, true>(qkv, nullptr, nullptr, pm, pl, pacc,
                                          b, h, n, split, be, qs, ks, vpl, ps16);
    }
}

// ---------------------------------------------------------------------------
// Edge attention combine
// ---------------------------------------------------------------------------
__global__ __launch_bounds__(256) void attn_edge_combine(
    const float* __restrict__ pm, const float* __restrict__ pl,
    const float* __restrict__ pacc, _Float16* __restrict__ outp)
{
    int be = blockIdx.x;
    int e = be & 1;
    int h = (be >> 1) % H_;
    int b = be / (2 * H_);
    int n = e ? (NB_ - 1) : 0;

    int t = threadIdx.x;
    int i = t >> 4;
    int c = t & 15;

    float M = -1e30f;
#pragma unroll 4
    for (int s = 0; s < NSPLIT; ++s)
        M = fmaxf(M, pm[(be * NSPLIT + s) * 16 + i]);

    float L = 0.f;
    float acc[4] = {0.f, 0.f, 0.f, 0.f};
    for (int s = 0; s < NSPLIT; ++s) {
        int ps = (be * NSPLIT + s) * 16 + i;
        float wgt = __expf(pm[ps] - M);
        L += pl[ps] * wgt;
#pragma unroll
        for (int u = 0; u < 4; ++u) acc[u] += pacc[(size_t)ps * 64 + c * 4 + u] * wgt;
    }

    float inv = 1.f / L;
    _Float16* dst = outp + ((size_t)(b * S_ + n * BS_ + i)) * D_ + h * DH_ + c * 4;
#pragma unroll
    for (int u = 0; u < 4; ++u) dst[u] = (_Float16)(acc[u] * inv);
}

// ---------------------------------------------------------------------------
// LN (r18): residual stream in f16. xh = LN(xh + g) (stats in f32).
// WRITE32: additionally write the f32 row (only the FINAL LN, for heads).
// ---------------------------------------------------------------------------
template<int WRITE32>
__global__ __launch_bounds__(256) void add_ln_kernel(
    _Float16* __restrict__ xh, const _Float16* __restrict__ g,
    const float* __restrict__ gamma, const float* __restrict__ beta,
    float* __restrict__ x32)
{
    int row = blockIdx.x;
    int t = threadIdx.x;
    _Float16* xr = xh + (size_t)row * D_;
    const _Float16* gr = g + (size_t)row * D_;

    float v[3];
    float s = 0.f, s2 = 0.f;
#pragma unroll
    for (int r = 0; r < 3; ++r) {
        int d = t + 256 * r;
        v[r] = (float)xr[d] + (float)gr[d];
        s += v[r];
        s2 += v[r] * v[r];
    }
#pragma unroll
    for (int off = 32; off; off >>= 1) {
        s  += __shfl_xor(s, off, 64);
        s2 += __shfl_xor(s2, off, 64);
    }
    __shared__ float sA[4], sB[4];
    int wave = t >> 6, lane = t & 63;
    if (lane == 0) { sA[wave] = s; sB[wave] = s2; }
    __syncthreads();
    s  = sA[0] + sA[1] + sA[2] + sA[3];
    s2 = sB[0] + sB[1] + sB[2] + sB[3];
    float mean = s * (1.0f / D_);
    float var = s2 * (1.0f / D_) - mean * mean;
    float rstd = rsqrtf(var + 1e-12f);
#pragma unroll
    for (int r = 0; r < 3; ++r) {
        int d = t + 256 * r;
        float o = (v[r] - mean) * rstd * gamma[d] + beta[d];
        xr[d] = (_Float16)o;
        if (WRITE32) x32[(size_t)row * D_ + d] = o;
    }
}

// ---------------------------------------------------------------------------
// Fused heads: blockIdx < 2048 -> start/end logits; else disc pool partial.
// ---------------------------------------------------------------------------
__global__ __launch_bounds__(256) void heads_fused(
    const float* __restrict__ x, const float* __restrict__ sw,
    const float* __restrict__ ew, const float* __restrict__ Wp,
    float* __restrict__ sl, float* __restrict__ el,
    float* __restrict__ partial)
{
    int bi = blockIdx.x;
    int t = threadIdx.x;
    if (bi < 2048) {
        int wave = t >> 6, lane = t & 63;
        int row = bi * 4 + wave;
        const float* xr = x + (size_t)row * D_;
        float a = 0.f, e = 0.f;
        for (int d = lane; d < D_; d += 64) {
            float xv = xr[d];
            a += xv * sw[d];
            e += xv * ew[d];
        }
#pragma unroll
        for (int off = 32; off; off >>= 1) {
            a += __shfl_xor(a, off, 64);
            e += __shfl_xor(e, off, 64);
        }
        if (lane == 0) { sl[row] = a; el[row] = e; }
    } else {
        int ei = bi - 2048;       // 0..23
        int jb = ei % 3;          // 0..2
        int ks = ei / 3;          // 0..7
        int j = jb * 256 + t;
        int k0 = ks * DKC;

        __shared__ float xs[DKC];
        if (t < DKC) xs[t] = x[k0 + t];   // x0 = x row 0
        __syncthreads();

        float s = 0.f;
#pragma unroll 8
        for (int kk = 0; kk < DKC; ++kk)
            s += xs[kk] * Wp[(size_t)(k0 + kk) * D_ + j];
        partial[ks * D_ + j] = s;
    }
}

// ---------------------------------------------------------------------------
// Fused final: r<4 -> softmax over S; r==4 -> disc finish.
// ---------------------------------------------------------------------------
__global__ __launch_bounds__(256) void final_fused(
    const float* __restrict__ sl, const float* __restrict__ el,
    const float* __restrict__ partial, const float* __restrict__ bp,
    const float* __restrict__ d1W, const float* __restrict__ d1b,
    const float* __restrict__ d2W, const float* __restrict__ d2b,
    float* __restrict__ outp)
{
    int r = blockIdx.x;
    int t = threadIdx.x;
    if (r < 4) {
        const float* src = (r < 2 ? sl : el) + (size_t)(r & 1) * S_;
        float* dst = outp + (r < 2 ? 0 : BT_) + (size_t)(r & 1) * S_;
        int wave = t >> 6, lane = t & 63;
        __shared__ float sm[4], ss[4];

        float m = -1e30f;
        for (int k = t; k < S_; k += 256) m = fmaxf(m, src[k]);
#pragma unroll
        for (int off = 32; off; off >>= 1) m = fmaxf(m, __shfl_xor(m, off, 64));
        if (lane == 0) sm[wave] = m;
        __syncthreads();
        m = fmaxf(fmaxf(sm[0], sm[1]), fmaxf(sm[2], sm[3]));

        float s = 0.f;
        for (int k = t; k < S_; k += 256) s += __expf(src[k] - m);
#pragma unroll
        for (int off = 32; off; off >>= 1) s += __shfl_xor(s, off, 64);
        if (lane == 0) ss[wave] = s;
        __syncthreads();
        s = ss[0] + ss[1] + ss[2] + ss[3];

        float inv = 1.f / s;
        for (int k = t; k < S_; k += 256) dst[k] = __expf(src[k] - m) * inv;
    } else {
        __shared__ float pool[D_];
        __shared__ float h1[20];
        float* out2 = outp + 2 * BT_;
        for (int j = t; j < D_; j += 256) {
            float s = bp[j];
#pragma unroll
            for (int ks = 0; ks < DKS; ++ks) s += partial[ks * D_ + j];
            pool[j] = tanhf(s);
        }
        __syncthreads();
        if (t < 20) {
            float s = d1b[t];
            for (int k = 0; k < D_; ++k) s += pool[k] * d1W[k * 20 + t];
            h1[t] = s;
        }
        __syncthreads();
        if (t == 0) {
            float d0 = d2b[0], d1v = d2b[1];
#pragma unroll
            for (int u = 0; u < 20; ++u) {
                d0  += h1[u] * d2W[u * 2 + 0];
                d1v += h1[u] * d2W[u * 2 + 1];
            }
            float m = fmaxf(d0, d1v);
            float e0 = __expf(d0 - m), e1 = __expf(d1v - m);
            float inv = 1.f / (e0 + e1);
            out2[0] = e0 * inv;
            out2[1] = e1 * inv;
        }
    }
}

// ---------------------------------------------------------------------------
extern "C" void kernel_launch(void* const* d_in, const int* in_sizes, int n_in,
                              void* d_out, int out_size, void* d_ws, size_t ws_size,
                              hipStream_t stream)
{
    const int*   ids   = (const int*)d_in[0];
    const int*   kbi   = (const int*)d_in[1];
    const float* emb   = (const float*)d_in[2];
    const float* Wqkv  = (const float*)d_in[3];
    const float* bqkv  = (const float*)d_in[4];
    const float* Wo    = (const float*)d_in[5];
    const float* bo    = (const float*)d_in[6];
    const float* ln1g  = (const float*)d_in[7];
    const float* ln1b  = (const float*)d_in[8];
    const float* Wff1  = (const float*)d_in[9];
    const float* bff1  = (const float*)d_in[10];
    const float* Wff2  = (const float*)d_in[11];
    const float* bff2  = (const float*)d_in[12];
    const float* ln2g  = (const float*)d_in[13];
    const float* ln2b  = (const float*)d_in[14];
    const float* Wp    = (const float*)d_in[15];
    const float* bp    = (const float*)d_in[16];
    const float* sw    = (const float*)d_in[17];
    const float* ew    = (const float*)d_in[18];
    const float* d1W   = (const float*)d_in[19];
    const float* d1b   = (const float*)d_in[20];
    const float* d2W   = (const float*)d_in[21];
    const float* d2b   = (const float*)d_in[22];
    float* outp = (float*)d_out;

    // workspace carve (float units)
    float* ws   = (float*)d_ws;
    float* x    = ws;                          // BT_*D_ f32 (final LN only)
    float* xbf  = x   + (size_t)BT_ * D_;      // f16 xh (residual stream)
    float* r1f  = xbf + (size_t)BT_ * D_ / 2;  // f16 qkv / f16 h
    float* abf  = r1f + (size_t)BT_ * FF_ / 2; // f16 attn out
    float* r2   = abf + (size_t)BT_ * D_ / 2;  // partials (early) / f16 g (late)
    float* wtf  = r2  + (size_t)BT_ * D_;      // f16 weights
    float* sl   = wtf + 7077888;
    float* el   = sl  + BT_;
    float* dpar = el  + BT_;                   // DKS * D_ disc partials

    _Float16* xh    = (_Float16*)xbf;
    _Float16* qkv16 = (_Float16*)r1f;
    _Float16* h16   = (_Float16*)r1f;
    _Float16* ab    = (_Float16*)abf;
    float* pm   = r2;
    float* pl   = r2 + NEDGE * NSPLIT * 16;
    float* pacc = pl + NEDGE * NSPLIT * 16;
    _Float16* g16 = (_Float16*)r2;   // aliased; partials dead once proj runs

    _Float16* Wt    = (_Float16*)wtf;
    _Float16* WqkvT = Wt;
    _Float16* WoT   = WqkvT + (size_t)2 * 2304 * 768;
    _Float16* Wff1T = WoT   + (size_t)2 * 768 * 768;
    _Float16* Wff2T = Wff1T + (size_t)2 * 3072 * 768;

    // fused weight convert + embed: one dispatch
    WSegs segs;
    int start = 0;
    for (int l = 0; l < 2; ++l) {
        int base = l * 4;
        segs.s[base + 0] = { Wqkv + (size_t)l * 768 * 2304,
                             WqkvT + (size_t)l * 2304 * 768, 768, 2304, start };
        start += (2304 / 32) * (768 / 32);
        segs.s[base + 1] = { Wo + (size_t)l * 768 * 768,
                             WoT + (size_t)l * 768 * 768, 768, 768, start };
        start += (768 / 32) * (768 / 32);
        segs.s[base + 2] = { Wff1 + (size_t)l * 768 * 3072,
                             Wff1T + (size_t)l * 3072 * 768, 768, 3072, start };
        start += (3072 / 32) * (768 / 32);
        segs.s[base + 3] = { Wff2 + (size_t)l * 3072 * 768,
                             Wff2T + (size_t)l * 768 * 3072, 3072, 768, start };
        start += (768 / 32) * (3072 / 32);
    }
    segs.total = start;   // 13824

    prep_all<<<segs.total + BT_, 256, 0, stream>>>(segs, ids, emb, xh);

    for (int l = 0; l < 2; ++l) {
        gemm_f16<0,1><<<dim3(2304/128, BT_/128), 256, 0, stream>>>(
            xh, WqkvT + (size_t)l * 2304 * 768, bqkv + (size_t)l * 3 * D_,
            qkv16, BT_, 3 * D_, D_);
        attn_fused<<<NSPARSE + NEDGE * NSPLIT, 256, 0, stream>>>(
            qkv16, kbi, ab, pm, pl, pacc);
        attn_edge_combine<<<NEDGE, 256, 0, stream>>>(pm, pl, pacc, ab);
        gemm_f16<0,1><<<dim3(768/128, BT_/128), 256, 0, stream>>>(
            ab, WoT + (size_t)l * 768 * 768, bo + (size_t)l * D_,
            g16, BT_, D_, D_);
        add_ln_kernel<0><<<BT_, 256, 0, stream>>>(
            xh, g16, ln1g + (size_t)l * D_, ln1b + (size_t)l * D_, nullptr);
        gemm_f16<1,1><<<dim3(3072/128, BT_/128), 256, 0, stream>>>(
            xh, Wff1T + (size_t)l * 3072 * 768, bff1 + (size_t)l * FF_,
            h16, BT_, FF_, D_);
        gemm_f16<0,1><<<dim3(768/128, BT_/128), 256, 0, stream>>>(
            h16, Wff2T + (size_t)l * 768 * 3072, bff2 + (size_t)l * D_,
            g16, BT_, D_, FF_);
        if (l == 1)
            add_ln_kernel<1><<<BT_, 256, 0, stream>>>(
                xh, g16, ln2g + (size_t)l * D_, ln2b + (size_t)l * D_, x);
        else
            add_ln_kernel<0><<<BT_, 256, 0, stream>>>(
                xh, g16, ln2g + (size_t)l * D_, ln2b + (size_t)l * D_, nullptr);
    }

    heads_fused<<<2048 + 3 * DKS, 256, 0, stream>>>(x, sw, ew, Wp, sl, el, dpar);
    final_fused<<<5, 256, 0, stream>>>(sl, el, dpar, bp, d1W, d1b, d2W, d2b, outp);
}

// Round 21
// 626.240 us; speedup vs baseline: 1.2381x; 1.0193x over previous
//
#include <hip/hip_runtime.h>
#include <hip/hip_bf16.h>
#include <math.h>

#define B_   2
#define S_   4096
#define D_   768
#define H_   12
#define DH_  64
#define BS_  16
#define NB_  256
#define FF_  3072
#define BT_  (B_ * S_)          // 8192 token rows
#define SCALE_F 0.125f          // 1/sqrt(64)

#define NSPLIT 32               // key-dimension splits for edge attention
#define TILES_PER_SPLIT (NB_ / NSPLIT)   // 8
#define NEDGE (B_ * H_ * 2)     // 48 edge (b,h,e) groups
#define NSPARSE (B_ * H_ * NB_) // 6144 sparse blocks
#define NXCD 8

typedef _Float16 f16x8 __attribute__((ext_vector_type(8)));
typedef _Float16 f16x4 __attribute__((ext_vector_type(4)));
typedef _Float16 f16x2 __attribute__((ext_vector_type(2)));
typedef float    f32x4 __attribute__((ext_vector_type(4)));
typedef float    f32x16 __attribute__((ext_vector_type(16)));

#define DKS 8                   // disc pool k-splits
#define DKC (D_ / DKS)          // 96 rows per split

#define SV2(v, k) __builtin_shufflevector(v, v, k, (k) + 1)

// XCD-aware swizzle (T1): valid bijection when nwg % NXCD == 0.
// HW maps bid -> XCD bid%8; this gives each XCD a CONTIGUOUS work range.
__device__ __forceinline__ int xcd_swz(int bid, int nwg)
{
    int q = nwg / NXCD;
    return (bid % NXCD) * q + bid / NXCD;
}

__device__ __forceinline__ float dot2acc(f16x2 a, f16x2 b, float c)
{
#if __has_builtin(__builtin_amdgcn_fdot2)
    return __builtin_amdgcn_fdot2(a, b, c, false);
#else
    return c + (float)a[0] * (float)b[0] + (float)a[1] * (float)b[1];
#endif
}

// async global->LDS, 16B per lane; LDS dest is wave-uniform base + lane*16
#define GLD16(gp, lp) __builtin_amdgcn_global_load_lds( \
    (const __attribute__((address_space(1))) void*)(gp), \
    (__attribute__((address_space(3))) void*)(lp), 16, 0, 0)

__device__ __forceinline__ float fast_tanh(float z)
{
    float az = fabsf(z);
    float t = __expf(-2.0f * az);
    float r = (1.0f - t) / (1.0f + t);
    return z < 0.f ? -r : r;
}

__device__ __forceinline__ float gelu_tanh(float v)
{
    float v3 = v * v * v;
    return 0.5f * v * (1.0f + fast_tanh(0.79788456080286535588f * (v + 0.044715f * v3)));
}

// ---------------------------------------------------------------------------
// Fused weight convert + embedding (vectorized transpose).
// ---------------------------------------------------------------------------
struct WSeg { const float* src; _Float16* dst; int K; int N; int start; };
struct WSegs { WSeg s[8]; int total; };

__global__ __launch_bounds__(256) void prep_all(
    WSegs segs, const int* __restrict__ ids, const float* __restrict__ emb,
    _Float16* __restrict__ xh)
{
    int bt = blockIdx.x;
    int t = threadIdx.x;
    if (bt < segs.total) {
        __shared__ float tile[32][33];
        int si = 0;
#pragma unroll
        for (int u = 1; u < 8; ++u)
            if (bt >= segs.s[u].start) si = u;
        const WSeg& sg = segs.s[si];
        int tid = bt - sg.start;
        int tn = sg.N >> 5;
        int n0 = (tid % tn) * 32;
        int k0 = (tid / tn) * 32;

        {
            int r = t >> 3, c = (t & 7) * 4;
            f32x4 v = *(const f32x4*)&sg.src[(size_t)(k0 + r) * sg.N + n0 + c];
            tile[r][c + 0] = v[0];
            tile[r][c + 1] = v[1];
            tile[r][c + 2] = v[2];
            tile[r][c + 3] = v[3];
        }
        __syncthreads();
        {
            int r = t >> 3, c = (t & 7) * 4;
            f16x4 o;
            o[0] = (_Float16)tile[c + 0][r];
            o[1] = (_Float16)tile[c + 1][r];
            o[2] = (_Float16)tile[c + 2][r];
            o[3] = (_Float16)tile[c + 3][r];
            *(f16x4*)&sg.dst[(size_t)(n0 + r) * sg.K + k0 + c] = o;
        }
    } else {
        int row = bt - segs.total;
        int id = ids[row];
        const float* src = emb + (size_t)id * D_;
        _Float16* dst16 = xh + (size_t)row * D_;
        for (int d = t; d < D_; d += 256)
            dst16[d] = (_Float16)src[d];
    }
}

// ---------------------------------------------------------------------------
// MFMA fp16 GEMM (r19 32x32x16 + r20 XCD swizzle). 1D grid, NT128 = N/128.
// ---------------------------------------------------------------------------
template<int ACT, int OUT16>
__global__ __launch_bounds__(256) void gemm_f16(
    const _Float16* __restrict__ A, const _Float16* __restrict__ Wt,
    const float* __restrict__ bias, void* __restrict__ Cp,
    int M, int N, int K, int NT128)
{
    __shared__ __attribute__((aligned(16))) _Float16 As[128 * 64];
    __shared__ __attribute__((aligned(16))) _Float16 Bs[128 * 64];

    int t = threadIdx.x;
    int w = t >> 6, l = t & 63;
    int swz = xcd_swz(blockIdx.x, gridDim.x);
    int bm = (swz / NT128) * 128, bn = (swz % NT128) * 128;
    int wr = (w >> 1) * 64, wc = (w & 1) * 64;

    f32x16 acc[2][2];
#pragma unroll
    for (int i = 0; i < 2; ++i)
#pragma unroll
        for (int j = 0; j < 2; ++j)
#pragma unroll
            for (int r = 0; r < 16; ++r) acc[i][j][r] = 0.f;

    const _Float16* gA[4];
    const _Float16* gB[4];
#pragma unroll
    for (int q = 0; q < 4; ++q) {
        int m = w * 4 + q;
        int row = m * 8 + (l >> 3);
        int sc = (l & 7) ^ (row & 7);
        gA[q] = A  + (size_t)(bm + row) * K + sc * 8;
        gB[q] = Wt + (size_t)(bn + row) * K + sc * 8;
    }

    int aoff[4][2], boff[4][2];
#pragma unroll
    for (int kk = 0; kk < 4; ++kk) {
        int ch = (kk * 2 + (l >> 5)) ^ (l & 7);
#pragma unroll
        for (int f = 0; f < 2; ++f) {
            aoff[kk][f] = (wr + f * 32 + (l & 31)) * 64 + ch * 8;
            boff[kk][f] = (wc + f * 32 + (l & 31)) * 64 + ch * 8;
        }
    }

    for (int k0 = 0; k0 < K; k0 += 64) {
#pragma unroll
        for (int q = 0; q < 4; ++q) {
            int m = w * 4 + q;
            GLD16(gA[q] + k0, As + m * 512);
            GLD16(gB[q] + k0, Bs + m * 512);
        }
        __syncthreads();

#pragma unroll
        for (int kk = 0; kk < 4; ++kk) {
            f16x8 af[2], bf[2];
#pragma unroll
            for (int f = 0; f < 2; ++f) {
                af[f] = *(const f16x8*)(As + aoff[kk][f]);
                bf[f] = *(const f16x8*)(Bs + boff[kk][f]);
            }
#pragma unroll
            for (int i = 0; i < 2; ++i)
#pragma unroll
                for (int j = 0; j < 2; ++j)
                    acc[i][j] = __builtin_amdgcn_mfma_f32_32x32x16_f16(
                        af[i], bf[j], acc[i][j], 0, 0, 0);
        }
        __syncthreads();
    }

#pragma unroll
    for (int i = 0; i < 2; ++i) {
#pragma unroll
        for (int j = 0; j < 2; ++j) {
            int col = bn + wc + j * 32 + (l & 31);
            float bv = bias[col];
#pragma unroll
            for (int rg = 0; rg < 4; ++rg) {
                int row0 = bm + wr + i * 32 + 8 * rg + 4 * (l >> 5);
#pragma unroll
                for (int r = 0; r < 4; ++r) {
                    float v = acc[i][j][rg * 4 + r] + bv;
                    if (ACT) v = gelu_tanh(v);
                    if (OUT16)
                        ((_Float16*)Cp)[(size_t)(row0 + r) * N + col] = (_Float16)v;
                    else
                        ((float*)Cp)[(size_t)(row0 + r) * N + col] = v;
                }
            }
        }
    }
}

// ---------------------------------------------------------------------------
// Attention core: K dbuf f16 LDS; V j-paired f16; PV on fdot2; lsum from the
// f16 p values; setprio(1) around compute.
// ---------------------------------------------------------------------------
template<int NT, bool EDGE>
__device__ __forceinline__ void attn_block(
    const _Float16* __restrict__ qkv, const int* __restrict__ key_idx,
    _Float16* __restrict__ outp, float* __restrict__ pm,
    float* __restrict__ pl, float* __restrict__ pacc,
    int b, int h, int n, int split, int be,
    _Float16 (*qs)[72], _Float16 (*ks)[16][72],
    _Float16 (*vpl)[8][64][2], _Float16 (*ps16)[24])
{
    int t = threadIdx.x;
    int i = t >> 4;        // query row / staging row
    int c = t & 15;
    int c4 = c * 4;

    // stage Q tile; load tile 0 into registers
    *(f16x4*)&qs[i][c4] =
        *(const f16x4*)&qkv[((size_t)(b * S_ + n * BS_ + i)) * (3 * D_) + h * DH_ + c4];
    int kb0 = EDGE ? split * NT : key_idx[n * 7];
    const _Float16* kp0 = qkv + ((size_t)(b * S_ + kb0 * BS_ + i)) * (3 * D_) + D_ + h * DH_;
    f16x4 kr = *(const f16x4*)(kp0 + c4);
    f16x4 vr = *(const f16x4*)(kp0 + D_ + c4);
    __syncthreads();   // qs visible

    f16x8 qv[8];
#pragma unroll
    for (int d0 = 0; d0 < 8; ++d0) qv[d0] = *(const f16x8*)&qs[i][d0 * 8];

    // write tile 0 into buffer 0; prefetch tile 1
    *(f16x4*)&ks[0][i][c4] = kr;
#pragma unroll
    for (int u = 0; u < 4; ++u) vpl[0][i >> 1][c4 + u][i & 1] = vr[u];
    if (NT > 1) {
        int kb1 = EDGE ? (split * NT + 1) : key_idx[n * 7 + 1];
        const _Float16* kp1 = qkv + ((size_t)(b * S_ + kb1 * BS_ + i)) * (3 * D_) + D_ + h * DH_;
        kr = *(const f16x4*)(kp1 + c4);
        vr = *(const f16x4*)(kp1 + D_ + c4);
    }
    __syncthreads();   // buffer 0 staged

    float m_old = -1e30f, lsum = 0.f;
    float acc0 = 0.f, acc1 = 0.f, acc2 = 0.f, acc3 = 0.f;
    const f16x2 one2 = {(_Float16)1.f, (_Float16)1.f};

#pragma unroll 1
    for (int jj = 0; jj < NT; ++jj) {
        int cur = jj & 1;
        if (jj + 1 < NT) {
            *(f16x4*)&ks[cur ^ 1][i][c4] = kr;
#pragma unroll
            for (int u = 0; u < 4; ++u) vpl[cur ^ 1][i >> 1][c4 + u][i & 1] = vr[u];
        }
        if (jj + 2 < NT) {
            int kb2 = EDGE ? (split * NT + jj + 2) : key_idx[n * 7 + jj + 2];
            const _Float16* kp2 = qkv + ((size_t)(b * S_ + kb2 * BS_ + i)) * (3 * D_) + D_ + h * DH_;
            kr = *(const f16x4*)(kp2 + c4);
            vr = *(const f16x4*)(kp2 + D_ + c4);
        }

        __builtin_amdgcn_s_setprio(1);
        // score: <q_i, k_c> via fdot2 over b128 LDS reads
        float s0 = 0.f, s1 = 0.f;
#pragma unroll
        for (int d0 = 0; d0 < 8; ++d0) {
            f16x8 kv = *(const f16x8*)&ks[cur][c][d0 * 8];
            s0 = dot2acc(SV2(qv[d0], 0), SV2(kv, 0), s0);
            s1 = dot2acc(SV2(qv[d0], 2), SV2(kv, 2), s1);
            s0 = dot2acc(SV2(qv[d0], 4), SV2(kv, 4), s0);
            s1 = dot2acc(SV2(qv[d0], 6), SV2(kv, 6), s1);
        }
        float s = (s0 + s1) * SCALE_F;

        // row max (fp32, 16-lane shuffle); p in f16 via LDS
        float rm = s;
#pragma unroll
        for (int off = 8; off; off >>= 1) rm = fmaxf(rm, __shfl_xor(rm, off, 64));
        float m_new = fmaxf(m_old, rm);
        float p = __expf(s - m_new);

        ps16[i][c] = (_Float16)p;
        f16x8 plo = *(const f16x8*)&ps16[i][0];   // p0..p7  (jp 0..3)
        f16x8 phi = *(const f16x8*)&ps16[i][8];   // p8..p15 (jp 4..7)

        // row sum from the same f16 p values (no shuffle reduce)
        float rs = 0.f;
        rs = dot2acc(SV2(plo, 0), one2, rs);
        rs = dot2acc(SV2(plo, 2), one2, rs);
        rs = dot2acc(SV2(plo, 4), one2, rs);
        rs = dot2acc(SV2(plo, 6), one2, rs);
        rs = dot2acc(SV2(phi, 0), one2, rs);
        rs = dot2acc(SV2(phi, 2), one2, rs);
        rs = dot2acc(SV2(phi, 4), one2, rs);
        rs = dot2acc(SV2(phi, 6), one2, rs);

        float corr = __expf(m_old - m_new);
        lsum = lsum * corr + rs;
        acc0 *= corr; acc1 *= corr; acc2 *= corr; acc3 *= corr;

        // PV: V j-paired; fdot2 accumulation (literal shuffle indices)
#define PVJ(JP, PSRC, OFF)                                            \
        {                                                             \
            f16x8 vv = *(const f16x8*)&vpl[cur][JP][c4][0];           \
            f16x2 pp = SV2(PSRC, OFF);                                \
            acc0 = dot2acc(pp, SV2(vv, 0), acc0);                     \
            acc1 = dot2acc(pp, SV2(vv, 2), acc1);                     \
            acc2 = dot2acc(pp, SV2(vv, 4), acc2);                     \
            acc3 = dot2acc(pp, SV2(vv, 6), acc3);                     \
        }
        PVJ(0, plo, 0) PVJ(1, plo, 2) PVJ(2, plo, 4) PVJ(3, plo, 6)
        PVJ(4, phi, 0) PVJ(5, phi, 2) PVJ(6, phi, 4) PVJ(7, phi, 6)
#undef PVJ
        __builtin_amdgcn_s_setprio(0);
        m_old = m_new;
        __syncthreads();   // all reads of cur done; writes to cur^1 visible
    }

    if (EDGE) {
        int psx = (be * NSPLIT + split) * 16 + i;
        if (c == 0) { pm[psx] = m_old; pl[psx] = lsum; }
        float* pd = pacc + (size_t)psx * 64 + c4;
        pd[0] = acc0; pd[1] = acc1; pd[2] = acc2; pd[3] = acc3;
    } else {
        float inv = 1.f / lsum;
        _Float16* dst = outp + ((size_t)(b * S_ + n * BS_ + i)) * D_ + h * DH_ + c4;
        dst[0] = (_Float16)(acc0 * inv);
        dst[1] = (_Float16)(acc1 * inv);
        dst[2] = (_Float16)(acc2 * inv);
        dst[3] = (_Float16)(acc3 * inv);
    }
}

// ---------------------------------------------------------------------------
// Fused attention dispatch: sparse + edge split-K in one grid.
// r20: XCD swizzle — each XCD gets ~960 consecutive bi (same b,h, adjacent
// n share 2/7 key blocks + blocks 0/255) -> K/V L2 locality.
// ---------------------------------------------------------------------------
__global__ __launch_bounds__(256) void attn_fused(
    const _Float16* __restrict__ qkv, const int* __restrict__ key_idx,
    _Float16* __restrict__ outp, float* __restrict__ pm,
    float* __restrict__ pl, float* __restrict__ pacc)
{
    __shared__ __attribute__((aligned(16))) _Float16 qs[16][72];
    __shared__ __attribute__((aligned(16))) _Float16 ks[2][16][72];
    __shared__ __attribute__((aligned(16))) _Float16 vpl[2][8][64][2];
    __shared__ __attribute__((aligned(16))) _Float16 ps16[16][24];

    int bi = xcd_swz(blockIdx.x, gridDim.x);
    if (bi < NSPARSE) {
        int n = bi % NB_;
        if (n == 0 || n == NB_ - 1) return;
        int h = (bi / NB_) % H_;
        int b = bi / (NB_ * H_);
        attn_block<7, false>(qkv, key_idx, outp, nullptr, nullptr, nullptr,
                             b, h, n, 0, 0, qs, ks, vpl, ps16);
    } else {
        int ei = bi - NSPARSE;
        int split = ei % NSPLIT;
        int be = ei / NSPLIT;
        int e = be & 1;
        int h = (be >> 1) % H_;
        int b = be / (2 * H_);
        int n = e ? (NB_ - 1) : 0;
        attn_block<TILES_PER_SPLIT, true>(qkv, nullptr, nullptr, pm, pl, pacc,
                                          b, h, n, split, be, qs, ks, vpl, ps16);
    }
}

// ---------------------------------------------------------------------------
// Edge attention combine
// ---------------------------------------------------------------------------
__global__ __launch_bounds__(256) void attn_edge_combine(
    const float* __restrict__ pm, const float* __restrict__ pl,
    const float* __restrict__ pacc, _Float16* __restrict__ outp)
{
    int be = blockIdx.x;
    int e = be & 1;
    int h = (be >> 1) % H_;
    int b = be / (2 * H_);
    int n = e ? (NB_ - 1) : 0;

    int t = threadIdx.x;
    int i = t >> 4;
    int c = t & 15;

    float M = -1e30f;
#pragma unroll 4
    for (int s = 0; s < NSPLIT; ++s)
        M = fmaxf(M, pm[(be * NSPLIT + s) * 16 + i]);

    float L = 0.f;
    float acc[4] = {0.f, 0.f, 0.f, 0.f};
    for (int s = 0; s < NSPLIT; ++s) {
        int ps = (be * NSPLIT + s) * 16 + i;
        float wgt = __expf(pm[ps] - M);
        L += pl[ps] * wgt;
#pragma unroll
        for (int u = 0; u < 4; ++u) acc[u] += pacc[(size_t)ps * 64 + c * 4 + u] * wgt;
    }

    float inv = 1.f / L;
    _Float16* dst = outp + ((size_t)(b * S_ + n * BS_ + i)) * D_ + h * DH_ + c * 4;
#pragma unroll
    for (int u = 0; u < 4; ++u) dst[u] = (_Float16)(acc[u] * inv);
}

// ---------------------------------------------------------------------------
// LN: residual stream in f16. xh = LN(xh + g) (stats in f32).
// WRITE32: additionally write the f32 row (only the FINAL LN, for heads).
// ---------------------------------------------------------------------------
template<int WRITE32>
__global__ __launch_bounds__(256) void add_ln_kernel(
    _Float16* __restrict__ xh, const _Float16* __restrict__ g,
    const float* __restrict__ gamma, const float* __restrict__ beta,
    float* __restrict__ x32)
{
    int row = blockIdx.x;
    int t = threadIdx.x;
    _Float16* xr = xh + (size_t)row * D_;
    const _Float16* gr = g + (size_t)row * D_;

    float v[3];
    float s = 0.f, s2 = 0.f;
#pragma unroll
    for (int r = 0; r < 3; ++r) {
        int d = t + 256 * r;
        v[r] = (float)xr[d] + (float)gr[d];
        s += v[r];
        s2 += v[r] * v[r];
    }
#pragma unroll
    for (int off = 32; off; off >>= 1) {
        s  += __shfl_xor(s, off, 64);
        s2 += __shfl_xor(s2, off, 64);
    }
    __shared__ float sA[4], sB[4];
    int wave = t >> 6, lane = t & 63;
    if (lane == 0) { sA[wave] = s; sB[wave] = s2; }
    __syncthreads();
    s  = sA[0] + sA[1] + sA[2] + sA[3];
    s2 = sB[0] + sB[1] + sB[2] + sB[3];
    float mean = s * (1.0f / D_);
    float var = s2 * (1.0f / D_) - mean * mean;
    float rstd = rsqrtf(var + 1e-12f);
#pragma unroll
    for (int r = 0; r < 3; ++r) {
        int d = t + 256 * r;
        float o = (v[r] - mean) * rstd * gamma[d] + beta[d];
        xr[d] = (_Float16)o;
        if (WRITE32) x32[(size_t)row * D_ + d] = o;
    }
}

// ---------------------------------------------------------------------------
// Fused heads: blockIdx < 2048 -> start/end logits; else disc pool partial.
// ---------------------------------------------------------------------------
__global__ __launch_bounds__(256) void heads_fused(
    const float* __restrict__ x, const float* __restrict__ sw,
    const float* __restrict__ ew, const float* __restrict__ Wp,
    float* __restrict__ sl, float* __restrict__ el,
    float* __restrict__ partial)
{
    int bi = blockIdx.x;
    int t = threadIdx.x;
    if (bi < 2048) {
        int wave = t >> 6, lane = t & 63;
        int row = bi * 4 + wave;
        const float* xr = x + (size_t)row * D_;
        float a = 0.f, e = 0.f;
        for (int d = lane; d < D_; d += 64) {
            float xv = xr[d];
            a += xv * sw[d];
            e += xv * ew[d];
        }
#pragma unroll
        for (int off = 32; off; off >>= 1) {
            a += __shfl_xor(a, off, 64);
            e += __shfl_xor(e, off, 64);
        }
        if (lane == 0) { sl[row] = a; el[row] = e; }
    } else {
        int ei = bi - 2048;       // 0..23
        int jb = ei % 3;          // 0..2
        int ks = ei / 3;          // 0..7
        int j = jb * 256 + t;
        int k0 = ks * DKC;

        __shared__ float xs[DKC];
        if (t < DKC) xs[t] = x[k0 + t];   // x0 = x row 0
        __syncthreads();

        float s = 0.f;
#pragma unroll 8
        for (int kk = 0; kk < DKC; ++kk)
            s += xs[kk] * Wp[(size_t)(k0 + kk) * D_ + j];
        partial[ks * D_ + j] = s;
    }
}

// ---------------------------------------------------------------------------
// Fused final: r<4 -> softmax over S; r==4 -> disc finish.
// ---------------------------------------------------------------------------
__global__ __launch_bounds__(256) void final_fused(
    const float* __restrict__ sl, const float* __restrict__ el,
    const float* __restrict__ partial, const float* __restrict__ bp,
    const float* __restrict__ d1W, const float* __restrict__ d1b,
    const float* __restrict__ d2W, const float* __restrict__ d2b,
    float* __restrict__ outp)
{
    int r = blockIdx.x;
    int t = threadIdx.x;
    if (r < 4) {
        const float* src = (r < 2 ? sl : el) + (size_t)(r & 1) * S_;
        float* dst = outp + (r < 2 ? 0 : BT_) + (size_t)(r & 1) * S_;
        int wave = t >> 6, lane = t & 63;
        __shared__ float sm[4], ss[4];

        float m = -1e30f;
        for (int k = t; k < S_; k += 256) m = fmaxf(m, src[k]);
#pragma unroll
        for (int off = 32; off; off >>= 1) m = fmaxf(m, __shfl_xor(m, off, 64));
        if (lane == 0) sm[wave] = m;
        __syncthreads();
        m = fmaxf(fmaxf(sm[0], sm[1]), fmaxf(sm[2], sm[3]));

        float s = 0.f;
        for (int k = t; k < S_; k += 256) s += __expf(src[k] - m);
#pragma unroll
        for (int off = 32; off; off >>= 1) s += __shfl_xor(s, off, 64);
        if (lane == 0) ss[wave] = s;
        __syncthreads();
        s = ss[0] + ss[1] + ss[2] + ss[3];

        float inv = 1.f / s;
        for (int k = t; k < S_; k += 256) dst[k] = __expf(src[k] - m) * inv;
    } else {
        __shared__ float pool[D_];
        __shared__ float h1[20];
        float* out2 = outp + 2 * BT_;
        for (int j = t; j < D_; j += 256) {
            float s = bp[j];
#pragma unroll
            for (int ks = 0; ks < DKS; ++ks) s += partial[ks * D_ + j];
            pool[j] = tanhf(s);
        }
        __syncthreads();
        if (t < 20) {
            float s = d1b[t];
            for (int k = 0; k < D_; ++k) s += pool[k] * d1W[k * 20 + t];
            h1[t] = s;
        }
        __syncthreads();
        if (t == 0) {
            float d0 = d2b[0], d1v = d2b[1];
#pragma unroll
            for (int u = 0; u < 20; ++u) {
                d0  += h1[u] * d2W[u * 2 + 0];
                d1v += h1[u] * d2W[u * 2 + 1];
            }
            float m = fmaxf(d0, d1v);
            float e0 = __expf(d0 - m), e1 = __expf(d1v - m);
            float inv = 1.f / (e0 + e1);
            out2[0] = e0 * inv;
            out2[1] = e1 * inv;
        }
    }
}

// ---------------------------------------------------------------------------
extern "C" void kernel_launch(void* const* d_in, const int* in_sizes, int n_in,
                              void* d_out, int out_size, void* d_ws, size_t ws_size,
                              hipStream_t stream)
{
    const int*   ids   = (const int*)d_in[0];
    const int*   kbi   = (const int*)d_in[1];
    const float* emb   = (const float*)d_in[2];
    const float* Wqkv  = (const float*)d_in[3];
    const float* bqkv  = (const float*)d_in[4];
    const float* Wo    = (const float*)d_in[5];
    const float* bo    = (const float*)d_in[6];
    const float* ln1g  = (const float*)d_in[7];
    const float* ln1b  = (const float*)d_in[8];
    const float* Wff1  = (const float*)d_in[9];
    const float* bff1  = (const float*)d_in[10];
    const float* Wff2  = (const float*)d_in[11];
    const float* bff2  = (const float*)d_in[12];
    const float* ln2g  = (const float*)d_in[13];
    const float* ln2b  = (const float*)d_in[14];
    const float* Wp    = (const float*)d_in[15];
    const float* bp    = (const float*)d_in[16];
    const float* sw    = (const float*)d_in[17];
    const float* ew    = (const float*)d_in[18];
    const float* d1W   = (const float*)d_in[19];
    const float* d1b   = (const float*)d_in[20];
    const float* d2W   = (const float*)d_in[21];
    const float* d2b   = (const float*)d_in[22];
    float* outp = (float*)d_out;

    // workspace carve (float units)
    float* ws   = (float*)d_ws;
    float* x    = ws;                          // BT_*D_ f32 (final LN only)
    float* xbf  = x   + (size_t)BT_ * D_;      // f16 xh (residual stream)
    float* r1f  = xbf + (size_t)BT_ * D_ / 2;  // f16 qkv / f16 h
    float* abf  = r1f + (size_t)BT_ * FF_ / 2; // f16 attn out
    float* r2   = abf + (size_t)BT_ * D_ / 2;  // partials (early) / f16 g (late)
    float* wtf  = r2  + (size_t)BT_ * D_;      // f16 weights
    float* sl   = wtf + 7077888;
    float* el   = sl  + BT_;
    float* dpar = el  + BT_;                   // DKS * D_ disc partials

    _Float16* xh    = (_Float16*)xbf;
    _Float16* qkv16 = (_Float16*)r1f;
    _Float16* h16   = (_Float16*)r1f;
    _Float16* ab    = (_Float16*)abf;
    float* pm   = r2;
    float* pl   = r2 + NEDGE * NSPLIT * 16;
    float* pacc = pl + NEDGE * NSPLIT * 16;
    _Float16* g16 = (_Float16*)r2;   // aliased; partials dead once proj runs

    _Float16* Wt    = (_Float16*)wtf;
    _Float16* WqkvT = Wt;
    _Float16* WoT   = WqkvT + (size_t)2 * 2304 * 768;
    _Float16* Wff1T = WoT   + (size_t)2 * 768 * 768;
    _Float16* Wff2T = Wff1T + (size_t)2 * 3072 * 768;

    // fused weight convert + embed: one dispatch
    WSegs segs;
    int start = 0;
    for (int l = 0; l < 2; ++l) {
        int base = l * 4;
        segs.s[base + 0] = { Wqkv + (size_t)l * 768 * 2304,
                             WqkvT + (size_t)l * 2304 * 768, 768, 2304, start };
        start += (2304 / 32) * (768 / 32);
        segs.s[base + 1] = { Wo + (size_t)l * 768 * 768,
                             WoT + (size_t)l * 768 * 768, 768, 768, start };
        start += (768 / 32) * (768 / 32);
        segs.s[base + 2] = { Wff1 + (size_t)l * 768 * 3072,
                             Wff1T + (size_t)l * 3072 * 768, 768, 3072, start };
        start += (3072 / 32) * (768 / 32);
        segs.s[base + 3] = { Wff2 + (size_t)l * 3072 * 768,
                             Wff2T + (size_t)l * 768 * 3072, 3072, 768, start };
        start += (768 / 32) * (3072 / 32);
    }
    segs.total = start;   // 13824

    prep_all<<<segs.total + BT_, 256, 0, stream>>>(segs, ids, emb, xh);

    for (int l = 0; l < 2; ++l) {
        gemm_f16<0,1><<<(2304/128) * (BT_/128), 256, 0, stream>>>(
            xh, WqkvT + (size_t)l * 2304 * 768, bqkv + (size_t)l * 3 * D_,
            qkv16, BT_, 3 * D_, D_, 2304/128);
        attn_fused<<<NSPARSE + NEDGE * NSPLIT, 256, 0, stream>>>(
            qkv16, kbi, ab, pm, pl, pacc);
        attn_edge_combine<<<NEDGE, 256, 0, stream>>>(pm, pl, pacc, ab);
        gemm_f16<0,1><<<(768/128) * (BT_/128), 256, 0, stream>>>(
            ab, WoT + (size_t)l * 768 * 768, bo + (size_t)l * D_,
            g16, BT_, D_, D_, 768/128);
        add_ln_kernel<0><<<BT_, 256, 0, stream>>>(
            xh, g16, ln1g + (size_t)l * D_, ln1b + (size_t)l * D_, nullptr);
        gemm_f16<1,1><<<(3072/128) * (BT_/128), 256, 0, stream>>>(
            xh, Wff1T + (size_t)l * 3072 * 768, bff1 + (size_t)l * FF_,
            h16, BT_, FF_, D_, 3072/128);
        gemm_f16<0,1><<<(768/128) * (BT_/128), 256, 0, stream>>>(
            h16, Wff2T + (size_t)l * 768 * 3072, bff2 + (size_t)l * D_,
            g16, BT_, D_, FF_, 768/128);
        if (l == 1)
            add_ln_kernel<1><<<BT_, 256, 0, stream>>>(
                xh, g16, ln2g + (size_t)l * D_, ln2b + (size_t)l * D_, x);
        else
            add_ln_kernel<0><<<BT_, 256, 0, stream>>>(
                xh, g16, ln2g + (size_t)l * D_, ln2b + (size_t)l * D_, nullptr);
    }

    heads_fused<<<2048 + 3 * DKS, 256, 0, stream>>>(x, sw, ew, Wp, sl, el, dpar);
    final_fused<<<5, 256, 0, stream>>>(sl, el, dpar, bp, d1W, d1b, d2W, d2b, outp);
}

// Round 22
// 608.834 us; speedup vs baseline: 1.2735x; 1.0286x over previous
//
#include <hip/hip_runtime.h>
#include <hip/hip_bf16.h>
#include <math.h>

#define B_   2
#define S_   4096
#define D_   768
#define H_   12
#define DH_  64
#define BS_  16
#define NB_  256
#define FF_  3072
#define BT_  (B_ * S_)          // 8192 token rows
#define SCALE_F 0.125f          // 1/sqrt(64)

#define NSPLIT 32               // key-dimension splits for edge attention
#define TILES_PER_SPLIT (NB_ / NSPLIT)   // 8
#define NEDGE (B_ * H_ * 2)     // 48 edge (b,h,e) groups
#define NSPARSE (B_ * H_ * NB_) // 6144 sparse blocks
#define NXCD 8

typedef _Float16 f16x8 __attribute__((ext_vector_type(8)));
typedef _Float16 f16x4 __attribute__((ext_vector_type(4)));
typedef _Float16 f16x2 __attribute__((ext_vector_type(2)));
typedef float    f32x4 __attribute__((ext_vector_type(4)));
typedef float    f32x16 __attribute__((ext_vector_type(16)));

#define DKS 8                   // disc pool k-splits
#define DKC (D_ / DKS)          // 96 rows per split

#define SV2(v, k) __builtin_shufflevector(v, v, k, (k) + 1)

// XCD-aware swizzle (T1): valid bijection when nwg % NXCD == 0.
__device__ __forceinline__ int xcd_swz(int bid, int nwg)
{
    int q = nwg / NXCD;
    return (bid % NXCD) * q + bid / NXCD;
}

__device__ __forceinline__ float dot2acc(f16x2 a, f16x2 b, float c)
{
#if __has_builtin(__builtin_amdgcn_fdot2)
    return __builtin_amdgcn_fdot2(a, b, c, false);
#else
    return c + (float)a[0] * (float)b[0] + (float)a[1] * (float)b[1];
#endif
}

// async global->LDS, 16B per lane; LDS dest is wave-uniform base + lane*16
#define GLD16(gp, lp) __builtin_amdgcn_global_load_lds( \
    (const __attribute__((address_space(1))) void*)(gp), \
    (__attribute__((address_space(3))) void*)(lp), 16, 0, 0)

__device__ __forceinline__ float fast_tanh(float z)
{
    float az = fabsf(z);
    float t = __expf(-2.0f * az);
    float r = (1.0f - t) / (1.0f + t);
    return z < 0.f ? -r : r;
}

__device__ __forceinline__ float gelu_tanh(float v)
{
    float v3 = v * v * v;
    return 0.5f * v * (1.0f + fast_tanh(0.79788456080286535588f * (v + 0.044715f * v3)));
}

// ---------------------------------------------------------------------------
// Fused weight convert + embedding (vectorized transpose).
// ---------------------------------------------------------------------------
struct WSeg { const float* src; _Float16* dst; int K; int N; int start; };
struct WSegs { WSeg s[8]; int total; };

__global__ __launch_bounds__(256) void prep_all(
    WSegs segs, const int* __restrict__ ids, const float* __restrict__ emb,
    _Float16* __restrict__ xh)
{
    int bt = blockIdx.x;
    int t = threadIdx.x;
    if (bt < segs.total) {
        __shared__ float tile[32][33];
        int si = 0;
#pragma unroll
        for (int u = 1; u < 8; ++u)
            if (bt >= segs.s[u].start) si = u;
        const WSeg& sg = segs.s[si];
        int tid = bt - sg.start;
        int tn = sg.N >> 5;
        int n0 = (tid % tn) * 32;
        int k0 = (tid / tn) * 32;

        {
            int r = t >> 3, c = (t & 7) * 4;
            f32x4 v = *(const f32x4*)&sg.src[(size_t)(k0 + r) * sg.N + n0 + c];
            tile[r][c + 0] = v[0];
            tile[r][c + 1] = v[1];
            tile[r][c + 2] = v[2];
            tile[r][c + 3] = v[3];
        }
        __syncthreads();
        {
            int r = t >> 3, c = (t & 7) * 4;
            f16x4 o;
            o[0] = (_Float16)tile[c + 0][r];
            o[1] = (_Float16)tile[c + 1][r];
            o[2] = (_Float16)tile[c + 2][r];
            o[3] = (_Float16)tile[c + 3][r];
            *(f16x4*)&sg.dst[(size_t)(n0 + r) * sg.K + k0 + c] = o;
        }
    } else {
        int row = bt - segs.total;
        int id = ids[row];
        const float* src = emb + (size_t)id * D_;
        _Float16* dst16 = xh + (size_t)row * D_;
        for (int d = t; d < D_; d += 256)
            dst16[d] = (_Float16)src[d];
    }
}

// ---------------------------------------------------------------------------
// MFMA fp16 GEMM (r21): templated M-block. MI = 32-row frags per wave.
// BM = MI*64; BN = 128. MI=2: 128x128 block (r19-verified). MI=1: 64x128
// block for the N=768 GEMMs (proj/ff2) — doubles grid to 768 blocks for
// latency-bound small-N shapes. Wave tile (MI*32)x64 = MIx2 frags 32x32.
// Staging: A chunks BM/8 total (QA=2*MI per wave); B 16 chunks (4/wave).
// row&7 == l&7 everywhere (bases multiples of 32) -> same XOR involution.
// ---------------------------------------------------------------------------
template<int MI, int ACT, int OUT16>
__global__ __launch_bounds__(256) void gemm_f16(
    const _Float16* __restrict__ A, const _Float16* __restrict__ Wt,
    const float* __restrict__ bias, void* __restrict__ Cp,
    int M, int N, int K, int NT128)
{
    constexpr int BM = MI * 64;
    constexpr int QA = 2 * MI;   // A 1KB chunks per wave

    __shared__ __attribute__((aligned(16))) _Float16 As[BM * 64];
    __shared__ __attribute__((aligned(16))) _Float16 Bs[128 * 64];

    int t = threadIdx.x;
    int w = t >> 6, l = t & 63;
    int swz = xcd_swz(blockIdx.x, gridDim.x);
    int bm = (swz / NT128) * BM, bn = (swz % NT128) * 128;
    int wr = (w >> 1) * (MI * 32), wc = (w & 1) * 64;

    f32x16 acc[MI][2];
#pragma unroll
    for (int i = 0; i < MI; ++i)
#pragma unroll
        for (int j = 0; j < 2; ++j)
#pragma unroll
            for (int r = 0; r < 16; ++r) acc[i][j][r] = 0.f;

    const _Float16* gA[QA];
    const _Float16* gB[4];
#pragma unroll
    for (int q = 0; q < QA; ++q) {
        int m = w * QA + q;
        int row = m * 8 + (l >> 3);
        int sc = (l & 7) ^ (row & 7);
        gA[q] = A + (size_t)(bm + row) * K + sc * 8;
    }
#pragma unroll
    for (int q = 0; q < 4; ++q) {
        int m = w * 4 + q;
        int row = m * 8 + (l >> 3);
        int sc = (l & 7) ^ (row & 7);
        gB[q] = Wt + (size_t)(bn + row) * K + sc * 8;
    }

    int aoff[4][MI], boff[4][2];
#pragma unroll
    for (int kk = 0; kk < 4; ++kk) {
        int ch = (kk * 2 + (l >> 5)) ^ (l & 7);
#pragma unroll
        for (int i = 0; i < MI; ++i)
            aoff[kk][i] = (wr + i * 32 + (l & 31)) * 64 + ch * 8;
#pragma unroll
        for (int j = 0; j < 2; ++j)
            boff[kk][j] = (wc + j * 32 + (l & 31)) * 64 + ch * 8;
    }

    for (int k0 = 0; k0 < K; k0 += 64) {
#pragma unroll
        for (int q = 0; q < QA; ++q)
            GLD16(gA[q] + k0, As + (w * QA + q) * 512);
#pragma unroll
        for (int q = 0; q < 4; ++q)
            GLD16(gB[q] + k0, Bs + (w * 4 + q) * 512);
        __syncthreads();

#pragma unroll
        for (int kk = 0; kk < 4; ++kk) {
            f16x8 af[MI], bf[2];
#pragma unroll
            for (int i = 0; i < MI; ++i)
                af[i] = *(const f16x8*)(As + aoff[kk][i]);
#pragma unroll
            for (int j = 0; j < 2; ++j)
                bf[j] = *(const f16x8*)(Bs + boff[kk][j]);
#pragma unroll
            for (int i = 0; i < MI; ++i)
#pragma unroll
                for (int j = 0; j < 2; ++j)
                    acc[i][j] = __builtin_amdgcn_mfma_f32_32x32x16_f16(
                        af[i], bf[j], acc[i][j], 0, 0, 0);
        }
        __syncthreads();
    }

    // epilogue: col = bn+wc+j*32+(l&31); rows = bm+wr+i*32+8*rg+4*(l>>5)+0..3
#pragma unroll
    for (int i = 0; i < MI; ++i) {
#pragma unroll
        for (int j = 0; j < 2; ++j) {
            int col = bn + wc + j * 32 + (l & 31);
            float bv = bias[col];
#pragma unroll
            for (int rg = 0; rg < 4; ++rg) {
                int row0 = bm + wr + i * 32 + 8 * rg + 4 * (l >> 5);
#pragma unroll
                for (int r = 0; r < 4; ++r) {
                    float v = acc[i][j][rg * 4 + r] + bv;
                    if (ACT) v = gelu_tanh(v);
                    if (OUT16)
                        ((_Float16*)Cp)[(size_t)(row0 + r) * N + col] = (_Float16)v;
                    else
                        ((float*)Cp)[(size_t)(row0 + r) * N + col] = v;
                }
            }
        }
    }
}

// ---------------------------------------------------------------------------
// Attention core: K dbuf f16 LDS; V j-paired f16; PV on fdot2; lsum from the
// f16 p values; setprio(1) around compute.
// ---------------------------------------------------------------------------
template<int NT, bool EDGE>
__device__ __forceinline__ void attn_block(
    const _Float16* __restrict__ qkv, const int* __restrict__ key_idx,
    _Float16* __restrict__ outp, float* __restrict__ pm,
    float* __restrict__ pl, float* __restrict__ pacc,
    int b, int h, int n, int split, int be,
    _Float16 (*qs)[72], _Float16 (*ks)[16][72],
    _Float16 (*vpl)[8][64][2], _Float16 (*ps16)[24])
{
    int t = threadIdx.x;
    int i = t >> 4;        // query row / staging row
    int c = t & 15;
    int c4 = c * 4;

    // stage Q tile; load tile 0 into registers
    *(f16x4*)&qs[i][c4] =
        *(const f16x4*)&qkv[((size_t)(b * S_ + n * BS_ + i)) * (3 * D_) + h * DH_ + c4];
    int kb0 = EDGE ? split * NT : key_idx[n * 7];
    const _Float16* kp0 = qkv + ((size_t)(b * S_ + kb0 * BS_ + i)) * (3 * D_) + D_ + h * DH_;
    f16x4 kr = *(const f16x4*)(kp0 + c4);
    f16x4 vr = *(const f16x4*)(kp0 + D_ + c4);
    __syncthreads();   // qs visible

    f16x8 qv[8];
#pragma unroll
    for (int d0 = 0; d0 < 8; ++d0) qv[d0] = *(const f16x8*)&qs[i][d0 * 8];

    // write tile 0 into buffer 0; prefetch tile 1
    *(f16x4*)&ks[0][i][c4] = kr;
#pragma unroll
    for (int u = 0; u < 4; ++u) vpl[0][i >> 1][c4 + u][i & 1] = vr[u];
    if (NT > 1) {
        int kb1 = EDGE ? (split * NT + 1) : key_idx[n * 7 + 1];
        const _Float16* kp1 = qkv + ((size_t)(b * S_ + kb1 * BS_ + i)) * (3 * D_) + D_ + h * DH_;
        kr = *(const f16x4*)(kp1 + c4);
        vr = *(const f16x4*)(kp1 + D_ + c4);
    }
    __syncthreads();   // buffer 0 staged

    float m_old = -1e30f, lsum = 0.f;
    float acc0 = 0.f, acc1 = 0.f, acc2 = 0.f, acc3 = 0.f;
    const f16x2 one2 = {(_Float16)1.f, (_Float16)1.f};

#pragma unroll 1
    for (int jj = 0; jj < NT; ++jj) {
        int cur = jj & 1;
        if (jj + 1 < NT) {
            *(f16x4*)&ks[cur ^ 1][i][c4] = kr;
#pragma unroll
            for (int u = 0; u < 4; ++u) vpl[cur ^ 1][i >> 1][c4 + u][i & 1] = vr[u];
        }
        if (jj + 2 < NT) {
            int kb2 = EDGE ? (split * NT + jj + 2) : key_idx[n * 7 + jj + 2];
            const _Float16* kp2 = qkv + ((size_t)(b * S_ + kb2 * BS_ + i)) * (3 * D_) + D_ + h * DH_;
            kr = *(const f16x4*)(kp2 + c4);
            vr = *(const f16x4*)(kp2 + D_ + c4);
        }

        __builtin_amdgcn_s_setprio(1);
        // score: <q_i, k_c> via fdot2 over b128 LDS reads
        float s0 = 0.f, s1 = 0.f;
#pragma unroll
        for (int d0 = 0; d0 < 8; ++d0) {
            f16x8 kv = *(const f16x8*)&ks[cur][c][d0 * 8];
            s0 = dot2acc(SV2(qv[d0], 0), SV2(kv, 0), s0);
            s1 = dot2acc(SV2(qv[d0], 2), SV2(kv, 2), s1);
            s0 = dot2acc(SV2(qv[d0], 4), SV2(kv, 4), s0);
            s1 = dot2acc(SV2(qv[d0], 6), SV2(kv, 6), s1);
        }
        float s = (s0 + s1) * SCALE_F;

        // row max (fp32, 16-lane shuffle); p in f16 via LDS
        float rm = s;
#pragma unroll
        for (int off = 8; off; off >>= 1) rm = fmaxf(rm, __shfl_xor(rm, off, 64));
        float m_new = fmaxf(m_old, rm);
        float p = __expf(s - m_new);

        ps16[i][c] = (_Float16)p;
        f16x8 plo = *(const f16x8*)&ps16[i][0];   // p0..p7  (jp 0..3)
        f16x8 phi = *(const f16x8*)&ps16[i][8];   // p8..p15 (jp 4..7)

        // row sum from the same f16 p values (no shuffle reduce)
        float rs = 0.f;
        rs = dot2acc(SV2(plo, 0), one2, rs);
        rs = dot2acc(SV2(plo, 2), one2, rs);
        rs = dot2acc(SV2(plo, 4), one2, rs);
        rs = dot2acc(SV2(plo, 6), one2, rs);
        rs = dot2acc(SV2(phi, 0), one2, rs);
        rs = dot2acc(SV2(phi, 2), one2, rs);
        rs = dot2acc(SV2(phi, 4), one2, rs);
        rs = dot2acc(SV2(phi, 6), one2, rs);

        float corr = __expf(m_old - m_new);
        lsum = lsum * corr + rs;
        acc0 *= corr; acc1 *= corr; acc2 *= corr; acc3 *= corr;

        // PV: V j-paired; fdot2 accumulation (literal shuffle indices)
#define PVJ(JP, PSRC, OFF)                                            \
        {                                                             \
            f16x8 vv = *(const f16x8*)&vpl[cur][JP][c4][0];           \
            f16x2 pp = SV2(PSRC, OFF);                                \
            acc0 = dot2acc(pp, SV2(vv, 0), acc0);                     \
            acc1 = dot2acc(pp, SV2(vv, 2), acc1);                     \
            acc2 = dot2acc(pp, SV2(vv, 4), acc2);                     \
            acc3 = dot2acc(pp, SV2(vv, 6), acc3);                     \
        }
        PVJ(0, plo, 0) PVJ(1, plo, 2) PVJ(2, plo, 4) PVJ(3, plo, 6)
        PVJ(4, phi, 0) PVJ(5, phi, 2) PVJ(6, phi, 4) PVJ(7, phi, 6)
#undef PVJ
        __builtin_amdgcn_s_setprio(0);
        m_old = m_new;
        __syncthreads();   // all reads of cur done; writes to cur^1 visible
    }

    if (EDGE) {
        int psx = (be * NSPLIT + split) * 16 + i;
        if (c == 0) { pm[psx] = m_old; pl[psx] = lsum; }
        float* pd = pacc + (size_t)psx * 64 + c4;
        pd[0] = acc0; pd[1] = acc1; pd[2] = acc2; pd[3] = acc3;
    } else {
        float inv = 1.f / lsum;
        _Float16* dst = outp + ((size_t)(b * S_ + n * BS_ + i)) * D_ + h * DH_ + c4;
        dst[0] = (_Float16)(acc0 * inv);
        dst[1] = (_Float16)(acc1 * inv);
        dst[2] = (_Float16)(acc2 * inv);
        dst[3] = (_Float16)(acc3 * inv);
    }
}

// ---------------------------------------------------------------------------
// Fused attention dispatch: sparse + edge split-K in one grid (XCD swizzled).
// ---------------------------------------------------------------------------
__global__ __launch_bounds__(256) void attn_fused(
    const _Float16* __restrict__ qkv, const int* __restrict__ key_idx,
    _Float16* __restrict__ outp, float* __restrict__ pm,
    float* __restrict__ pl, float* __restrict__ pacc)
{
    __shared__ __attribute__((aligned(16))) _Float16 qs[16][72];
    __shared__ __attribute__((aligned(16))) _Float16 ks[2][16][72];
    __shared__ __attribute__((aligned(16))) _Float16 vpl[2][8][64][2];
    __shared__ __attribute__((aligned(16))) _Float16 ps16[16][24];

    int bi = xcd_swz(blockIdx.x, gridDim.x);
    if (bi < NSPARSE) {
        int n = bi % NB_;
        if (n == 0 || n == NB_ - 1) return;
        int h = (bi / NB_) % H_;
        int b = bi / (NB_ * H_);
        attn_block<7, false>(qkv, key_idx, outp, nullptr, nullptr, nullptr,
                             b, h, n, 0, 0, qs, ks, vpl, ps16);
    } else {
        int ei = bi - NSPARSE;
        int split = ei % NSPLIT;
        int be = ei / NSPLIT;
        int e = be & 1;
        int h = (be >> 1) % H_;
        int b = be / (2 * H_);
        int n = e ? (NB_ - 1) : 0;
        attn_block<TILES_PER_SPLIT, true>(qkv, nullptr, nullptr, pm, pl, pacc,
                                          b, h, n, split, be, qs, ks, vpl, ps16);
    }
}

// ---------------------------------------------------------------------------
// Edge attention combine
// ---------------------------------------------------------------------------
__global__ __launch_bounds__(256) void attn_edge_combine(
    const float* __restrict__ pm, const float* __restrict__ pl,
    const float* __restrict__ pacc, _Float16* __restrict__ outp)
{
    int be = blockIdx.x;
    int e = be & 1;
    int h = (be >> 1) % H_;
    int b = be / (2 * H_);
    int n = e ? (NB_ - 1) : 0;

    int t = threadIdx.x;
    int i = t >> 4;
    int c = t & 15;

    float M = -1e30f;
#pragma unroll 4
    for (int s = 0; s < NSPLIT; ++s)
        M = fmaxf(M, pm[(be * NSPLIT + s) * 16 + i]);

    float L = 0.f;
    float acc[4] = {0.f, 0.f, 0.f, 0.f};
    for (int s = 0; s < NSPLIT; ++s) {
        int ps = (be * NSPLIT + s) * 16 + i;
        float wgt = __expf(pm[ps] - M);
        L += pl[ps] * wgt;
#pragma unroll
        for (int u = 0; u < 4; ++u) acc[u] += pacc[(size_t)ps * 64 + c * 4 + u] * wgt;
    }

    float inv = 1.f / L;
    _Float16* dst = outp + ((size_t)(b * S_ + n * BS_ + i)) * D_ + h * DH_ + c * 4;
#pragma unroll
    for (int u = 0; u < 4; ++u) dst[u] = (_Float16)(acc[u] * inv);
}

// ---------------------------------------------------------------------------
// LN: residual stream in f16. xh = LN(xh + g) (stats in f32).
// WRITE32: additionally write the f32 row (only the FINAL LN, for heads).
// ---------------------------------------------------------------------------
template<int WRITE32>
__global__ __launch_bounds__(256) void add_ln_kernel(
    _Float16* __restrict__ xh, const _Float16* __restrict__ g,
    const float* __restrict__ gamma, const float* __restrict__ beta,
    float* __restrict__ x32)
{
    int row = blockIdx.x;
    int t = threadIdx.x;
    _Float16* xr = xh + (size_t)row * D_;
    const _Float16* gr = g + (size_t)row * D_;

    float v[3];
    float s = 0.f, s2 = 0.f;
#pragma unroll
    for (int r = 0; r < 3; ++r) {
        int d = t + 256 * r;
        v[r] = (float)xr[d] + (float)gr[d];
        s += v[r];
        s2 += v[r] * v[r];
    }
#pragma unroll
    for (int off = 32; off; off >>= 1) {
        s  += __shfl_xor(s, off, 64);
        s2 += __shfl_xor(s2, off, 64);
    }
    __shared__ float sA[4], sB[4];
    int wave = t >> 6, lane = t & 63;
    if (lane == 0) { sA[wave] = s; sB[wave] = s2; }
    __syncthreads();
    s  = sA[0] + sA[1] + sA[2] + sA[3];
    s2 = sB[0] + sB[1] + sB[2] + sB[3];
    float mean = s * (1.0f / D_);
    float var = s2 * (1.0f / D_) - mean * mean;
    float rstd = rsqrtf(var + 1e-12f);
#pragma unroll
    for (int r = 0; r < 3; ++r) {
        int d = t + 256 * r;
        float o = (v[r] - mean) * rstd * gamma[d] + beta[d];
        xr[d] = (_Float16)o;
        if (WRITE32) x32[(size_t)row * D_ + d] = o;
    }
}

// ---------------------------------------------------------------------------
// Fused heads: blockIdx < 2048 -> start/end logits; else disc pool partial.
// ---------------------------------------------------------------------------
__global__ __launch_bounds__(256) void heads_fused(
    const float* __restrict__ x, const float* __restrict__ sw,
    const float* __restrict__ ew, const float* __restrict__ Wp,
    float* __restrict__ sl, float* __restrict__ el,
    float* __restrict__ partial)
{
    int bi = blockIdx.x;
    int t = threadIdx.x;
    if (bi < 2048) {
        int wave = t >> 6, lane = t & 63;
        int row = bi * 4 + wave;
        const float* xr = x + (size_t)row * D_;
        float a = 0.f, e = 0.f;
        for (int d = lane; d < D_; d += 64) {
            float xv = xr[d];
            a += xv * sw[d];
            e += xv * ew[d];
        }
#pragma unroll
        for (int off = 32; off; off >>= 1) {
            a += __shfl_xor(a, off, 64);
            e += __shfl_xor(e, off, 64);
        }
        if (lane == 0) { sl[row] = a; el[row] = e; }
    } else {
        int ei = bi - 2048;       // 0..23
        int jb = ei % 3;          // 0..2
        int ks = ei / 3;          // 0..7
        int j = jb * 256 + t;
        int k0 = ks * DKC;

        __shared__ float xs[DKC];
        if (t < DKC) xs[t] = x[k0 + t];   // x0 = x row 0
        __syncthreads();

        float s = 0.f;
#pragma unroll 8
        for (int kk = 0; kk < DKC; ++kk)
            s += xs[kk] * Wp[(size_t)(k0 + kk) * D_ + j];
        partial[ks * D_ + j] = s;
    }
}

// ---------------------------------------------------------------------------
// Fused final: r<4 -> softmax over S; r==4 -> disc finish.
// ---------------------------------------------------------------------------
__global__ __launch_bounds__(256) void final_fused(
    const float* __restrict__ sl, const float* __restrict__ el,
    const float* __restrict__ partial, const float* __restrict__ bp,
    const float* __restrict__ d1W, const float* __restrict__ d1b,
    const float* __restrict__ d2W, const float* __restrict__ d2b,
    float* __restrict__ outp)
{
    int r = blockIdx.x;
    int t = threadIdx.x;
    if (r < 4) {
        const float* src = (r < 2 ? sl : el) + (size_t)(r & 1) * S_;
        float* dst = outp + (r < 2 ? 0 : BT_) + (size_t)(r & 1) * S_;
        int wave = t >> 6, lane = t & 63;
        __shared__ float sm[4], ss[4];

        float m = -1e30f;
        for (int k = t; k < S_; k += 256) m = fmaxf(m, src[k]);
#pragma unroll
        for (int off = 32; off; off >>= 1) m = fmaxf(m, __shfl_xor(m, off, 64));
        if (lane == 0) sm[wave] = m;
        __syncthreads();
        m = fmaxf(fmaxf(sm[0], sm[1]), fmaxf(sm[2], sm[3]));

        float s = 0.f;
        for (int k = t; k < S_; k += 256) s += __expf(src[k] - m);
#pragma unroll
        for (int off = 32; off; off >>= 1) s += __shfl_xor(s, off, 64);
        if (lane == 0) ss[wave] = s;
        __syncthreads();
        s = ss[0] + ss[1] + ss[2] + ss[3];

        float inv = 1.f / s;
        for (int k = t; k < S_; k += 256) dst[k] = __expf(src[k] - m) * inv;
    } else {
        __shared__ float pool[D_];
        __shared__ float h1[20];
        float* out2 = outp + 2 * BT_;
        for (int j = t; j < D_; j += 256) {
            float s = bp[j];
#pragma unroll
            for (int ks = 0; ks < DKS; ++ks) s += partial[ks * D_ + j];
            pool[j] = tanhf(s);
        }
        __syncthreads();
        if (t < 20) {
            float s = d1b[t];
            for (int k = 0; k < D_; ++k) s += pool[k] * d1W[k * 20 + t];
            h1[t] = s;
        }
        __syncthreads();
        if (t == 0) {
            float d0 = d2b[0], d1v = d2b[1];
#pragma unroll
            for (int u = 0; u < 20; ++u) {
                d0  += h1[u] * d2W[u * 2 + 0];
                d1v += h1[u] * d2W[u * 2 + 1];
            }
            float m = fmaxf(d0, d1v);
            float e0 = __expf(d0 - m), e1 = __expf(d1v - m);
            float inv = 1.f / (e0 + e1);
            out2[0] = e0 * inv;
            out2[1] = e1 * inv;
        }
    }
}

// ---------------------------------------------------------------------------
extern "C" void kernel_launch(void* const* d_in, const int* in_sizes, int n_in,
                              void* d_out, int out_size, void* d_ws, size_t ws_size,
                              hipStream_t stream)
{
    const int*   ids   = (const int*)d_in[0];
    const int*   kbi   = (const int*)d_in[1];
    const float* emb   = (const float*)d_in[2];
    const float* Wqkv  = (const float*)d_in[3];
    const float* bqkv  = (const float*)d_in[4];
    const float* Wo    = (const float*)d_in[5];
    const float* bo    = (const float*)d_in[6];
    const float* ln1g  = (const float*)d_in[7];
    const float* ln1b  = (const float*)d_in[8];
    const float* Wff1  = (const float*)d_in[9];
    const float* bff1  = (const float*)d_in[10];
    const float* Wff2  = (const float*)d_in[11];
    const float* bff2  = (const float*)d_in[12];
    const float* ln2g  = (const float*)d_in[13];
    const float* ln2b  = (const float*)d_in[14];
    const float* Wp    = (const float*)d_in[15];
    const float* bp    = (const float*)d_in[16];
    const float* sw    = (const float*)d_in[17];
    const float* ew    = (const float*)d_in[18];
    const float* d1W   = (const float*)d_in[19];
    const float* d1b   = (const float*)d_in[20];
    const float* d2W   = (const float*)d_in[21];
    const float* d2b   = (const float*)d_in[22];
    float* outp = (float*)d_out;

    // workspace carve (float units)
    float* ws   = (float*)d_ws;
    float* x    = ws;                          // BT_*D_ f32 (final LN only)
    float* xbf  = x   + (size_t)BT_ * D_;      // f16 xh (residual stream)
    float* r1f  = xbf + (size_t)BT_ * D_ / 2;  // f16 qkv / f16 h
    float* abf  = r1f + (size_t)BT_ * FF_ / 2; // f16 attn out
    float* r2   = abf + (size_t)BT_ * D_ / 2;  // partials (early) / f16 g (late)
    float* wtf  = r2  + (size_t)BT_ * D_;      // f16 weights
    float* sl   = wtf + 7077888;
    float* el   = sl  + BT_;
    float* dpar = el  + BT_;                   // DKS * D_ disc partials

    _Float16* xh    = (_Float16*)xbf;
    _Float16* qkv16 = (_Float16*)r1f;
    _Float16* h16   = (_Float16*)r1f;
    _Float16* ab    = (_Float16*)abf;
    float* pm   = r2;
    float* pl   = r2 + NEDGE * NSPLIT * 16;
    float* pacc = pl + NEDGE * NSPLIT * 16;
    _Float16* g16 = (_Float16*)r2;   // aliased; partials dead once proj runs

    _Float16* Wt    = (_Float16*)wtf;
    _Float16* WqkvT = Wt;
    _Float16* WoT   = WqkvT + (size_t)2 * 2304 * 768;
    _Float16* Wff1T = WoT   + (size_t)2 * 768 * 768;
    _Float16* Wff2T = Wff1T + (size_t)2 * 3072 * 768;

    // fused weight convert + embed: one dispatch
    WSegs segs;
    int start = 0;
    for (int l = 0; l < 2; ++l) {
        int base = l * 4;
        segs.s[base + 0] = { Wqkv + (size_t)l * 768 * 2304,
                             WqkvT + (size_t)l * 2304 * 768, 768, 2304, start };
        start += (2304 / 32) * (768 / 32);
        segs.s[base + 1] = { Wo + (size_t)l * 768 * 768,
                             WoT + (size_t)l * 768 * 768, 768, 768, start };
        start += (768 / 32) * (768 / 32);
        segs.s[base + 2] = { Wff1 + (size_t)l * 768 * 3072,
                             Wff1T + (size_t)l * 3072 * 768, 768, 3072, start };
        start += (3072 / 32) * (768 / 32);
        segs.s[base + 3] = { Wff2 + (size_t)l * 3072 * 768,
                             Wff2T + (size_t)l * 768 * 3072, 3072, 768, start };
        start += (768 / 32) * (3072 / 32);
    }
    segs.total = start;   // 13824

    prep_all<<<segs.total + BT_, 256, 0, stream>>>(segs, ids, emb, xh);

    for (int l = 0; l < 2; ++l) {
        // qkv: BM=128, grid 64x18 = 1152
        gemm_f16<2,0,1><<<(BT_/128) * (2304/128), 256, 0, stream>>>(
            xh, WqkvT + (size_t)l * 2304 * 768, bqkv + (size_t)l * 3 * D_,
            qkv16, BT_, 3 * D_, D_, 2304/128);
        attn_fused<<<NSPARSE + NEDGE * NSPLIT, 256, 0, stream>>>(
            qkv16, kbi, ab, pm, pl, pacc);
        attn_edge_combine<<<NEDGE, 256, 0, stream>>>(pm, pl, pacc, ab);
        // proj: BM=64, grid 128x6 = 768 (latency-bound shape -> 2x blocks)
        gemm_f16<1,0,1><<<(BT_/64) * (768/128), 256, 0, stream>>>(
            ab, WoT + (size_t)l * 768 * 768, bo + (size_t)l * D_,
            g16, BT_, D_, D_, 768/128);
        add_ln_kernel<0><<<BT_, 256, 0, stream>>>(
            xh, g16, ln1g + (size_t)l * D_, ln1b + (size_t)l * D_, nullptr);
        // ff1: BM=128, grid 64x24 = 1536
        gemm_f16<2,1,1><<<(BT_/128) * (3072/128), 256, 0, stream>>>(
            xh, Wff1T + (size_t)l * 3072 * 768, bff1 + (size_t)l * FF_,
            h16, BT_, FF_, D_, 3072/128);
        // ff2: BM=64, grid 128x6 = 768
        gemm_f16<1,0,1><<<(BT_/64) * (768/128), 256, 0, stream>>>(
            h16, Wff2T + (size_t)l * 768 * 3072, bff2 + (size_t)l * D_,
            g16, BT_, D_, FF_, 768/128);
        if (l == 1)
            add_ln_kernel<1><<<BT_, 256, 0, stream>>>(
                xh, g16, ln2g + (size_t)l * D_, ln2b + (size_t)l * D_, x);
        else
            add_ln_kernel<0><<<BT_, 256, 0, stream>>>(
                xh, g16, ln2g + (size_t)l * D_, ln2b + (size_t)l * D_, nullptr);
    }

    heads_fused<<<2048 + 3 * DKS, 256, 0, stream>>>(x, sw, ew, Wp, sl, el, dpar);
    final_fused<<<5, 256, 0, stream>>>(sl, el, dpar, bp, d1W, d1b, d2W, d2b, outp);
}

// Round 23
// 607.570 us; speedup vs baseline: 1.2761x; 1.0021x over previous
//
#include <hip/hip_runtime.h>
#include <hip/hip_bf16.h>
#include <math.h>

#define B_   2
#define S_   4096
#define D_   768
#define H_   12
#define DH_  64
#define BS_  16
#define NB_  256
#define FF_  3072
#define BT_  (B_ * S_)          // 8192 token rows
#define SCALE_F 0.125f          // 1/sqrt(64)

#define NSPLIT 32               // key-dimension splits for edge attention
#define TILES_PER_SPLIT (NB_ / NSPLIT)   // 8
#define NEDGE (B_ * H_ * 2)     // 48 edge (b,h,e) groups
#define NSPARSE (B_ * H_ * NB_) // 6144 sparse blocks
#define NXCD 8

typedef _Float16 f16x8 __attribute__((ext_vector_type(8)));
typedef _Float16 f16x4 __attribute__((ext_vector_type(4)));
typedef _Float16 f16x2 __attribute__((ext_vector_type(2)));
typedef float    f32x4 __attribute__((ext_vector_type(4)));
typedef float    f32x16 __attribute__((ext_vector_type(16)));

#define DKS 8                   // disc pool k-splits
#define DKC (D_ / DKS)          // 96 rows per split

#define SV2(v, k) __builtin_shufflevector(v, v, k, (k) + 1)

// XCD-aware swizzle (T1): valid bijection when nwg % NXCD == 0.
__device__ __forceinline__ int xcd_swz(int bid, int nwg)
{
    int q = nwg / NXCD;
    return (bid % NXCD) * q + bid / NXCD;
}

__device__ __forceinline__ float dot2acc(f16x2 a, f16x2 b, float c)
{
#if __has_builtin(__builtin_amdgcn_fdot2)
    return __builtin_amdgcn_fdot2(a, b, c, false);
#else
    return c + (float)a[0] * (float)b[0] + (float)a[1] * (float)b[1];
#endif
}

// async global->LDS, 16B per lane; LDS dest is wave-uniform base + lane*16
#define GLD16(gp, lp) __builtin_amdgcn_global_load_lds( \
    (const __attribute__((address_space(1))) void*)(gp), \
    (__attribute__((address_space(3))) void*)(lp), 16, 0, 0)

__device__ __forceinline__ float fast_tanh(float z)
{
    float az = fabsf(z);
    float t = __expf(-2.0f * az);
    float r = (1.0f - t) / (1.0f + t);
    return z < 0.f ? -r : r;
}

__device__ __forceinline__ float gelu_tanh(float v)
{
    float v3 = v * v * v;
    return 0.5f * v * (1.0f + fast_tanh(0.79788456080286535588f * (v + 0.044715f * v3)));
}

// ---------------------------------------------------------------------------
// Fused weight convert + embedding (vectorized transpose).
// ---------------------------------------------------------------------------
struct WSeg { const float* src; _Float16* dst; int K; int N; int start; };
struct WSegs { WSeg s[8]; int total; };

__global__ __launch_bounds__(256) void prep_all(
    WSegs segs, const int* __restrict__ ids, const float* __restrict__ emb,
    _Float16* __restrict__ xh)
{
    int bt = blockIdx.x;
    int t = threadIdx.x;
    if (bt < segs.total) {
        __shared__ float tile[32][33];
        int si = 0;
#pragma unroll
        for (int u = 1; u < 8; ++u)
            if (bt >= segs.s[u].start) si = u;
        const WSeg& sg = segs.s[si];
        int tid = bt - sg.start;
        int tn = sg.N >> 5;
        int n0 = (tid % tn) * 32;
        int k0 = (tid / tn) * 32;

        {
            int r = t >> 3, c = (t & 7) * 4;
            f32x4 v = *(const f32x4*)&sg.src[(size_t)(k0 + r) * sg.N + n0 + c];
            tile[r][c + 0] = v[0];
            tile[r][c + 1] = v[1];
            tile[r][c + 2] = v[2];
            tile[r][c + 3] = v[3];
        }
        __syncthreads();
        {
            int r = t >> 3, c = (t & 7) * 4;
            f16x4 o;
            o[0] = (_Float16)tile[c + 0][r];
            o[1] = (_Float16)tile[c + 1][r];
            o[2] = (_Float16)tile[c + 2][r];
            o[3] = (_Float16)tile[c + 3][r];
            *(f16x4*)&sg.dst[(size_t)(n0 + r) * sg.K + k0 + c] = o;
        }
    } else {
        int row = bt - segs.total;
        int id = ids[row];
        const float* src = emb + (size_t)id * D_;
        _Float16* dst16 = xh + (size_t)row * D_;
        for (int d = t; d < D_; d += 256)
            dst16[d] = (_Float16)src[d];
    }
}

// ---------------------------------------------------------------------------
// MFMA fp16 GEMM (r22): templated M-block + optional 2-phase double buffer.
// MI=2 (BM=128): single-buffered (dbuf would need 64KB -> m132 occupancy
// cliff). MI=1 (BM=64): DBUF=1, 48KB LDS — T3-minimum schedule: issue
// STAGE(next) BEFORE compute(cur); ONE barrier/iter whose implicit vmcnt(0)
// lands after compute, so the prefetch flight overlaps the MFMAs.
// ---------------------------------------------------------------------------
template<int MI, int DBUF, int ACT, int OUT16>
__global__ __launch_bounds__(256) void gemm_f16(
    const _Float16* __restrict__ A, const _Float16* __restrict__ Wt,
    const float* __restrict__ bias, void* __restrict__ Cp,
    int M, int N, int K, int NT128)
{
    constexpr int BM = MI * 64;
    constexpr int QA = 2 * MI;          // A 1KB chunks per wave
    constexpr int ASZ = BM * 64;        // f16 elems per A buffer
    constexpr int BSZ = 128 * 64;       // f16 elems per B buffer

    __shared__ __attribute__((aligned(16))) _Float16 As[(DBUF ? 2 : 1) * ASZ];
    __shared__ __attribute__((aligned(16))) _Float16 Bs[(DBUF ? 2 : 1) * BSZ];

    int t = threadIdx.x;
    int w = t >> 6, l = t & 63;
    int swz = xcd_swz(blockIdx.x, gridDim.x);
    int bm = (swz / NT128) * BM, bn = (swz % NT128) * 128;
    int wr = (w >> 1) * (MI * 32), wc = (w & 1) * 64;

    f32x16 acc[MI][2];
#pragma unroll
    for (int i = 0; i < MI; ++i)
#pragma unroll
        for (int j = 0; j < 2; ++j)
#pragma unroll
            for (int r = 0; r < 16; ++r) acc[i][j][r] = 0.f;

    const _Float16* gA[QA];
    const _Float16* gB[4];
#pragma unroll
    for (int q = 0; q < QA; ++q) {
        int m = w * QA + q;
        int row = m * 8 + (l >> 3);
        int sc = (l & 7) ^ (row & 7);
        gA[q] = A + (size_t)(bm + row) * K + sc * 8;
    }
#pragma unroll
    for (int q = 0; q < 4; ++q) {
        int m = w * 4 + q;
        int row = m * 8 + (l >> 3);
        int sc = (l & 7) ^ (row & 7);
        gB[q] = Wt + (size_t)(bn + row) * K + sc * 8;
    }

    int aoff[4][MI], boff[4][2];
#pragma unroll
    for (int kk = 0; kk < 4; ++kk) {
        int ch = (kk * 2 + (l >> 5)) ^ (l & 7);
#pragma unroll
        for (int i = 0; i < MI; ++i)
            aoff[kk][i] = (wr + i * 32 + (l & 31)) * 64 + ch * 8;
#pragma unroll
        for (int j = 0; j < 2; ++j)
            boff[kk][j] = (wc + j * 32 + (l & 31)) * 64 + ch * 8;
    }

#define STAGE_(BUF, K0)                                                   \
    {                                                                     \
        _Float16* ab_ = As + (BUF) * ASZ;                                 \
        _Float16* bb_ = Bs + (BUF) * BSZ;                                 \
        _Pragma("unroll")                                                 \
        for (int q = 0; q < QA; ++q)                                      \
            GLD16(gA[q] + (K0), ab_ + (w * QA + q) * 512);                \
        _Pragma("unroll")                                                 \
        for (int q = 0; q < 4; ++q)                                       \
            GLD16(gB[q] + (K0), bb_ + (w * 4 + q) * 512);                 \
    }

#define COMPUTE_(BUF)                                                     \
    {                                                                     \
        const _Float16* ab_ = As + (BUF) * ASZ;                           \
        const _Float16* bb_ = Bs + (BUF) * BSZ;                           \
        _Pragma("unroll")                                                 \
        for (int kk = 0; kk < 4; ++kk) {                                  \
            f16x8 af[MI], bf[2];                                          \
            _Pragma("unroll")                                             \
            for (int i = 0; i < MI; ++i)                                  \
                af[i] = *(const f16x8*)(ab_ + aoff[kk][i]);               \
            _Pragma("unroll")                                             \
            for (int j = 0; j < 2; ++j)                                   \
                bf[j] = *(const f16x8*)(bb_ + boff[kk][j]);               \
            _Pragma("unroll")                                             \
            for (int i = 0; i < MI; ++i)                                  \
                _Pragma("unroll")                                         \
                for (int j = 0; j < 2; ++j)                               \
                    acc[i][j] = __builtin_amdgcn_mfma_f32_32x32x16_f16(   \
                        af[i], bf[j], acc[i][j], 0, 0, 0);                \
        }                                                                 \
    }

    if (DBUF) {
        // 2-phase: prefetch of tile k+1 flies during compute of tile k.
        STAGE_(0, 0);
        __syncthreads();
        int cur = 0;
#pragma unroll 2
        for (int k0 = 0; k0 < K; k0 += 64) {
            if (k0 + 64 < K) STAGE_(cur ^ 1, k0 + 64);
            COMPUTE_(cur);
            __syncthreads();   // drains prefetch (vmcnt) + ds reads (lgkm)
            cur ^= 1;
        }
    } else {
        for (int k0 = 0; k0 < K; k0 += 64) {
            STAGE_(0, k0);
            __syncthreads();
            COMPUTE_(0);
            __syncthreads();
        }
    }
#undef STAGE_
#undef COMPUTE_

    // epilogue: col = bn+wc+j*32+(l&31); rows = bm+wr+i*32+8*rg+4*(l>>5)+0..3
#pragma unroll
    for (int i = 0; i < MI; ++i) {
#pragma unroll
        for (int j = 0; j < 2; ++j) {
            int col = bn + wc + j * 32 + (l & 31);
            float bv = bias[col];
#pragma unroll
            for (int rg = 0; rg < 4; ++rg) {
                int row0 = bm + wr + i * 32 + 8 * rg + 4 * (l >> 5);
#pragma unroll
                for (int r = 0; r < 4; ++r) {
                    float v = acc[i][j][rg * 4 + r] + bv;
                    if (ACT) v = gelu_tanh(v);
                    if (OUT16)
                        ((_Float16*)Cp)[(size_t)(row0 + r) * N + col] = (_Float16)v;
                    else
                        ((float*)Cp)[(size_t)(row0 + r) * N + col] = v;
                }
            }
        }
    }
}

// ---------------------------------------------------------------------------
// Attention core: K dbuf f16 LDS; V j-paired f16; PV on fdot2; lsum from the
// f16 p values; setprio(1) around compute.
// ---------------------------------------------------------------------------
template<int NT, bool EDGE>
__device__ __forceinline__ void attn_block(
    const _Float16* __restrict__ qkv, const int* __restrict__ key_idx,
    _Float16* __restrict__ outp, float* __restrict__ pm,
    float* __restrict__ pl, float* __restrict__ pacc,
    int b, int h, int n, int split, int be,
    _Float16 (*qs)[72], _Float16 (*ks)[16][72],
    _Float16 (*vpl)[8][64][2], _Float16 (*ps16)[24])
{
    int t = threadIdx.x;
    int i = t >> 4;        // query row / staging row
    int c = t & 15;
    int c4 = c * 4;

    // stage Q tile; load tile 0 into registers
    *(f16x4*)&qs[i][c4] =
        *(const f16x4*)&qkv[((size_t)(b * S_ + n * BS_ + i)) * (3 * D_) + h * DH_ + c4];
    int kb0 = EDGE ? split * NT : key_idx[n * 7];
    const _Float16* kp0 = qkv + ((size_t)(b * S_ + kb0 * BS_ + i)) * (3 * D_) + D_ + h * DH_;
    f16x4 kr = *(const f16x4*)(kp0 + c4);
    f16x4 vr = *(const f16x4*)(kp0 + D_ + c4);
    __syncthreads();   // qs visible

    f16x8 qv[8];
#pragma unroll
    for (int d0 = 0; d0 < 8; ++d0) qv[d0] = *(const f16x8*)&qs[i][d0 * 8];

    // write tile 0 into buffer 0; prefetch tile 1
    *(f16x4*)&ks[0][i][c4] = kr;
#pragma unroll
    for (int u = 0; u < 4; ++u) vpl[0][i >> 1][c4 + u][i & 1] = vr[u];
    if (NT > 1) {
        int kb1 = EDGE ? (split * NT + 1) : key_idx[n * 7 + 1];
        const _Float16* kp1 = qkv + ((size_t)(b * S_ + kb1 * BS_ + i)) * (3 * D_) + D_ + h * DH_;
        kr = *(const f16x4*)(kp1 + c4);
        vr = *(const f16x4*)(kp1 + D_ + c4);
    }
    __syncthreads();   // buffer 0 staged

    float m_old = -1e30f, lsum = 0.f;
    float acc0 = 0.f, acc1 = 0.f, acc2 = 0.f, acc3 = 0.f;
    const f16x2 one2 = {(_Float16)1.f, (_Float16)1.f};

#pragma unroll 1
    for (int jj = 0; jj < NT; ++jj) {
        int cur = jj & 1;
        if (jj + 1 < NT) {
            *(f16x4*)&ks[cur ^ 1][i][c4] = kr;
#pragma unroll
            for (int u = 0; u < 4; ++u) vpl[cur ^ 1][i >> 1][c4 + u][i & 1] = vr[u];
        }
        if (jj + 2 < NT) {
            int kb2 = EDGE ? (split * NT + jj + 2) : key_idx[n * 7 + jj + 2];
            const _Float16* kp2 = qkv + ((size_t)(b * S_ + kb2 * BS_ + i)) * (3 * D_) + D_ + h * DH_;
            kr = *(const f16x4*)(kp2 + c4);
            vr = *(const f16x4*)(kp2 + D_ + c4);
        }

        __builtin_amdgcn_s_setprio(1);
        // score: <q_i, k_c> via fdot2 over b128 LDS reads
        float s0 = 0.f, s1 = 0.f;
#pragma unroll
        for (int d0 = 0; d0 < 8; ++d0) {
            f16x8 kv = *(const f16x8*)&ks[cur][c][d0 * 8];
            s0 = dot2acc(SV2(qv[d0], 0), SV2(kv, 0), s0);
            s1 = dot2acc(SV2(qv[d0], 2), SV2(kv, 2), s1);
            s0 = dot2acc(SV2(qv[d0], 4), SV2(kv, 4), s0);
            s1 = dot2acc(SV2(qv[d0], 6), SV2(kv, 6), s1);
        }
        float s = (s0 + s1) * SCALE_F;

        // row max (fp32, 16-lane shuffle); p in f16 via LDS
        float rm = s;
#pragma unroll
        for (int off = 8; off; off >>= 1) rm = fmaxf(rm, __shfl_xor(rm, off, 64));
        float m_new = fmaxf(m_old, rm);
        float p = __expf(s - m_new);

        ps16[i][c] = (_Float16)p;
        f16x8 plo = *(const f16x8*)&ps16[i][0];   // p0..p7  (jp 0..3)
        f16x8 phi = *(const f16x8*)&ps16[i][8];   // p8..p15 (jp 4..7)

        // row sum from the same f16 p values (no shuffle reduce)
        float rs = 0.f;
        rs = dot2acc(SV2(plo, 0), one2, rs);
        rs = dot2acc(SV2(plo, 2), one2, rs);
        rs = dot2acc(SV2(plo, 4), one2, rs);
        rs = dot2acc(SV2(plo, 6), one2, rs);
        rs = dot2acc(SV2(phi, 0), one2, rs);
        rs = dot2acc(SV2(phi, 2), one2, rs);
        rs = dot2acc(SV2(phi, 4), one2, rs);
        rs = dot2acc(SV2(phi, 6), one2, rs);

        float corr = __expf(m_old - m_new);
        lsum = lsum * corr + rs;
        acc0 *= corr; acc1 *= corr; acc2 *= corr; acc3 *= corr;

        // PV: V j-paired; fdot2 accumulation (literal shuffle indices)
#define PVJ(JP, PSRC, OFF)                                            \
        {                                                             \
            f16x8 vv = *(const f16x8*)&vpl[cur][JP][c4][0];           \
            f16x2 pp = SV2(PSRC, OFF);                                \
            acc0 = dot2acc(pp, SV2(vv, 0), acc0);                     \
            acc1 = dot2acc(pp, SV2(vv, 2), acc1);                     \
            acc2 = dot2acc(pp, SV2(vv, 4), acc2);                     \
            acc3 = dot2acc(pp, SV2(vv, 6), acc3);                     \
        }
        PVJ(0, plo, 0) PVJ(1, plo, 2) PVJ(2, plo, 4) PVJ(3, plo, 6)
        PVJ(4, phi, 0) PVJ(5, phi, 2) PVJ(6, phi, 4) PVJ(7, phi, 6)
#undef PVJ
        __builtin_amdgcn_s_setprio(0);
        m_old = m_new;
        __syncthreads();   // all reads of cur done; writes to cur^1 visible
    }

    if (EDGE) {
        int psx = (be * NSPLIT + split) * 16 + i;
        if (c == 0) { pm[psx] = m_old; pl[psx] = lsum; }
        float* pd = pacc + (size_t)psx * 64 + c4;
        pd[0] = acc0; pd[1] = acc1; pd[2] = acc2; pd[3] = acc3;
    } else {
        float inv = 1.f / lsum;
        _Float16* dst = outp + ((size_t)(b * S_ + n * BS_ + i)) * D_ + h * DH_ + c4;
        dst[0] = (_Float16)(acc0 * inv);
        dst[1] = (_Float16)(acc1 * inv);
        dst[2] = (_Float16)(acc2 * inv);
        dst[3] = (_Float16)(acc3 * inv);
    }
}

// ---------------------------------------------------------------------------
// Fused attention dispatch: sparse + edge split-K in one grid (XCD swizzled).
// ---------------------------------------------------------------------------
__global__ __launch_bounds__(256) void attn_fused(
    const _Float16* __restrict__ qkv, const int* __restrict__ key_idx,
    _Float16* __restrict__ outp, float* __restrict__ pm,
    float* __restrict__ pl, float* __restrict__ pacc)
{
    __shared__ __attribute__((aligned(16))) _Float16 qs[16][72];
    __shared__ __attribute__((aligned(16))) _Float16 ks[2][16][72];
    __shared__ __attribute__((aligned(16))) _Float16 vpl[2][8][64][2];
    __shared__ __attribute__((aligned(16))) _Float16 ps16[16][24];

    int bi = xcd_swz(blockIdx.x, gridDim.x);
    if (bi < NSPARSE) {
        int n = bi % NB_;
        if (n == 0 || n == NB_ - 1) return;
        int h = (bi / NB_) % H_;
        int b = bi / (NB_ * H_);
        attn_block<7, false>(qkv, key_idx, outp, nullptr, nullptr, nullptr,
                             b, h, n, 0, 0, qs, ks, vpl, ps16);
    } else {
        int ei = bi - NSPARSE;
        int split = ei % NSPLIT;
        int be = ei / NSPLIT;
        int e = be & 1;
        int h = (be >> 1) % H_;
        int b = be / (2 * H_);
        int n = e ? (NB_ - 1) : 0;
        attn_block<TILES_PER_SPLIT, true>(qkv, nullptr, nullptr, pm, pl, pacc,
                                          b, h, n, split, be, qs, ks, vpl, ps16);
    }
}

// ---------------------------------------------------------------------------
// Edge attention combine
// ---------------------------------------------------------------------------
__global__ __launch_bounds__(256) void attn_edge_combine(
    const float* __restrict__ pm, const float* __restrict__ pl,
    const float* __restrict__ pacc, _Float16* __restrict__ outp)
{
    int be = blockIdx.x;
    int e = be & 1;
    int h = (be >> 1) % H_;
    int b = be / (2 * H_);
    int n = e ? (NB_ - 1) : 0;

    int t = threadIdx.x;
    int i = t >> 4;
    int c = t & 15;

    float M = -1e30f;
#pragma unroll 4
    for (int s = 0; s < NSPLIT; ++s)
        M = fmaxf(M, pm[(be * NSPLIT + s) * 16 + i]);

    float L = 0.f;
    float acc[4] = {0.f, 0.f, 0.f, 0.f};
    for (int s = 0; s < NSPLIT; ++s) {
        int ps = (be * NSPLIT + s) * 16 + i;
        float wgt = __expf(pm[ps] - M);
        L += pl[ps] * wgt;
#pragma unroll
        for (int u = 0; u < 4; ++u) acc[u] += pacc[(size_t)ps * 64 + c * 4 + u] * wgt;
    }

    float inv = 1.f / L;
    _Float16* dst = outp + ((size_t)(b * S_ + n * BS_ + i)) * D_ + h * DH_ + c * 4;
#pragma unroll
    for (int u = 0; u < 4; ++u) dst[u] = (_Float16)(acc[u] * inv);
}

// ---------------------------------------------------------------------------
// LN: residual stream in f16. xh = LN(xh + g) (stats in f32).
// WRITE32: additionally write the f32 row (only the FINAL LN, for heads).
// ---------------------------------------------------------------------------
template<int WRITE32>
__global__ __launch_bounds__(256) void add_ln_kernel(
    _Float16* __restrict__ xh, const _Float16* __restrict__ g,
    const float* __restrict__ gamma, const float* __restrict__ beta,
    float* __restrict__ x32)
{
    int row = blockIdx.x;
    int t = threadIdx.x;
    _Float16* xr = xh + (size_t)row * D_;
    const _Float16* gr = g + (size_t)row * D_;

    float v[3];
    float s = 0.f, s2 = 0.f;
#pragma unroll
    for (int r = 0; r < 3; ++r) {
        int d = t + 256 * r;
        v[r] = (float)xr[d] + (float)gr[d];
        s += v[r];
        s2 += v[r] * v[r];
    }
#pragma unroll
    for (int off = 32; off; off >>= 1) {
        s  += __shfl_xor(s, off, 64);
        s2 += __shfl_xor(s2, off, 64);
    }
    __shared__ float sA[4], sB[4];
    int wave = t >> 6, lane = t & 63;
    if (lane == 0) { sA[wave] = s; sB[wave] = s2; }
    __syncthreads();
    s  = sA[0] + sA[1] + sA[2] + sA[3];
    s2 = sB[0] + sB[1] + sB[2] + sB[3];
    float mean = s * (1.0f / D_);
    float var = s2 * (1.0f / D_) - mean * mean;
    float rstd = rsqrtf(var + 1e-12f);
#pragma unroll
    for (int r = 0; r < 3; ++r) {
        int d = t + 256 * r;
        float o = (v[r] - mean) * rstd * gamma[d] + beta[d];
        xr[d] = (_Float16)o;
        if (WRITE32) x32[(size_t)row * D_ + d] = o;
    }
}

// ---------------------------------------------------------------------------
// Fused heads: blockIdx < 2048 -> start/end logits; else disc pool partial.
// ---------------------------------------------------------------------------
__global__ __launch_bounds__(256) void heads_fused(
    const float* __restrict__ x, const float* __restrict__ sw,
    const float* __restrict__ ew, const float* __restrict__ Wp,
    float* __restrict__ sl, float* __restrict__ el,
    float* __restrict__ partial)
{
    int bi = blockIdx.x;
    int t = threadIdx.x;
    if (bi < 2048) {
        int wave = t >> 6, lane = t & 63;
        int row = bi * 4 + wave;
        const float* xr = x + (size_t)row * D_;
        float a = 0.f, e = 0.f;
        for (int d = lane; d < D_; d += 64) {
            float xv = xr[d];
            a += xv * sw[d];
            e += xv * ew[d];
        }
#pragma unroll
        for (int off = 32; off; off >>= 1) {
            a += __shfl_xor(a, off, 64);
            e += __shfl_xor(e, off, 64);
        }
        if (lane == 0) { sl[row] = a; el[row] = e; }
    } else {
        int ei = bi - 2048;       // 0..23
        int jb = ei % 3;          // 0..2
        int ks = ei / 3;          // 0..7
        int j = jb * 256 + t;
        int k0 = ks * DKC;

        __shared__ float xs[DKC];
        if (t < DKC) xs[t] = x[k0 + t];   // x0 = x row 0
        __syncthreads();

        float s = 0.f;
#pragma unroll 8
        for (int kk = 0; kk < DKC; ++kk)
            s += xs[kk] * Wp[(size_t)(k0 + kk) * D_ + j];
        partial[ks * D_ + j] = s;
    }
}

// ---------------------------------------------------------------------------
// Fused final: r<4 -> softmax over S; r==4 -> disc finish.
// ---------------------------------------------------------------------------
__global__ __launch_bounds__(256) void final_fused(
    const float* __restrict__ sl, const float* __restrict__ el,
    const float* __restrict__ partial, const float* __restrict__ bp,
    const float* __restrict__ d1W, const float* __restrict__ d1b,
    const float* __restrict__ d2W, const float* __restrict__ d2b,
    float* __restrict__ outp)
{
    int r = blockIdx.x;
    int t = threadIdx.x;
    if (r < 4) {
        const float* src = (r < 2 ? sl : el) + (size_t)(r & 1) * S_;
        float* dst = outp + (r < 2 ? 0 : BT_) + (size_t)(r & 1) * S_;
        int wave = t >> 6, lane = t & 63;
        __shared__ float sm[4], ss[4];

        float m = -1e30f;
        for (int k = t; k < S_; k += 256) m = fmaxf(m, src[k]);
#pragma unroll
        for (int off = 32; off; off >>= 1) m = fmaxf(m, __shfl_xor(m, off, 64));
        if (lane == 0) sm[wave] = m;
        __syncthreads();
        m = fmaxf(fmaxf(sm[0], sm[1]), fmaxf(sm[2], sm[3]));

        float s = 0.f;
        for (int k = t; k < S_; k += 256) s += __expf(src[k] - m);
#pragma unroll
        for (int off = 32; off; off >>= 1) s += __shfl_xor(s, off, 64);
        if (lane == 0) ss[wave] = s;
        __syncthreads();
        s = ss[0] + ss[1] + ss[2] + ss[3];

        float inv = 1.f / s;
        for (int k = t; k < S_; k += 256) dst[k] = __expf(src[k] - m) * inv;
    } else {
        __shared__ float pool[D_];
        __shared__ float h1[20];
        float* out2 = outp + 2 * BT_;
        for (int j = t; j < D_; j += 256) {
            float s = bp[j];
#pragma unroll
            for (int ks = 0; ks < DKS; ++ks) s += partial[ks * D_ + j];
            pool[j] = tanhf(s);
        }
        __syncthreads();
        if (t < 20) {
            float s = d1b[t];
            for (int k = 0; k < D_; ++k) s += pool[k] * d1W[k * 20 + t];
            h1[t] = s;
        }
        __syncthreads();
        if (t == 0) {
            float d0 = d2b[0], d1v = d2b[1];
#pragma unroll
            for (int u = 0; u < 20; ++u) {
                d0  += h1[u] * d2W[u * 2 + 0];
                d1v += h1[u] * d2W[u * 2 + 1];
            }
            float m = fmaxf(d0, d1v);
            float e0 = __expf(d0 - m), e1 = __expf(d1v - m);
            float inv = 1.f / (e0 + e1);
            out2[0] = e0 * inv;
            out2[1] = e1 * inv;
        }
    }
}

// ---------------------------------------------------------------------------
extern "C" void kernel_launch(void* const* d_in, const int* in_sizes, int n_in,
                              void* d_out, int out_size, void* d_ws, size_t ws_size,
                              hipStream_t stream)
{
    const int*   ids   = (const int*)d_in[0];
    const int*   kbi   = (const int*)d_in[1];
    const float* emb   = (const float*)d_in[2];
    const float* Wqkv  = (const float*)d_in[3];
    const float* bqkv  = (const float*)d_in[4];
    const float* Wo    = (const float*)d_in[5];
    const float* bo    = (const float*)d_in[6];
    const float* ln1g  = (const float*)d_in[7];
    const float* ln1b  = (const float*)d_in[8];
    const float* Wff1  = (const float*)d_in[9];
    const float* bff1  = (const float*)d_in[10];
    const float* Wff2  = (const float*)d_in[11];
    const float* bff2  = (const float*)d_in[12];
    const float* ln2g  = (const float*)d_in[13];
    const float* ln2b  = (const float*)d_in[14];
    const float* Wp    = (const float*)d_in[15];
    const float* bp    = (const float*)d_in[16];
    const float* sw    = (const float*)d_in[17];
    const float* ew    = (const float*)d_in[18];
    const float* d1W   = (const float*)d_in[19];
    const float* d1b   = (const float*)d_in[20];
    const float* d2W   = (const float*)d_in[21];
    const float* d2b   = (const float*)d_in[22];
    float* outp = (float*)d_out;

    // workspace carve (float units)
    float* ws   = (float*)d_ws;
    float* x    = ws;                          // BT_*D_ f32 (final LN only)
    float* xbf  = x   + (size_t)BT_ * D_;      // f16 xh (residual stream)
    float* r1f  = xbf + (size_t)BT_ * D_ / 2;  // f16 qkv / f16 h
    float* abf  = r1f + (size_t)BT_ * FF_ / 2; // f16 attn out
    float* r2   = abf + (size_t)BT_ * D_ / 2;  // partials (early) / f16 g (late)
    float* wtf  = r2  + (size_t)BT_ * D_;      // f16 weights
    float* sl   = wtf + 7077888;
    float* el   = sl  + BT_;
    float* dpar = el  + BT_;                   // DKS * D_ disc partials

    _Float16* xh    = (_Float16*)xbf;
    _Float16* qkv16 = (_Float16*)r1f;
    _Float16* h16   = (_Float16*)r1f;
    _Float16* ab    = (_Float16*)abf;
    float* pm   = r2;
    float* pl   = r2 + NEDGE * NSPLIT * 16;
    float* pacc = pl + NEDGE * NSPLIT * 16;
    _Float16* g16 = (_Float16*)r2;   // aliased; partials dead once proj runs

    _Float16* Wt    = (_Float16*)wtf;
    _Float16* WqkvT = Wt;
    _Float16* WoT   = WqkvT + (size_t)2 * 2304 * 768;
    _Float16* Wff1T = WoT   + (size_t)2 * 768 * 768;
    _Float16* Wff2T = Wff1T + (size_t)2 * 3072 * 768;

    // fused weight convert + embed: one dispatch
    WSegs segs;
    int start = 0;
    for (int l = 0; l < 2; ++l) {
        int base = l * 4;
        segs.s[base + 0] = { Wqkv + (size_t)l * 768 * 2304,
                             WqkvT + (size_t)l * 2304 * 768, 768, 2304, start };
        start += (2304 / 32) * (768 / 32);
        segs.s[base + 1] = { Wo + (size_t)l * 768 * 768,
                             WoT + (size_t)l * 768 * 768, 768, 768, start };
        start += (768 / 32) * (768 / 32);
        segs.s[base + 2] = { Wff1 + (size_t)l * 768 * 3072,
                             Wff1T + (size_t)l * 3072 * 768, 768, 3072, start };
        start += (3072 / 32) * (768 / 32);
        segs.s[base + 3] = { Wff2 + (size_t)l * 3072 * 768,
                             Wff2T + (size_t)l * 768 * 3072, 3072, 768, start };
        start += (768 / 32) * (3072 / 32);
    }
    segs.total = start;   // 13824

    prep_all<<<segs.total + BT_, 256, 0, stream>>>(segs, ids, emb, xh);

    for (int l = 0; l < 2; ++l) {
        // qkv: BM=128 single-buffer, grid 64x18 = 1152
        gemm_f16<2,0,0,1><<<(BT_/128) * (2304/128), 256, 0, stream>>>(
            xh, WqkvT + (size_t)l * 2304 * 768, bqkv + (size_t)l * 3 * D_,
            qkv16, BT_, 3 * D_, D_, 2304/128);
        attn_fused<<<NSPARSE + NEDGE * NSPLIT, 256, 0, stream>>>(
            qkv16, kbi, ab, pm, pl, pacc);
        attn_edge_combine<<<NEDGE, 256, 0, stream>>>(pm, pl, pacc, ab);
        // proj: BM=64 + 2-phase dbuf, grid 128x6 = 768
        gemm_f16<1,1,0,1><<<(BT_/64) * (768/128), 256, 0, stream>>>(
            ab, WoT + (size_t)l * 768 * 768, bo + (size_t)l * D_,
            g16, BT_, D_, D_, 768/128);
        add_ln_kernel<0><<<BT_, 256, 0, stream>>>(
            xh, g16, ln1g + (size_t)l * D_, ln1b + (size_t)l * D_, nullptr);
        // ff1: BM=128 single-buffer, grid 64x24 = 1536
        gemm_f16<2,0,1,1><<<(BT_/128) * (3072/128), 256, 0, stream>>>(
            xh, Wff1T + (size_t)l * 3072 * 768, bff1 + (size_t)l * FF_,
            h16, BT_, FF_, D_, 3072/128);
        // ff2: BM=64 + 2-phase dbuf, grid 128x6 = 768
        gemm_f16<1,1,0,1><<<(BT_/64) * (768/128), 256, 0, stream>>>(
            h16, Wff2T + (size_t)l * 768 * 3072, bff2 + (size_t)l * D_,
            g16, BT_, D_, FF_, 768/128);
        if (l == 1)
            add_ln_kernel<1><<<BT_, 256, 0, stream>>>(
                xh, g16, ln2g + (size_t)l * D_, ln2b + (size_t)l * D_, x);
        else
            add_ln_kernel<0><<<BT_, 256, 0, stream>>>(
                xh, g16, ln2g + (size_t)l * D_, ln2b + (size_t)l * D_, nullptr);
    }

    heads_fused<<<2048 + 3 * DKS, 256, 0, stream>>>(x, sw, ew, Wp, sl, el, dpar);
    final_fused<<<5, 256, 0, stream>>>(sl, el, dpar, bp, d1W, d1b, d2W, d2b, outp);
}

// Round 25
// 548.180 us; speedup vs baseline: 1.4144x; 1.1083x over previous
//
#include <hip/hip_runtime.h>
#include <hip/hip_bf16.h>
#include <math.h>

#define B_   2
#define S_   4096
#define D_   768
#define H_   12
#define DH_  64
#define BS_  16
#define NB_  256
#define FF_  3072
#define BT_  (B_ * S_)          // 8192 token rows
#define SCALE_F 0.125f          // 1/sqrt(64)

#define NSPLIT 32               // key-dimension splits for edge attention
#define TILES_PER_SPLIT (NB_ / NSPLIT)   // 8
#define NEDGE (B_ * H_ * 2)     // 48 edge (b,h,e) groups
#define NSPARSE (B_ * H_ * NB_) // 6144 sparse work items
#define NXCD 8

typedef _Float16 f16x8 __attribute__((ext_vector_type(8)));
typedef _Float16 f16x4 __attribute__((ext_vector_type(4)));
typedef _Float16 f16x2 __attribute__((ext_vector_type(2)));
typedef float    f32x4 __attribute__((ext_vector_type(4)));
typedef float    f32x16 __attribute__((ext_vector_type(16)));

#define DKS 8                   // disc pool k-splits
#define DKC (D_ / DKS)          // 96 rows per split

// legacy K=16 f16 MFMA: spelled WITHOUT underscore before f16 (r24 fix)
#define MFMA_PV(a, b, c) __builtin_amdgcn_mfma_f32_16x16x16f16(a, b, c, 0, 0, 0)

// XCD-aware swizzle (T1): valid bijection when nwg % NXCD == 0.
__device__ __forceinline__ int xcd_swz(int bid, int nwg)
{
    int q = nwg / NXCD;
    return (bid % NXCD) * q + bid / NXCD;
}

// async global->LDS, 16B per lane; LDS dest is wave-uniform base + lane*16
#define GLD16(gp, lp) __builtin_amdgcn_global_load_lds( \
    (const __attribute__((address_space(1))) void*)(gp), \
    (__attribute__((address_space(3))) void*)(lp), 16, 0, 0)

__device__ __forceinline__ float fast_tanh(float z)
{
    float az = fabsf(z);
    float t = __expf(-2.0f * az);
    float r = (1.0f - t) / (1.0f + t);
    return z < 0.f ? -r : r;
}

__device__ __forceinline__ float gelu_tanh(float v)
{
    float v3 = v * v * v;
    return 0.5f * v * (1.0f + fast_tanh(0.79788456080286535588f * (v + 0.044715f * v3)));
}

// ---------------------------------------------------------------------------
// Fused weight convert + embedding (vectorized transpose).
// ---------------------------------------------------------------------------
struct WSeg { const float* src; _Float16* dst; int K; int N; int start; };
struct WSegs { WSeg s[8]; int total; };

__global__ __launch_bounds__(256) void prep_all(
    WSegs segs, const int* __restrict__ ids, const float* __restrict__ emb,
    _Float16* __restrict__ xh)
{
    int bt = blockIdx.x;
    int t = threadIdx.x;
    if (bt < segs.total) {
        __shared__ float tile[32][33];
        int si = 0;
#pragma unroll
        for (int u = 1; u < 8; ++u)
            if (bt >= segs.s[u].start) si = u;
        const WSeg& sg = segs.s[si];
        int tid = bt - sg.start;
        int tn = sg.N >> 5;
        int n0 = (tid % tn) * 32;
        int k0 = (tid / tn) * 32;

        {
            int r = t >> 3, c = (t & 7) * 4;
            f32x4 v = *(const f32x4*)&sg.src[(size_t)(k0 + r) * sg.N + n0 + c];
            tile[r][c + 0] = v[0];
            tile[r][c + 1] = v[1];
            tile[r][c + 2] = v[2];
            tile[r][c + 3] = v[3];
        }
        __syncthreads();
        {
            int r = t >> 3, c = (t & 7) * 4;
            f16x4 o;
            o[0] = (_Float16)tile[c + 0][r];
            o[1] = (_Float16)tile[c + 1][r];
            o[2] = (_Float16)tile[c + 2][r];
            o[3] = (_Float16)tile[c + 3][r];
            *(f16x4*)&sg.dst[(size_t)(n0 + r) * sg.K + k0 + c] = o;
        }
    } else {
        int row = bt - segs.total;
        int id = ids[row];
        const float* src = emb + (size_t)id * D_;
        _Float16* dst16 = xh + (size_t)row * D_;
        for (int d = t; d < D_; d += 256)
            dst16[d] = (_Float16)src[d];
    }
}

// ---------------------------------------------------------------------------
// MFMA fp16 GEMM (r22): templated M-block + optional 2-phase double buffer.
// ---------------------------------------------------------------------------
template<int MI, int DBUF, int ACT, int OUT16>
__global__ __launch_bounds__(256) void gemm_f16(
    const _Float16* __restrict__ A, const _Float16* __restrict__ Wt,
    const float* __restrict__ bias, void* __restrict__ Cp,
    int M, int N, int K, int NT128)
{
    constexpr int BM = MI * 64;
    constexpr int QA = 2 * MI;          // A 1KB chunks per wave
    constexpr int ASZ = BM * 64;        // f16 elems per A buffer
    constexpr int BSZ = 128 * 64;       // f16 elems per B buffer

    __shared__ __attribute__((aligned(16))) _Float16 As[(DBUF ? 2 : 1) * ASZ];
    __shared__ __attribute__((aligned(16))) _Float16 Bs[(DBUF ? 2 : 1) * BSZ];

    int t = threadIdx.x;
    int w = t >> 6, l = t & 63;
    int swz = xcd_swz(blockIdx.x, gridDim.x);
    int bm = (swz / NT128) * BM, bn = (swz % NT128) * 128;
    int wr = (w >> 1) * (MI * 32), wc = (w & 1) * 64;

    f32x16 acc[MI][2];
#pragma unroll
    for (int i = 0; i < MI; ++i)
#pragma unroll
        for (int j = 0; j < 2; ++j)
#pragma unroll
            for (int r = 0; r < 16; ++r) acc[i][j][r] = 0.f;

    const _Float16* gA[QA];
    const _Float16* gB[4];
#pragma unroll
    for (int q = 0; q < QA; ++q) {
        int m = w * QA + q;
        int row = m * 8 + (l >> 3);
        int sc = (l & 7) ^ (row & 7);
        gA[q] = A + (size_t)(bm + row) * K + sc * 8;
    }
#pragma unroll
    for (int q = 0; q < 4; ++q) {
        int m = w * 4 + q;
        int row = m * 8 + (l >> 3);
        int sc = (l & 7) ^ (row & 7);
        gB[q] = Wt + (size_t)(bn + row) * K + sc * 8;
    }

    int aoff[4][MI], boff[4][2];
#pragma unroll
    for (int kk = 0; kk < 4; ++kk) {
        int ch = (kk * 2 + (l >> 5)) ^ (l & 7);
#pragma unroll
        for (int i = 0; i < MI; ++i)
            aoff[kk][i] = (wr + i * 32 + (l & 31)) * 64 + ch * 8;
#pragma unroll
        for (int j = 0; j < 2; ++j)
            boff[kk][j] = (wc + j * 32 + (l & 31)) * 64 + ch * 8;
    }

#define STAGE_(BUF, K0)                                                   \
    {                                                                     \
        _Float16* ab_ = As + (BUF) * ASZ;                                 \
        _Float16* bb_ = Bs + (BUF) * BSZ;                                 \
        _Pragma("unroll")                                                 \
        for (int q = 0; q < QA; ++q)                                      \
            GLD16(gA[q] + (K0), ab_ + (w * QA + q) * 512);                \
        _Pragma("unroll")                                                 \
        for (int q = 0; q < 4; ++q)                                       \
            GLD16(gB[q] + (K0), bb_ + (w * 4 + q) * 512);                 \
    }

#define COMPUTE_(BUF)                                                     \
    {                                                                     \
        const _Float16* ab_ = As + (BUF) * ASZ;                           \
        const _Float16* bb_ = Bs + (BUF) * BSZ;                           \
        _Pragma("unroll")                                                 \
        for (int kk = 0; kk < 4; ++kk) {                                  \
            f16x8 af[MI], bf[2];                                          \
            _Pragma("unroll")                                             \
            for (int i = 0; i < MI; ++i)                                  \
                af[i] = *(const f16x8*)(ab_ + aoff[kk][i]);               \
            _Pragma("unroll")                                             \
            for (int j = 0; j < 2; ++j)                                   \
                bf[j] = *(const f16x8*)(bb_ + boff[kk][j]);               \
            _Pragma("unroll")                                             \
            for (int i = 0; i < MI; ++i)                                  \
                _Pragma("unroll")                                         \
                for (int j = 0; j < 2; ++j)                               \
                    acc[i][j] = __builtin_amdgcn_mfma_f32_32x32x16_f16(   \
                        af[i], bf[j], acc[i][j], 0, 0, 0);                \
        }                                                                 \
    }

    if (DBUF) {
        STAGE_(0, 0);
        __syncthreads();
        int cur = 0;
#pragma unroll 2
        for (int k0 = 0; k0 < K; k0 += 64) {
            if (k0 + 64 < K) STAGE_(cur ^ 1, k0 + 64);
            COMPUTE_(cur);
            __syncthreads();
            cur ^= 1;
        }
    } else {
        for (int k0 = 0; k0 < K; k0 += 64) {
            STAGE_(0, k0);
            __syncthreads();
            COMPUTE_(0);
            __syncthreads();
        }
    }
#undef STAGE_
#undef COMPUTE_

#pragma unroll
    for (int i = 0; i < MI; ++i) {
#pragma unroll
        for (int j = 0; j < 2; ++j) {
            int col = bn + wc + j * 32 + (l & 31);
            float bv = bias[col];
#pragma unroll
            for (int rg = 0; rg < 4; ++rg) {
                int row0 = bm + wr + i * 32 + 8 * rg + 4 * (l >> 5);
#pragma unroll
                for (int r = 0; r < 4; ++r) {
                    float v = acc[i][j][rg * 4 + r] + bv;
                    if (ACT) v = gelu_tanh(v);
                    if (OUT16)
                        ((_Float16*)Cp)[(size_t)(row0 + r) * N + col] = (_Float16)v;
                    else
                        ((float*)Cp)[(size_t)(row0 + r) * N + col] = v;
                }
            }
        }
    }
}

// ---------------------------------------------------------------------------
// MFMA attention (r23 rewrite, r24 builtin-spelling fix). ONE WAVE per
// (b,h,n)[,split]; no barriers. Scores: S = mfma_16x16x32(K, Q) x2 (swapped
// operands) -> lane l holds S[key=g*4+r][query=l&15] (g=l>>4) — exactly the
// A-fragment layout P[row=q][k] for PV mfma_16x16x16(P, V): zero cross-lane
// shuffles on P. K/Q fragments load straight from global (dwordx4); V staged
// per tile into vq[64][24] f16. Softmax stats fp32; corr/lsum rebroadcast to
// PV row layout (q' = g*4+r) with 4 shfl.
// ---------------------------------------------------------------------------
template<int NT, bool EDGE>
__device__ __forceinline__ void attn_wave(
    const _Float16* __restrict__ qkv, const int* __restrict__ key_idx,
    _Float16* __restrict__ outp, float* __restrict__ pm,
    float* __restrict__ pl, float* __restrict__ pacc,
    int b, int h, int n, int split, int be,
    _Float16 (*vq)[24])
{
    int l = threadIdx.x & 63;
    int q = l & 15;          // query (score B / P-A row); also key for staging
    int g = l >> 4;          // k-group

    // Q fragments (B-operand): Q[query=q][k = g*8+u (+32 for half 1)]
    const _Float16* qp = qkv + ((size_t)(b * S_ + n * BS_ + q)) * (3 * D_) + h * DH_ + g * 8;
    f16x8 qf0 = *(const f16x8*)qp;
    f16x8 qf1 = *(const f16x8*)(qp + 32);

    float m_old = -1e30f, lsum = 0.f;
    f32x4 o[4];
#pragma unroll
    for (int db = 0; db < 4; ++db) o[db] = (f32x4){0.f, 0.f, 0.f, 0.f};

#pragma unroll 1
    for (int jj = 0; jj < NT; ++jj) {
        int kb = EDGE ? (split * NT + jj) : key_idx[n * 7 + jj];
        const _Float16* kvrow = qkv + ((size_t)(b * S_ + kb * BS_ + q)) * (3 * D_);

        // K fragments (A-operand): K[key=q][k = g*8+u (+32)]
        f16x8 kf0 = *(const f16x8*)(kvrow + D_ + h * DH_ + g * 8);
        f16x8 kf1 = *(const f16x8*)(kvrow + D_ + h * DH_ + g * 8 + 32);

        // stage V: lane covers key=q, d-range g*16..+16 -> vq[d][key]
        {
            const _Float16* vp = kvrow + 2 * D_ + h * DH_ + g * 16;
            f16x8 v0 = *(const f16x8*)vp;
            f16x8 v1 = *(const f16x8*)(vp + 8);
#pragma unroll
            for (int u = 0; u < 8; ++u) vq[g * 16 + u][q] = v0[u];
#pragma unroll
            for (int u = 0; u < 8; ++u) vq[g * 16 + 8 + u][q] = v1[u];
        }

        // scores: D[key][query] = K x Q over k=0..63
        f32x4 sc = (f32x4){0.f, 0.f, 0.f, 0.f};
        sc = __builtin_amdgcn_mfma_f32_16x16x32_f16(kf0, qf0, sc, 0, 0, 0);
        sc = __builtin_amdgcn_mfma_f32_16x16x32_f16(kf1, qf1, sc, 0, 0, 0);
#pragma unroll
        for (int r = 0; r < 4; ++r) sc[r] *= SCALE_F;

        // online softmax per query (lanes q, q+16, q+32, q+48 share a query)
        float tm = fmaxf(fmaxf(sc[0], sc[1]), fmaxf(sc[2], sc[3]));
        tm = fmaxf(tm, __shfl_xor(tm, 16, 64));
        tm = fmaxf(tm, __shfl_xor(tm, 32, 64));
        float m_new = fmaxf(m_old, tm);

        float pr[4];
        float rs = 0.f;
#pragma unroll
        for (int r = 0; r < 4; ++r) { pr[r] = __expf(sc[r] - m_new); rs += pr[r]; }
        rs += __shfl_xor(rs, 16, 64);
        rs += __shfl_xor(rs, 32, 64);

        float corr = __expf(m_old - m_new);
        lsum = lsum * corr + rs;
        m_old = m_new;

        // rescale O (rows q' = g*4+r): fetch corr per row via shfl
        float cq[4];
#pragma unroll
        for (int r = 0; r < 4; ++r) cq[r] = __shfl(corr, g * 4 + r, 64);
#pragma unroll
        for (int db = 0; db < 4; ++db)
#pragma unroll
            for (int r = 0; r < 4; ++r) o[db][r] *= cq[r];

        // P -> f16 A-fragment (layout already correct: pa[u] = P[q][g*4+u])
        f16x4 pa;
#pragma unroll
        for (int r = 0; r < 4; ++r) pa[r] = (_Float16)pr[r];

        // PV: for each 16-wide d-block, B-frag = V[k=g*4+u][d=db*16+q]
#pragma unroll
        for (int db = 0; db < 4; ++db) {
            f16x4 vb = *(const f16x4*)&vq[db * 16 + q][g * 4];
            o[db] = MFMA_PV(pa, vb, o[db]);
        }
    }

    if (EDGE) {
        int base16 = (be * NSPLIT + split) * 16;
        if (l < 16) { pm[base16 + l] = m_old; pl[base16 + l] = lsum; }
#pragma unroll
        for (int db = 0; db < 4; ++db)
#pragma unroll
            for (int r = 0; r < 4; ++r)
                pacc[(size_t)(base16 + g * 4 + r) * 64 + db * 16 + q] = o[db][r];
    } else {
        float linv[4];
#pragma unroll
        for (int r = 0; r < 4; ++r) linv[r] = 1.f / __shfl(lsum, g * 4 + r, 64);
#pragma unroll
        for (int r = 0; r < 4; ++r) {
            _Float16* dst = outp + ((size_t)(b * S_ + n * BS_ + g * 4 + r)) * D_ + h * DH_ + q;
#pragma unroll
            for (int db = 0; db < 4; ++db)
                dst[db * 16] = (_Float16)(o[db][r] * linv[r]);
        }
    }
}

// ---------------------------------------------------------------------------
// Fused attention dispatch: 4 independent waves per block (no barriers).
// ---------------------------------------------------------------------------
__global__ __launch_bounds__(256) void attn_fused(
    const _Float16* __restrict__ qkv, const int* __restrict__ key_idx,
    _Float16* __restrict__ outp, float* __restrict__ pm,
    float* __restrict__ pl, float* __restrict__ pacc)
{
    __shared__ __attribute__((aligned(16))) _Float16 vqs[4][64][24];

    int w = threadIdx.x >> 6;
    int bi = xcd_swz(blockIdx.x, gridDim.x) * 4 + w;

    if (bi < NSPARSE) {
        int n = bi % NB_;
        if (n == 0 || n == NB_ - 1) return;   // per-wave exit; kernel has no barriers
        int h = (bi / NB_) % H_;
        int b = bi / (NB_ * H_);
        attn_wave<7, false>(qkv, key_idx, outp, nullptr, nullptr, nullptr,
                            b, h, n, 0, 0, vqs[w]);
    } else {
        int ei = bi - NSPARSE;
        int split = ei % NSPLIT;
        int be = ei / NSPLIT;
        int e = be & 1;
        int h = (be >> 1) % H_;
        int b = be / (2 * H_);
        int n = e ? (NB_ - 1) : 0;
        attn_wave<TILES_PER_SPLIT, true>(qkv, nullptr, nullptr, pm, pl, pacc,
                                         b, h, n, split, be, vqs[w]);
    }
}

// ---------------------------------------------------------------------------
// Edge attention combine (unchanged layout)
// ---------------------------------------------------------------------------
__global__ __launch_bounds__(256) void attn_edge_combine(
    const float* __restrict__ pm, const float* __restrict__ pl,
    const float* __restrict__ pacc, _Float16* __restrict__ outp)
{
    int be = blockIdx.x;
    int e = be & 1;
    int h = (be >> 1) % H_;
    int b = be / (2 * H_);
    int n = e ? (NB_ - 1) : 0;

    int t = threadIdx.x;
    int i = t >> 4;
    int c = t & 15;

    float M = -1e30f;
#pragma unroll 4
    for (int s = 0; s < NSPLIT; ++s)
        M = fmaxf(M, pm[(be * NSPLIT + s) * 16 + i]);

    float L = 0.f;
    float acc[4] = {0.f, 0.f, 0.f, 0.f};
    for (int s = 0; s < NSPLIT; ++s) {
        int ps = (be * NSPLIT + s) * 16 + i;
        float wgt = __expf(pm[ps] - M);
        L += pl[ps] * wgt;
#pragma unroll
        for (int u = 0; u < 4; ++u) acc[u] += pacc[(size_t)ps * 64 + c * 4 + u] * wgt;
    }

    float inv = 1.f / L;
    _Float16* dst = outp + ((size_t)(b * S_ + n * BS_ + i)) * D_ + h * DH_ + c * 4;
#pragma unroll
    for (int u = 0; u < 4; ++u) dst[u] = (_Float16)(acc[u] * inv);
}

// ---------------------------------------------------------------------------
// LN: residual stream in f16. xh = LN(xh + g) (stats in f32).
// ---------------------------------------------------------------------------
template<int WRITE32>
__global__ __launch_bounds__(256) void add_ln_kernel(
    _Float16* __restrict__ xh, const _Float16* __restrict__ g,
    const float* __restrict__ gamma, const float* __restrict__ beta,
    float* __restrict__ x32)
{
    int row = blockIdx.x;
    int t = threadIdx.x;
    _Float16* xr = xh + (size_t)row * D_;
    const _Float16* gr = g + (size_t)row * D_;

    float v[3];
    float s = 0.f, s2 = 0.f;
#pragma unroll
    for (int r = 0; r < 3; ++r) {
        int d = t + 256 * r;
        v[r] = (float)xr[d] + (float)gr[d];
        s += v[r];
        s2 += v[r] * v[r];
    }
#pragma unroll
    for (int off = 32; off; off >>= 1) {
        s  += __shfl_xor(s, off, 64);
        s2 += __shfl_xor(s2, off, 64);
    }
    __shared__ float sA[4], sB[4];
    int wave = t >> 6, lane = t & 63;
    if (lane == 0) { sA[wave] = s; sB[wave] = s2; }
    __syncthreads();
    s  = sA[0] + sA[1] + sA[2] + sA[3];
    s2 = sB[0] + sB[1] + sB[2] + sB[3];
    float mean = s * (1.0f / D_);
    float var = s2 * (1.0f / D_) - mean * mean;
    float rstd = rsqrtf(var + 1e-12f);
#pragma unroll
    for (int r = 0; r < 3; ++r) {
        int d = t + 256 * r;
        float o = (v[r] - mean) * rstd * gamma[d] + beta[d];
        xr[d] = (_Float16)o;
        if (WRITE32) x32[(size_t)row * D_ + d] = o;
    }
}

// ---------------------------------------------------------------------------
// Fused heads: blockIdx < 2048 -> start/end logits; else disc pool partial.
// ---------------------------------------------------------------------------
__global__ __launch_bounds__(256) void heads_fused(
    const float* __restrict__ x, const float* __restrict__ sw,
    const float* __restrict__ ew, const float* __restrict__ Wp,
    float* __restrict__ sl, float* __restrict__ el,
    float* __restrict__ partial)
{
    int bi = blockIdx.x;
    int t = threadIdx.x;
    if (bi < 2048) {
        int wave = t >> 6, lane = t & 63;
        int row = bi * 4 + wave;
        const float* xr = x + (size_t)row * D_;
        float a = 0.f, e = 0.f;
        for (int d = lane; d < D_; d += 64) {
            float xv = xr[d];
            a += xv * sw[d];
            e += xv * ew[d];
        }
#pragma unroll
        for (int off = 32; off; off >>= 1) {
            a += __shfl_xor(a, off, 64);
            e += __shfl_xor(e, off, 64);
        }
        if (lane == 0) { sl[row] = a; el[row] = e; }
    } else {
        int ei = bi - 2048;       // 0..23
        int jb = ei % 3;          // 0..2
        int ks = ei / 3;          // 0..7
        int j = jb * 256 + t;
        int k0 = ks * DKC;

        __shared__ float xs[DKC];
        if (t < DKC) xs[t] = x[k0 + t];   // x0 = x row 0
        __syncthreads();

        float s = 0.f;
#pragma unroll 8
        for (int kk = 0; kk < DKC; ++kk)
            s += xs[kk] * Wp[(size_t)(k0 + kk) * D_ + j];
        partial[ks * D_ + j] = s;
    }
}

// ---------------------------------------------------------------------------
// Fused final: r<4 -> softmax over S; r==4 -> disc finish.
// ---------------------------------------------------------------------------
__global__ __launch_bounds__(256) void final_fused(
    const float* __restrict__ sl, const float* __restrict__ el,
    const float* __restrict__ partial, const float* __restrict__ bp,
    const float* __restrict__ d1W, const float* __restrict__ d1b,
    const float* __restrict__ d2W, const float* __restrict__ d2b,
    float* __restrict__ outp)
{
    int r = blockIdx.x;
    int t = threadIdx.x;
    if (r < 4) {
        const float* src = (r < 2 ? sl : el) + (size_t)(r & 1) * S_;
        float* dst = outp + (r < 2 ? 0 : BT_) + (size_t)(r & 1) * S_;
        int wave = t >> 6, lane = t & 63;
        __shared__ float sm[4], ss[4];

        float m = -1e30f;
        for (int k = t; k < S_; k += 256) m = fmaxf(m, src[k]);
#pragma unroll
        for (int off = 32; off; off >>= 1) m = fmaxf(m, __shfl_xor(m, off, 64));
        if (lane == 0) sm[wave] = m;
        __syncthreads();
        m = fmaxf(fmaxf(sm[0], sm[1]), fmaxf(sm[2], sm[3]));

        float s = 0.f;
        for (int k = t; k < S_; k += 256) s += __expf(src[k] - m);
#pragma unroll
        for (int off = 32; off; off >>= 1) s += __shfl_xor(s, off, 64);
        if (lane == 0) ss[wave] = s;
        __syncthreads();
        s = ss[0] + ss[1] + ss[2] + ss[3];

        float inv = 1.f / s;
        for (int k = t; k < S_; k += 256) dst[k] = __expf(src[k] - m) * inv;
    } else {
        __shared__ float pool[D_];
        __shared__ float h1[20];
        float* out2 = outp + 2 * BT_;
        for (int j = t; j < D_; j += 256) {
            float s = bp[j];
#pragma unroll
            for (int ks = 0; ks < DKS; ++ks) s += partial[ks * D_ + j];
            pool[j] = tanhf(s);
        }
        __syncthreads();
        if (t < 20) {
            float s = d1b[t];
            for (int k = 0; k < D_; ++k) s += pool[k] * d1W[k * 20 + t];
            h1[t] = s;
        }
        __syncthreads();
        if (t == 0) {
            float d0 = d2b[0], d1v = d2b[1];
#pragma unroll
            for (int u = 0; u < 20; ++u) {
                d0  += h1[u] * d2W[u * 2 + 0];
                d1v += h1[u] * d2W[u * 2 + 1];
            }
            float m = fmaxf(d0, d1v);
            float e0 = __expf(d0 - m), e1 = __expf(d1v - m);
            float inv = 1.f / (e0 + e1);
            out2[0] = e0 * inv;
            out2[1] = e1 * inv;
        }
    }
}

// ---------------------------------------------------------------------------
extern "C" void kernel_launch(void* const* d_in, const int* in_sizes, int n_in,
                              void* d_out, int out_size, void* d_ws, size_t ws_size,
                              hipStream_t stream)
{
    const int*   ids   = (const int*)d_in[0];
    const int*   kbi   = (const int*)d_in[1];
    const float* emb   = (const float*)d_in[2];
    const float* Wqkv  = (const float*)d_in[3];
    const float* bqkv  = (const float*)d_in[4];
    const float* Wo    = (const float*)d_in[5];
    const float* bo    = (const float*)d_in[6];
    const float* ln1g  = (const float*)d_in[7];
    const float* ln1b  = (const float*)d_in[8];
    const float* Wff1  = (const float*)d_in[9];
    const float* bff1  = (const float*)d_in[10];
    const float* Wff2  = (const float*)d_in[11];
    const float* bff2  = (const float*)d_in[12];
    const float* ln2g  = (const float*)d_in[13];
    const float* ln2b  = (const float*)d_in[14];
    const float* Wp    = (const float*)d_in[15];
    const float* bp    = (const float*)d_in[16];
    const float* sw    = (const float*)d_in[17];
    const float* ew    = (const float*)d_in[18];
    const float* d1W   = (const float*)d_in[19];
    const float* d1b   = (const float*)d_in[20];
    const float* d2W   = (const float*)d_in[21];
    const float* d2b   = (const float*)d_in[22];
    float* outp = (float*)d_out;

    // workspace carve (float units)
    float* ws   = (float*)d_ws;
    float* x    = ws;                          // BT_*D_ f32 (final LN only)
    float* xbf  = x   + (size_t)BT_ * D_;      // f16 xh (residual stream)
    float* r1f  = xbf + (size_t)BT_ * D_ / 2;  // f16 qkv / f16 h
    float* abf  = r1f + (size_t)BT_ * FF_ / 2; // f16 attn out
    float* r2   = abf + (size_t)BT_ * D_ / 2;  // partials (early) / f16 g (late)
    float* wtf  = r2  + (size_t)BT_ * D_;      // f16 weights
    float* sl   = wtf + 7077888;
    float* el   = sl  + BT_;
    float* dpar = el  + BT_;                   // DKS * D_ disc partials

    _Float16* xh    = (_Float16*)xbf;
    _Float16* qkv16 = (_Float16*)r1f;
    _Float16* h16   = (_Float16*)r1f;
    _Float16* ab    = (_Float16*)abf;
    float* pm   = r2;
    float* pl   = r2 + NEDGE * NSPLIT * 16;
    float* pacc = pl + NEDGE * NSPLIT * 16;
    _Float16* g16 = (_Float16*)r2;   // aliased; partials dead once proj runs

    _Float16* Wt    = (_Float16*)wtf;
    _Float16* WqkvT = Wt;
    _Float16* WoT   = WqkvT + (size_t)2 * 2304 * 768;
    _Float16* Wff1T = WoT   + (size_t)2 * 768 * 768;
    _Float16* Wff2T = Wff1T + (size_t)2 * 3072 * 768;

    // fused weight convert + embed: one dispatch
    WSegs segs;
    int start = 0;
    for (int l = 0; l < 2; ++l) {
        int base = l * 4;
        segs.s[base + 0] = { Wqkv + (size_t)l * 768 * 2304,
                             WqkvT + (size_t)l * 2304 * 768, 768, 2304, start };
        start += (2304 / 32) * (768 / 32);
        segs.s[base + 1] = { Wo + (size_t)l * 768 * 768,
                             WoT + (size_t)l * 768 * 768, 768, 768, start };
        start += (768 / 32) * (768 / 32);
        segs.s[base + 2] = { Wff1 + (size_t)l * 768 * 3072,
                             Wff1T + (size_t)l * 3072 * 768, 768, 3072, start };
        start += (3072 / 32) * (768 / 32);
        segs.s[base + 3] = { Wff2 + (size_t)l * 3072 * 768,
                             Wff2T + (size_t)l * 768 * 3072, 3072, 768, start };
        start += (768 / 32) * (3072 / 32);
    }
    segs.total = start;   // 13824

    prep_all<<<segs.total + BT_, 256, 0, stream>>>(segs, ids, emb, xh);

    for (int l = 0; l < 2; ++l) {
        // qkv: BM=128 single-buffer, grid 1152
        gemm_f16<2,0,0,1><<<(BT_/128) * (2304/128), 256, 0, stream>>>(
            xh, WqkvT + (size_t)l * 2304 * 768, bqkv + (size_t)l * 3 * D_,
            qkv16, BT_, 3 * D_, D_, 2304/128);
        // attention: 7680 work items, 4 waves/block -> 1920 blocks (no barriers)
        attn_fused<<<(NSPARSE + NEDGE * NSPLIT) / 4, 256, 0, stream>>>(
            qkv16, kbi, ab, pm, pl, pacc);
        attn_edge_combine<<<NEDGE, 256, 0, stream>>>(pm, pl, pacc, ab);
        // proj: BM=64 + 2-phase dbuf, grid 768
        gemm_f16<1,1,0,1><<<(BT_/64) * (768/128), 256, 0, stream>>>(
            ab, WoT + (size_t)l * 768 * 768, bo + (size_t)l * D_,
            g16, BT_, D_, D_, 768/128);
        add_ln_kernel<0><<<BT_, 256, 0, stream>>>(
            xh, g16, ln1g + (size_t)l * D_, ln1b + (size_t)l * D_, nullptr);
        // ff1: BM=128 single-buffer, grid 1536
        gemm_f16<2,0,1,1><<<(BT_/128) * (3072/128), 256, 0, stream>>>(
            xh, Wff1T + (size_t)l * 3072 * 768, bff1 + (size_t)l * FF_,
            h16, BT_, FF_, D_, 3072/128);
        // ff2: BM=64 + 2-phase dbuf, grid 768
        gemm_f16<1,1,0,1><<<(BT_/64) * (768/128), 256, 0, stream>>>(
            h16, Wff2T + (size_t)l * 768 * 3072, bff2 + (size_t)l * D_,
            g16, BT_, D_, FF_, 768/128);
        if (l == 1)
            add_ln_kernel<1><<<BT_, 256, 0, stream>>>(
                xh, g16, ln2g + (size_t)l * D_, ln2b + (size_t)l * D_, x);
        else
            add_ln_kernel<0><<<BT_, 256, 0, stream>>>(
                xh, g16, ln2g + (size_t)l * D_, ln2b + (size_t)l * D_, nullptr);
    }

    heads_fused<<<2048 + 3 * DKS, 256, 0, stream>>>(x, sw, ew, Wp, sl, el, dpar);
    final_fused<<<5, 256, 0, stream>>>(sl, el, dpar, bp, d1W, d1b, d2W, d2b, outp);
}